// Round 14
// baseline (419.595 us; speedup 1.0000x reference)
//
#include <hip/hip_runtime.h>
#include <stdint.h>

typedef short bf16x8 __attribute__((ext_vector_type(8)));
typedef short bf16x4 __attribute__((ext_vector_type(4)));
typedef float f32x4 __attribute__((ext_vector_type(4)));
typedef float f32x16 __attribute__((ext_vector_type(16)));
typedef int i32x4 __attribute__((ext_vector_type(4)));

__device__ __forceinline__ short f2bf(float f) {
  union { float f; uint32_t u; } v; v.f = f;
  uint32_t r = (v.u + 0x7FFFu + ((v.u >> 16) & 1u)) >> 16;
  return (short)(uint16_t)r;
}

__device__ __forceinline__ int cvtpk(float lo, float hi) {
  int r;
  asm("v_cvt_pk_bf16_f32 %0, %1, %2" : "=v"(r) : "v"(lo), "v"(hi));
  return r;
}

// async global->LDS, 16B per lane; LDS dest must be linear in lane order
__device__ __forceinline__ void gload16(const void* g, void* l) {
  __builtin_amdgcn_global_load_lds(
      (const __attribute__((address_space(1))) unsigned int*)g,
      (__attribute__((address_space(3))) unsigned int*)l, 16, 0, 0);
}

#define WAITV(n) asm volatile("s_waitcnt vmcnt(" #n ")" ::: "memory")
#define BARRIER()                          \
  do {                                     \
    __builtin_amdgcn_s_barrier();          \
    asm volatile("" ::: "memory");         \
  } while (0)

// ---------------- elementwise f32 -> bf16 ----------------
__global__ __launch_bounds__(256) void k_convert(const float* __restrict__ in,
                                                 short* __restrict__ out, int n) {
  int i = (blockIdx.x * 256 + threadIdx.x) * 4;
  if (i >= n) return;
  float4 v = *reinterpret_cast<const float4*>(in + i);
  bf16x4 o; o[0] = f2bf(v.x); o[1] = f2bf(v.y); o[2] = f2bf(v.z); o[3] = f2bf(v.w);
  *reinterpret_cast<bf16x4*>(out + i) = o;
}

// ---------------- transpose + convert: out[C][R] = bf16(in[R][C]) ----------------
__global__ __launch_bounds__(256) void k_transpose_cvt(const float* __restrict__ in,
                                                       short* __restrict__ out,
                                                       int R, int C) {
  __shared__ float tile[32][33];
  int r0 = blockIdx.y * 32, c0 = blockIdx.x * 32;
  int tx = threadIdx.x & 31, ty = threadIdx.x >> 5;
#pragma unroll
  for (int j = 0; j < 4; ++j)
    tile[ty + j * 8][tx] = in[(size_t)(r0 + ty + j * 8) * C + c0 + tx];
  __syncthreads();
#pragma unroll
  for (int j = 0; j < 4; ++j)
    out[(size_t)(c0 + ty + j * 8) * R + r0 + tx] = f2bf(tile[tx][ty + j * 8]);
}

// ---------------- column sums, two-stage deterministic reduction ----------------
__global__ __launch_bounds__(256) void k_colsum1(const float* __restrict__ E,
                                                 const float* __restrict__ F,
                                                 float* __restrict__ partial) {
  const int c = blockIdx.x * 256 + threadIdx.x;
  const int tc = blockIdx.y, which = blockIdx.z;
  const float* src = (which ? F : E) + (size_t)(tc * 64) * 1024 + c;
  float s = 0.f;
#pragma unroll 8
  for (int t = 0; t < 64; ++t) s += src[(size_t)t * 1024];
  partial[((size_t)which * 64 + tc) * 1024 + c] = s;
}

__global__ __launch_bounds__(256) void k_colsum2(const float* __restrict__ partial,
                                                 float* __restrict__ sE,
                                                 float* __restrict__ sF) {
  const int bid = blockIdx.x;
  const int which = bid >> 2, c = (bid & 3) * 256 + threadIdx.x;
  const float* p = partial + (size_t)which * 64 * 1024 + c;
  float s = 0.f;
#pragma unroll 8
  for (int t = 0; t < 64; ++t) s += p[(size_t)t * 1024];
  (which ? sF : sE)[c] = s;
}

// ---------------- GEMM_q: qb = x @ Wq + bq  (256x256, BK=32, quad-buffered) ----------
__global__ __launch_bounds__(512, 2) void k_gemm_q(const short* __restrict__ A,
                                                   const short* __restrict__ BT,
                                                   const float* __restrict__ bias,
                                                   short* __restrict__ qb) {
  __shared__ __align__(16) char lds[4 * 32768];
  const int tid = threadIdx.x, l = tid & 63, wv = tid >> 6;
  const int wm = wv >> 2, wn = wv & 3;
  const int r16 = l & 15, g4 = l >> 4;
  const int orig = blockIdx.x;
  const int xcd = orig & 7, loc = orig >> 3;
  const int m0 = (xcd * 8 + (loc & 7)) * 256, n0 = (loc >> 3) * 256;
  const int sl = (tid & 3) ^ ((tid >> 3) & 3);
  const short* aS = A + (size_t)(m0 + (tid >> 2)) * 1024 + sl * 8;
  const short* bS = BT + (size_t)(n0 + (tid >> 2)) * 1024 + sl * 8;
  const int sw = (g4 ^ ((r16 >> 1) & 3)) * 16;

  f32x4 acc[8][4];
#pragma unroll
  for (int i = 0; i < 8; ++i)
#pragma unroll
    for (int j = 0; j < 4; ++j) acc[i][j] = f32x4{0.f, 0.f, 0.f, 0.f};

#define STAGEQ(kt, bf)                                                      \
  {                                                                         \
    const int k0_ = (kt) * 32;                                              \
    gload16(aS + k0_, lds + (bf) * 32768 + tid * 16);                       \
    gload16(aS + 131072 + k0_, lds + (bf) * 32768 + 8192 + tid * 16);       \
    gload16(bS + k0_, lds + (bf) * 32768 + 16384 + tid * 16);               \
    gload16(bS + 131072 + k0_, lds + (bf) * 32768 + 24576 + tid * 16);      \
  }

  STAGEQ(0, 0); STAGEQ(1, 1); STAGEQ(2, 2);

  for (int kt = 0; kt < 32; ++kt) {
    if (kt < 30) WAITV(8);
    else if (kt == 30) WAITV(4);
    else WAITV(0);
    BARRIER();
    if (kt + 3 < 32) STAGEQ(kt + 3, (kt + 3) & 3);
    const char* aT = lds + (kt & 3) * 32768;
    const char* bT = aT + 16384;
    bf16x8 af[8], bfr[4];
#pragma unroll
    for (int mi = 0; mi < 8; ++mi)
      af[mi] = *(const bf16x8*)(aT + (wm * 128 + mi * 16 + r16) * 64 + sw);
#pragma unroll
    for (int ni = 0; ni < 4; ++ni)
      bfr[ni] = *(const bf16x8*)(bT + (wn * 64 + ni * 16 + r16) * 64 + sw);
    __builtin_amdgcn_s_setprio(1);
#pragma unroll
    for (int mi = 0; mi < 8; ++mi)
#pragma unroll
      for (int ni = 0; ni < 4; ++ni)
        acc[mi][ni] = __builtin_amdgcn_mfma_f32_16x16x32_bf16(af[mi], bfr[ni], acc[mi][ni], 0, 0, 0);
    __builtin_amdgcn_s_setprio(0);
  }
#undef STAGEQ

#pragma unroll
  for (int i = 0; i < 8; ++i)
#pragma unroll
    for (int j = 0; j < 4; ++j) {
      int row = m0 + wm * 128 + i * 16 + g4 * 4;
      int col = n0 + wn * 64 + j * 16 + r16;
      float bv = bias[col];
#pragma unroll
      for (int q = 0; q < 4; ++q)
        qb[(size_t)(row + q) * 1024 + col] = f2bf(acc[i][j][q] + bv);
    }
}

// ---------------- xE GEMM (128x128, BK=32, quad-buffered, K=4096) ----------------
__global__ __launch_bounds__(256, 2) void k_proj(const short* __restrict__ Et,
                                                 const short* __restrict__ Ft,
                                                 const short* __restrict__ xT,
                                                 short* __restrict__ xEk,
                                                 short* __restrict__ xEv) {
  const int z = blockIdx.z, b = z >> 1, which = z & 1;
  const short* __restrict__ AT = which ? Ft : Et;
  const short* __restrict__ BTp = xT + ((size_t)b << 10) * 4096;
  short* __restrict__ outp = which ? xEv : xEk;
  __shared__ __align__(16) char lds[4 * 16384];
  const int tid = threadIdx.x, l = tid & 63, wv = tid >> 6;
  const int wm = wv >> 1, wn = wv & 1;
  const int r16 = l & 15, g4 = l >> 4;
  const int m0 = blockIdx.x * 128, n0 = blockIdx.y * 128;
  const int sl = (tid & 3) ^ ((tid >> 3) & 3);
  const short* aS = AT + (size_t)(m0 + (tid >> 2)) * 4096 + sl * 8;
  const short* bS = BTp + (size_t)(n0 + (tid >> 2)) * 4096 + sl * 8;
  const int sw = (g4 ^ ((r16 >> 1) & 3)) * 16;

  f32x4 acc[4][4];
#pragma unroll
  for (int i = 0; i < 4; ++i)
#pragma unroll
    for (int j = 0; j < 4; ++j) acc[i][j] = f32x4{0.f, 0.f, 0.f, 0.f};

#define STAGE2(kt, bf)                                                      \
  {                                                                         \
    const int k0_ = (kt) * 32;                                              \
    gload16(aS + k0_, lds + (bf) * 16384 + tid * 16);                       \
    gload16(aS + 262144 + k0_, lds + (bf) * 16384 + 4096 + tid * 16);       \
    gload16(bS + k0_, lds + (bf) * 16384 + 8192 + tid * 16);                \
    gload16(bS + 262144 + k0_, lds + (bf) * 16384 + 12288 + tid * 16);      \
  }

  STAGE2(0, 0); STAGE2(1, 1); STAGE2(2, 2);

  for (int kt = 0; kt < 128; ++kt) {
    if (kt < 126) WAITV(8);
    else if (kt == 126) WAITV(4);
    else WAITV(0);
    BARRIER();
    if (kt + 3 < 128) STAGE2(kt + 3, (kt + 3) & 3);
    const char* aT = lds + (kt & 3) * 16384;
    const char* bT = aT + 8192;
    bf16x8 af[4], bfr[4];
#pragma unroll
    for (int mi = 0; mi < 4; ++mi)
      af[mi] = *(const bf16x8*)(aT + (wm * 64 + mi * 16 + r16) * 64 + sw);
#pragma unroll
    for (int ni = 0; ni < 4; ++ni)
      bfr[ni] = *(const bf16x8*)(bT + (wn * 64 + ni * 16 + r16) * 64 + sw);
    __builtin_amdgcn_s_setprio(1);
#pragma unroll
    for (int mi = 0; mi < 4; ++mi)
#pragma unroll
      for (int ni = 0; ni < 4; ++ni)
        acc[mi][ni] = __builtin_amdgcn_mfma_f32_16x16x32_bf16(af[mi], bfr[ni], acc[mi][ni], 0, 0, 0);
    __builtin_amdgcn_s_setprio(0);
  }
#undef STAGE2

#pragma unroll
  for (int i = 0; i < 4; ++i)
#pragma unroll
    for (int j = 0; j < 4; ++j) {
      int row = m0 + wm * 64 + i * 16 + g4 * 4;   // kk
      int col = n0 + wn * 64 + j * 16 + r16;      // c
#pragma unroll
      for (int q = 0; q < 4; ++q)
        outp[((size_t)(b * 1024) + row + q) * 1024 + col] = f2bf(acc[i][j][q]);
    }
}

// ---------------- kp/vp GEMM: kp = (0.125*log2e)*(xEk@Wk + sE*bk); vpt transposed ----
__global__ __launch_bounds__(256, 2) void k_kpvp(const short* __restrict__ xEk,
                                                 const short* __restrict__ xEv,
                                                 const short* __restrict__ WaT,
                                                 const float* __restrict__ b_attn,
                                                 const float* __restrict__ sE,
                                                 const float* __restrict__ sF,
                                                 short* __restrict__ kp,
                                                 short* __restrict__ vpt) {
  const int which = blockIdx.z;
  const short* __restrict__ A = which ? xEv : xEk;
  const short* __restrict__ BT = WaT + (size_t)(1024 + which * 1024) * 1024;
  const float* __restrict__ bias = b_attn + 1024 + which * 1024;
  const float* __restrict__ rs = which ? sF : sE;
  __shared__ __align__(16) char lds[4 * 16384];
  const int tid = threadIdx.x, l = tid & 63, wv = tid >> 6;
  const int wm = wv >> 1, wn = wv & 1;
  const int r16 = l & 15, g4 = l >> 4;
  const int m0 = blockIdx.x * 128, n0 = blockIdx.y * 128;
  const int sl = (tid & 3) ^ ((tid >> 3) & 3);
  const short* aS = A + (size_t)(m0 + (tid >> 2)) * 1024 + sl * 8;
  const short* bS = BT + (size_t)(n0 + (tid >> 2)) * 1024 + sl * 8;
  const int sw = (g4 ^ ((r16 >> 1) & 3)) * 16;

  f32x4 acc[4][4];
#pragma unroll
  for (int i = 0; i < 4; ++i)
#pragma unroll
    for (int j = 0; j < 4; ++j) acc[i][j] = f32x4{0.f, 0.f, 0.f, 0.f};

#define STAGEP(kt, bf)                                                      \
  {                                                                         \
    const int k0_ = (kt) * 32;                                              \
    gload16(aS + k0_, lds + (bf) * 16384 + tid * 16);                       \
    gload16(aS + 65536 + k0_, lds + (bf) * 16384 + 4096 + tid * 16);        \
    gload16(bS + k0_, lds + (bf) * 16384 + 8192 + tid * 16);                \
    gload16(bS + 65536 + k0_, lds + (bf) * 16384 + 12288 + tid * 16);       \
  }

  STAGEP(0, 0); STAGEP(1, 1); STAGEP(2, 2);

  for (int kt = 0; kt < 32; ++kt) {
    if (kt < 30) WAITV(8);
    else if (kt == 30) WAITV(4);
    else WAITV(0);
    BARRIER();
    if (kt + 3 < 32) STAGEP(kt + 3, (kt + 3) & 3);
    const char* aT = lds + (kt & 3) * 16384;
    const char* bT = aT + 8192;
    bf16x8 af[4], bfr[4];
#pragma unroll
    for (int mi = 0; mi < 4; ++mi)
      af[mi] = *(const bf16x8*)(aT + (wm * 64 + mi * 16 + r16) * 64 + sw);
#pragma unroll
    for (int ni = 0; ni < 4; ++ni)
      bfr[ni] = *(const bf16x8*)(bT + (wn * 64 + ni * 16 + r16) * 64 + sw);
    __builtin_amdgcn_s_setprio(1);
#pragma unroll
    for (int mi = 0; mi < 4; ++mi)
#pragma unroll
      for (int ni = 0; ni < 4; ++ni)
        acc[mi][ni] = __builtin_amdgcn_mfma_f32_16x16x32_bf16(af[mi], bfr[ni], acc[mi][ni], 0, 0, 0);
    __builtin_amdgcn_s_setprio(0);
  }
#undef STAGEP

  if (which) {
    // vpt[b][col][kk] = acc + sF[kk]*bv[col]  (transposed store)
#pragma unroll
    for (int i = 0; i < 4; ++i)
#pragma unroll
      for (int j = 0; j < 4; ++j) {
        int row = m0 + wm * 64 + i * 16 + g4 * 4;   // global (b,kk) row
        int col = n0 + wn * 64 + j * 16 + r16;
        int bb = row >> 10;
        float bv = bias[col];
        bf16x4 ov;
#pragma unroll
        for (int q = 0; q < 4; ++q)
          ov[q] = f2bf(acc[i][j][q] + rs[(row + q) & 1023] * bv);
        *reinterpret_cast<bf16x4*>(
            &vpt[(((size_t)bb << 10) + col) * 1024 + (row & 1023)]) = ov;
      }
  } else {
    // kp[row][col] = 0.125*log2e*(acc + sE[kk]*bk[col])  -> S arrives in exp2 domain
    const float KSCALE = 0.125f * 1.4426950408889634f;
#pragma unroll
    for (int i = 0; i < 4; ++i)
#pragma unroll
      for (int j = 0; j < 4; ++j) {
        int row = m0 + wm * 64 + i * 16 + g4 * 4;
        int col = n0 + wn * 64 + j * 16 + r16;
        float bv = bias[col];
#pragma unroll
        for (int q = 0; q < 4; ++q)
          kp[(size_t)(row + q) * 1024 + col] =
              f2bf((acc[i][j][q] + rs[(row + q) & 1023] * bv) * KSCALE);
      }
  }
}

// ---------------- Flash attention: swapped 32x32x16, no-max exp2 softmax,
//                  T14 async stage split; 4 blocks/CU ----------
__global__ __launch_bounds__(256, 4) void k_attn(const short* __restrict__ qb,
                                                 const short* __restrict__ kp,
                                                 const short* __restrict__ vpt,
                                                 short* __restrict__ y) {
  __shared__ __align__(16) char KsB[128 * 128];   // [kk][d] swizzled, 16 KB
  __shared__ __align__(16) char VtB[64 * 256];    // [d][kk] swizzled, 16 KB
  const int tid = threadIdx.x, lane = tid & 63, w = tid >> 6;
  const int r32 = lane & 31, hi = lane >> 5;
  const int iblk = 31 - blockIdx.x;     // heavy blocks first
  const int bh = blockIdx.y, b = bh >> 4, h = bh & 15;
  const int t0 = iblk * 128;
  const int tl = w * 32 + r32;          // local row
  const int T = t0 + tl;                // global row (within b)

  bf16x8 qf[4];
#pragma unroll
  for (int kd = 0; kd < 4; ++kd)
    qf[kd] = *reinterpret_cast<const bf16x8*>(
        &qb[(size_t)(b * 4096 + T) * 1024 + h * 64 + kd * 16 + hi * 8]);

  f32x16 o[2];
#pragma unroll
  for (int i = 0; i < 16; ++i) { o[0][i] = 0.f; o[1][i] = 0.f; }
  float lrun = 0.f;

  const short* kpb = kp + ((size_t)b << 20) + h * 64;             // [kk][c]
  const short* vtb = vpt + (((size_t)b << 10) + h * 64) * 1024;   // [c][kk]

  const int kkl_ = tid >> 3, c8 = tid & 7;
  const int dl_ = tid >> 4, c16 = tid & 15;
  bf16x8 kreg[4], vreg[4];

#define LOADT(jt)                                                              \
  {                                                                            \
    const int kk0_ = (jt) * 128;                                               \
    _Pragma("unroll") for (int it = 0; it < 4; ++it) {                         \
      kreg[it] = *reinterpret_cast<const bf16x8*>(                             \
          &kpb[(size_t)(kk0_ + it * 32 + kkl_) * 1024 + c8 * 8]);              \
      vreg[it] = *reinterpret_cast<const bf16x8*>(                             \
          &vtb[(size_t)(it * 16 + dl_) * 1024 + kk0_ + c16 * 8]);              \
    }                                                                          \
  }

  LOADT(0);

  const int ntiles = (iblk + 1 < 8) ? (iblk + 1) : 8;
  for (int jt = 0; jt < ntiles; ++jt) {
    WAITV(0);        // prefetched regs valid
    BARRIER();       // all waves done reading previous tile's LDS
#pragma unroll
    for (int it = 0; it < 4; ++it) {
      int kk = it * 32 + kkl_;
      *reinterpret_cast<bf16x8*>(&KsB[kk * 128 + ((c8 * 16) ^ ((kk & 7) << 4))]) = kreg[it];
      int d = it * 16 + dl_;
      *reinterpret_cast<bf16x8*>(&VtB[d * 256 + ((c16 * 16) ^ ((d & 7) << 4))]) = vreg[it];
    }
    __syncthreads();                    // writes visible
    if (jt + 1 < ntiles) LOADT(jt + 1); // async: latency hides under compute below

#pragma unroll
    for (int st = 0; st < 2; ++st) {          // 64-kk sub-tiles
      f32x16 s[2];
#pragma unroll
      for (int i = 0; i < 16; ++i) { s[0][i] = 0.f; s[1][i] = 0.f; }
#pragma unroll
      for (int ni = 0; ni < 2; ++ni) {
        int row = (st * 2 + ni) * 32 + r32;
#pragma unroll
        for (int kd = 0; kd < 4; ++kd) {
          bf16x8 kf = *reinterpret_cast<const bf16x8*>(
              &KsB[row * 128 + ((kd * 32 + hi * 16) ^ ((row & 7) << 4))]);
          s[ni] = __builtin_amdgcn_mfma_f32_32x32x16_bf16(kf, qf[kd], s[ni], 0, 0, 0);
        }
      }

      if (jt == iblk) {  // causal mask on diagonal tile
#pragma unroll
        for (int ni = 0; ni < 2; ++ni)
#pragma unroll
          for (int j = 0; j < 16; ++j) {
            int kkl = (st * 2 + ni) * 32 + (j & 3) + 8 * (j >> 2) + 4 * hi;
            if (kkl > tl) s[ni][j] = -1e30f;
          }
      }

      // --- no-max softmax, exp2 domain (log2e folded into kp): P = exp2(S)
      float r0 = 0.f, r1 = 0.f, r2 = 0.f, r3 = 0.f;
#pragma unroll
      for (int j = 0; j < 16; j += 2) {
        float e0 = __builtin_amdgcn_exp2f(s[0][j]);
        float e1 = __builtin_amdgcn_exp2f(s[0][j + 1]);
        float e2 = __builtin_amdgcn_exp2f(s[1][j]);
        float e3 = __builtin_amdgcn_exp2f(s[1][j + 1]);
        s[0][j] = e0; s[0][j + 1] = e1; s[1][j] = e2; s[1][j + 1] = e3;
        r0 += e0; r1 += e1; r2 += e2; r3 += e3;
      }
      float rsum = (r0 + r1) + (r2 + r3);
      rsum += __shfl_xor(rsum, 32, 64);
      lrun += rsum;

      // --- pack P -> bf16 B-frags (cvtpk + permlane32_swap) and PV MFMA
#pragma unroll
      for (int kbl = 0; kbl < 4; ++kbl) {
        const int ni = kbl >> 1, jb = (kbl & 1) * 8;
        int lo0 = cvtpk(s[ni][jb + 0], s[ni][jb + 1]);
        int lo1 = cvtpk(s[ni][jb + 2], s[ni][jb + 3]);
        int hi0 = cvtpk(s[ni][jb + 4], s[ni][jb + 5]);
        int hi1 = cvtpk(s[ni][jb + 6], s[ni][jb + 7]);
        asm("v_permlane32_swap_b32 %0, %1" : "+v"(lo0), "+v"(hi0));
        asm("v_permlane32_swap_b32 %0, %1" : "+v"(lo1), "+v"(hi1));
        i32x4 pw; pw[0] = lo0; pw[1] = lo1; pw[2] = hi0; pw[3] = hi1;
        bf16x8 pf = __builtin_bit_cast(bf16x8, pw);
        const int kb = st * 4 + kbl;
#pragma unroll
        for (int mo = 0; mo < 2; ++mo) {
          int row = mo * 32 + r32;
          bf16x8 vf = *reinterpret_cast<const bf16x8*>(
              &VtB[row * 256 + ((kb * 32 + hi * 16) ^ ((row & 7) << 4))]);
          o[mo] = __builtin_amdgcn_mfma_f32_32x32x16_bf16(vf, pf, o[mo], 0, 0, 0);
        }
      }
    }
  }

  float inv = 1.0f / lrun;
#pragma unroll
  for (int mo = 0; mo < 2; ++mo)
#pragma unroll
    for (int rq = 0; rq < 4; ++rq) {
      bf16x4 ov;
#pragma unroll
      for (int c = 0; c < 4; ++c) ov[c] = f2bf(o[mo][rq * 4 + c] * inv);
      *reinterpret_cast<bf16x4*>(
          &y[(size_t)(b * 4096 + T) * 1024 + h * 64 + mo * 32 + rq * 8 + hi * 4]) = ov;
    }
#undef LOADT
}

// ---------------- GEMM2: out = y @ W_proj + b (128x128, BK=32, quad-buffered) --------
__global__ __launch_bounds__(256, 2) void k_gemm_out(const short* __restrict__ A,
                                                     const short* __restrict__ BT,
                                                     const float* __restrict__ bias,
                                                     float* __restrict__ C) {
  __shared__ __align__(16) char lds[4 * 16384];
  const int tid = threadIdx.x, l = tid & 63, wv = tid >> 6;
  const int wm = wv >> 1, wn = wv & 1;
  const int r16 = l & 15, g4 = l >> 4;
  const int m0 = blockIdx.x * 128, n0 = blockIdx.y * 128;
  const int sl = (tid & 3) ^ ((tid >> 3) & 3);
  const short* aS = A + (size_t)(m0 + (tid >> 2)) * 1024 + sl * 8;
  const short* bS = BT + (size_t)(n0 + (tid >> 2)) * 1024 + sl * 8;
  const int sw = (g4 ^ ((r16 >> 1) & 3)) * 16;

  f32x4 acc[4][4];
#pragma unroll
  for (int i = 0; i < 4; ++i)
#pragma unroll
    for (int j = 0; j < 4; ++j) acc[i][j] = f32x4{0.f, 0.f, 0.f, 0.f};

#define STAGE3(kt, bf)                                                      \
  {                                                                         \
    const int k0_ = (kt) * 32;                                              \
    gload16(aS + k0_, lds + (bf) * 16384 + tid * 16);                       \
    gload16(aS + 65536 + k0_, lds + (bf) * 16384 + 4096 + tid * 16);        \
    gload16(bS + k0_, lds + (bf) * 16384 + 8192 + tid * 16);                \
    gload16(bS + 65536 + k0_, lds + (bf) * 16384 + 12288 + tid * 16);       \
  }

  STAGE3(0, 0); STAGE3(1, 1); STAGE3(2, 2);

  for (int kt = 0; kt < 32; ++kt) {
    if (kt < 30) WAITV(8);
    else if (kt == 30) WAITV(4);
    else WAITV(0);
    BARRIER();
    if (kt + 3 < 32) STAGE3(kt + 3, (kt + 3) & 3);
    const char* aT = lds + (kt & 3) * 16384;
    const char* bT = aT + 8192;
    bf16x8 af[4], bfr[4];
#pragma unroll
    for (int mi = 0; mi < 4; ++mi)
      af[mi] = *(const bf16x8*)(aT + (wm * 64 + mi * 16 + r16) * 64 + sw);
#pragma unroll
    for (int ni = 0; ni < 4; ++ni)
      bfr[ni] = *(const bf16x8*)(bT + (wn * 64 + ni * 16 + r16) * 64 + sw);
    __builtin_amdgcn_s_setprio(1);
#pragma unroll
    for (int mi = 0; mi < 4; ++mi)
#pragma unroll
      for (int ni = 0; ni < 4; ++ni)
        acc[mi][ni] = __builtin_amdgcn_mfma_f32_16x16x32_bf16(af[mi], bfr[ni], acc[mi][ni], 0, 0, 0);
    __builtin_amdgcn_s_setprio(0);
  }
#undef STAGE3

#pragma unroll
  for (int i = 0; i < 4; ++i)
#pragma unroll
    for (int j = 0; j < 4; ++j) {
      int row = m0 + wm * 64 + i * 16 + g4 * 4;
      int col = n0 + wn * 64 + j * 16 + r16;
      float bv = bias[col];
#pragma unroll
      for (int q = 0; q < 4; ++q)
        C[(size_t)(row + q) * 1024 + col] = acc[i][j][q] + bv;
    }
}

extern "C" void kernel_launch(void* const* d_in, const int* in_sizes, int n_in,
                              void* d_out, int out_size, void* d_ws, size_t ws_size,
                              hipStream_t stream) {
  const float* x      = (const float*)d_in[0];
  const float* W_attn = (const float*)d_in[1];
  const float* b_attn = (const float*)d_in[2];
  const float* W_proj = (const float*)d_in[3];
  const float* b_proj = (const float*)d_in[4];
  const float* E      = (const float*)d_in[5];
  const float* F      = (const float*)d_in[6];
  float* out = (float*)d_out;

  char* ws = (char*)d_ws;
  short* xb  = (short*)(ws + 0);          //  32 MB: x bf16            (16384x1024)
  short* WaT = (short*)(ws + 33554432);   //   6 MB: W_attn^T bf16     (3072x1024)
  short* WpT = (short*)(ws + 39845888);   //   2 MB: W_proj^T bf16     (1024x1024)
  short* Et  = (short*)(ws + 41943040);   //   8 MB: E^T bf16          (1024x4096)
  short* Ft  = (short*)(ws + 50331648);   //   8 MB: F^T bf16          (1024x4096)
  short* qb  = (short*)(ws + 58720256);   //  32 MB: q bf16            (16384x1024)
  short* xTb = (short*)(ws + 92274688);   //  32 MB: x^T bf16          (4x1024x4096)
  short* xEk = (short*)(ws + 125829120);  //   8 MB: E^T@x bf16        (4x1024x1024)
  short* xEv = (short*)(ws + 134217728);  //   8 MB: F^T@x bf16        (4x1024x1024)
  short* kp  = (short*)(ws + 142606336);  //   8 MB: k_proj bf16       (4x1024x1024)
  short* vpt = (short*)(ws + 150994944);  //   8 MB: v_proj^T bf16     (4x1024x1024)
  short* yb  = (short*)(ws + 159383552);  //  32 MB: attn out bf16     (16384x1024)
  float* sE  = (float*)(ws + 192937984);  //   4 KB: colsum(E)
  float* sF  = (float*)(ws + 192942080);  //   4 KB: colsum(F)
  float* part= (float*)(ws + 192946176);  // 512 KB: colsum partials (2x64x1024)

  k_convert<<<16384, 256, 0, stream>>>(x, xb, 16777216);
  k_transpose_cvt<<<dim3(96, 32), 256, 0, stream>>>(W_attn, WaT, 1024, 3072);
  k_transpose_cvt<<<dim3(32, 32), 256, 0, stream>>>(W_proj, WpT, 1024, 1024);
  k_transpose_cvt<<<dim3(32, 128), 256, 0, stream>>>(E, Et, 4096, 1024);
  k_transpose_cvt<<<dim3(32, 128), 256, 0, stream>>>(F, Ft, 4096, 1024);
  for (int b = 0; b < 4; ++b)
    k_transpose_cvt<<<dim3(32, 128), 256, 0, stream>>>(
        x + (size_t)b * 4096 * 1024, xTb + (size_t)b * 1024 * 4096, 4096, 1024);
  k_colsum1<<<dim3(4, 64, 2), 256, 0, stream>>>(E, F, part);
  k_colsum2<<<8, 256, 0, stream>>>(part, sE, sF);

  k_gemm_q<<<256, 512, 0, stream>>>(xb, WaT, b_attn, qb);
  k_proj<<<dim3(8, 8, 8), 256, 0, stream>>>(Et, Ft, xTb, xEk, xEv);
  k_kpvp<<<dim3(32, 8, 2), 256, 0, stream>>>(xEk, xEv, WaT, b_attn, sE, sF, kp, vpt);
  k_attn<<<dim3(32, 64), 256, 0, stream>>>(qb, kp, vpt, yb);
  k_gemm_out<<<dim3(128, 8), 256, 0, stream>>>(yb, WpT, b_proj, out);
}

// Round 15
// 366.097 us; speedup vs baseline: 1.1461x; 1.1461x over previous
//
#include <hip/hip_runtime.h>
#include <stdint.h>

typedef short bf16x8 __attribute__((ext_vector_type(8)));
typedef short bf16x4 __attribute__((ext_vector_type(4)));
typedef float f32x4 __attribute__((ext_vector_type(4)));
typedef float f32x16 __attribute__((ext_vector_type(16)));
typedef int i32x4 __attribute__((ext_vector_type(4)));

__device__ __forceinline__ short f2bf(float f) {
  union { float f; uint32_t u; } v; v.f = f;
  uint32_t r = (v.u + 0x7FFFu + ((v.u >> 16) & 1u)) >> 16;
  return (short)(uint16_t)r;
}

__device__ __forceinline__ int cvtpk(float lo, float hi) {
  int r;
  asm("v_cvt_pk_bf16_f32 %0, %1, %2" : "=v"(r) : "v"(lo), "v"(hi));
  return r;
}

// async global->LDS, 16B per lane; LDS dest must be linear in lane order
__device__ __forceinline__ void gload16(const void* g, void* l) {
  __builtin_amdgcn_global_load_lds(
      (const __attribute__((address_space(1))) unsigned int*)g,
      (__attribute__((address_space(3))) unsigned int*)l, 16, 0, 0);
}

#define WAITV(n) asm volatile("s_waitcnt vmcnt(" #n ")" ::: "memory")
#define BARRIER()                          \
  do {                                     \
    __builtin_amdgcn_s_barrier();          \
    asm volatile("" ::: "memory");         \
  } while (0)

// ---------------- elementwise f32 -> bf16 ----------------
__global__ __launch_bounds__(256) void k_convert(const float* __restrict__ in,
                                                 short* __restrict__ out, int n) {
  int i = (blockIdx.x * 256 + threadIdx.x) * 4;
  if (i >= n) return;
  float4 v = *reinterpret_cast<const float4*>(in + i);
  bf16x4 o; o[0] = f2bf(v.x); o[1] = f2bf(v.y); o[2] = f2bf(v.z); o[3] = f2bf(v.w);
  *reinterpret_cast<bf16x4*>(out + i) = o;
}

// ---------------- transpose + convert: out[C][R] = bf16(in[R][C]) ----------------
__global__ __launch_bounds__(256) void k_transpose_cvt(const float* __restrict__ in,
                                                       short* __restrict__ out,
                                                       int R, int C) {
  __shared__ float tile[32][33];
  int r0 = blockIdx.y * 32, c0 = blockIdx.x * 32;
  int tx = threadIdx.x & 31, ty = threadIdx.x >> 5;
#pragma unroll
  for (int j = 0; j < 4; ++j)
    tile[ty + j * 8][tx] = in[(size_t)(r0 + ty + j * 8) * C + c0 + tx];
  __syncthreads();
#pragma unroll
  for (int j = 0; j < 4; ++j)
    out[(size_t)(c0 + ty + j * 8) * R + r0 + tx] = f2bf(tile[tx][ty + j * 8]);
}

// ---------------- column sums, two-stage deterministic reduction ----------------
__global__ __launch_bounds__(256) void k_colsum1(const float* __restrict__ E,
                                                 const float* __restrict__ F,
                                                 float* __restrict__ partial) {
  const int c = blockIdx.x * 256 + threadIdx.x;
  const int tc = blockIdx.y, which = blockIdx.z;
  const float* src = (which ? F : E) + (size_t)(tc * 64) * 1024 + c;
  float s = 0.f;
#pragma unroll 8
  for (int t = 0; t < 64; ++t) s += src[(size_t)t * 1024];
  partial[((size_t)which * 64 + tc) * 1024 + c] = s;
}

__global__ __launch_bounds__(256) void k_colsum2(const float* __restrict__ partial,
                                                 float* __restrict__ sE,
                                                 float* __restrict__ sF) {
  const int bid = blockIdx.x;
  const int which = bid >> 2, c = (bid & 3) * 256 + threadIdx.x;
  const float* p = partial + (size_t)which * 64 * 1024 + c;
  float s = 0.f;
#pragma unroll 8
  for (int t = 0; t < 64; ++t) s += p[(size_t)t * 1024];
  (which ? sF : sE)[c] = s;
}

// ---------------- GEMM_q: qb = x @ Wq + bq  (256x256, BK=32, quad-buffered) ----------
__global__ __launch_bounds__(512, 2) void k_gemm_q(const short* __restrict__ A,
                                                   const short* __restrict__ BT,
                                                   const float* __restrict__ bias,
                                                   short* __restrict__ qb) {
  __shared__ __align__(16) char lds[4 * 32768];
  const int tid = threadIdx.x, l = tid & 63, wv = tid >> 6;
  const int wm = wv >> 2, wn = wv & 3;
  const int r16 = l & 15, g4 = l >> 4;
  const int orig = blockIdx.x;
  const int xcd = orig & 7, loc = orig >> 3;
  const int m0 = (xcd * 8 + (loc & 7)) * 256, n0 = (loc >> 3) * 256;
  const int sl = (tid & 3) ^ ((tid >> 3) & 3);
  const short* aS = A + (size_t)(m0 + (tid >> 2)) * 1024 + sl * 8;
  const short* bS = BT + (size_t)(n0 + (tid >> 2)) * 1024 + sl * 8;
  const int sw = (g4 ^ ((r16 >> 1) & 3)) * 16;

  f32x4 acc[8][4];
#pragma unroll
  for (int i = 0; i < 8; ++i)
#pragma unroll
    for (int j = 0; j < 4; ++j) acc[i][j] = f32x4{0.f, 0.f, 0.f, 0.f};

#define STAGEQ(kt, bf)                                                      \
  {                                                                         \
    const int k0_ = (kt) * 32;                                              \
    gload16(aS + k0_, lds + (bf) * 32768 + tid * 16);                       \
    gload16(aS + 131072 + k0_, lds + (bf) * 32768 + 8192 + tid * 16);       \
    gload16(bS + k0_, lds + (bf) * 32768 + 16384 + tid * 16);               \
    gload16(bS + 131072 + k0_, lds + (bf) * 32768 + 24576 + tid * 16);      \
  }

  STAGEQ(0, 0); STAGEQ(1, 1); STAGEQ(2, 2);

  for (int kt = 0; kt < 32; ++kt) {
    if (kt < 30) WAITV(8);
    else if (kt == 30) WAITV(4);
    else WAITV(0);
    BARRIER();
    if (kt + 3 < 32) STAGEQ(kt + 3, (kt + 3) & 3);
    const char* aT = lds + (kt & 3) * 32768;
    const char* bT = aT + 16384;
    bf16x8 af[8], bfr[4];
#pragma unroll
    for (int mi = 0; mi < 8; ++mi)
      af[mi] = *(const bf16x8*)(aT + (wm * 128 + mi * 16 + r16) * 64 + sw);
#pragma unroll
    for (int ni = 0; ni < 4; ++ni)
      bfr[ni] = *(const bf16x8*)(bT + (wn * 64 + ni * 16 + r16) * 64 + sw);
    __builtin_amdgcn_s_setprio(1);
#pragma unroll
    for (int mi = 0; mi < 8; ++mi)
#pragma unroll
      for (int ni = 0; ni < 4; ++ni)
        acc[mi][ni] = __builtin_amdgcn_mfma_f32_16x16x32_bf16(af[mi], bfr[ni], acc[mi][ni], 0, 0, 0);
    __builtin_amdgcn_s_setprio(0);
  }
#undef STAGEQ

#pragma unroll
  for (int i = 0; i < 8; ++i)
#pragma unroll
    for (int j = 0; j < 4; ++j) {
      int row = m0 + wm * 128 + i * 16 + g4 * 4;
      int col = n0 + wn * 64 + j * 16 + r16;
      float bv = bias[col];
#pragma unroll
      for (int q = 0; q < 4; ++q)
        qb[(size_t)(row + q) * 1024 + col] = f2bf(acc[i][j][q] + bv);
    }
}

// ---------------- xE GEMM (128x128, BK=32, quad-buffered, K=4096) ----------------
__global__ __launch_bounds__(256, 2) void k_proj(const short* __restrict__ Et,
                                                 const short* __restrict__ Ft,
                                                 const short* __restrict__ xT,
                                                 short* __restrict__ xEk,
                                                 short* __restrict__ xEv) {
  const int z = blockIdx.z, b = z >> 1, which = z & 1;
  const short* __restrict__ AT = which ? Ft : Et;
  const short* __restrict__ BTp = xT + ((size_t)b << 10) * 4096;
  short* __restrict__ outp = which ? xEv : xEk;
  __shared__ __align__(16) char lds[4 * 16384];
  const int tid = threadIdx.x, l = tid & 63, wv = tid >> 6;
  const int wm = wv >> 1, wn = wv & 1;
  const int r16 = l & 15, g4 = l >> 4;
  const int m0 = blockIdx.x * 128, n0 = blockIdx.y * 128;
  const int sl = (tid & 3) ^ ((tid >> 3) & 3);
  const short* aS = AT + (size_t)(m0 + (tid >> 2)) * 4096 + sl * 8;
  const short* bS = BTp + (size_t)(n0 + (tid >> 2)) * 4096 + sl * 8;
  const int sw = (g4 ^ ((r16 >> 1) & 3)) * 16;

  f32x4 acc[4][4];
#pragma unroll
  for (int i = 0; i < 4; ++i)
#pragma unroll
    for (int j = 0; j < 4; ++j) acc[i][j] = f32x4{0.f, 0.f, 0.f, 0.f};

#define STAGE2(kt, bf)                                                      \
  {                                                                         \
    const int k0_ = (kt) * 32;                                              \
    gload16(aS + k0_, lds + (bf) * 16384 + tid * 16);                       \
    gload16(aS + 262144 + k0_, lds + (bf) * 16384 + 4096 + tid * 16);       \
    gload16(bS + k0_, lds + (bf) * 16384 + 8192 + tid * 16);                \
    gload16(bS + 262144 + k0_, lds + (bf) * 16384 + 12288 + tid * 16);      \
  }

  STAGE2(0, 0); STAGE2(1, 1); STAGE2(2, 2);

  for (int kt = 0; kt < 128; ++kt) {
    if (kt < 126) WAITV(8);
    else if (kt == 126) WAITV(4);
    else WAITV(0);
    BARRIER();
    if (kt + 3 < 128) STAGE2(kt + 3, (kt + 3) & 3);
    const char* aT = lds + (kt & 3) * 16384;
    const char* bT = aT + 8192;
    bf16x8 af[4], bfr[4];
#pragma unroll
    for (int mi = 0; mi < 4; ++mi)
      af[mi] = *(const bf16x8*)(aT + (wm * 64 + mi * 16 + r16) * 64 + sw);
#pragma unroll
    for (int ni = 0; ni < 4; ++ni)
      bfr[ni] = *(const bf16x8*)(bT + (wn * 64 + ni * 16 + r16) * 64 + sw);
    __builtin_amdgcn_s_setprio(1);
#pragma unroll
    for (int mi = 0; mi < 4; ++mi)
#pragma unroll
      for (int ni = 0; ni < 4; ++ni)
        acc[mi][ni] = __builtin_amdgcn_mfma_f32_16x16x32_bf16(af[mi], bfr[ni], acc[mi][ni], 0, 0, 0);
    __builtin_amdgcn_s_setprio(0);
  }
#undef STAGE2

#pragma unroll
  for (int i = 0; i < 4; ++i)
#pragma unroll
    for (int j = 0; j < 4; ++j) {
      int row = m0 + wm * 64 + i * 16 + g4 * 4;   // kk
      int col = n0 + wn * 64 + j * 16 + r16;      // c
#pragma unroll
      for (int q = 0; q < 4; ++q)
        outp[((size_t)(b * 1024) + row + q) * 1024 + col] = f2bf(acc[i][j][q]);
    }
}

// ---------------- kp/vp GEMM: kp = (0.125*log2e)*(xEk@Wk + sE*bk); vpt transposed ----
__global__ __launch_bounds__(256, 2) void k_kpvp(const short* __restrict__ xEk,
                                                 const short* __restrict__ xEv,
                                                 const short* __restrict__ WaT,
                                                 const float* __restrict__ b_attn,
                                                 const float* __restrict__ sE,
                                                 const float* __restrict__ sF,
                                                 short* __restrict__ kp,
                                                 short* __restrict__ vpt) {
  const int which = blockIdx.z;
  const short* __restrict__ A = which ? xEv : xEk;
  const short* __restrict__ BT = WaT + (size_t)(1024 + which * 1024) * 1024;
  const float* __restrict__ bias = b_attn + 1024 + which * 1024;
  const float* __restrict__ rs = which ? sF : sE;
  __shared__ __align__(16) char lds[4 * 16384];
  const int tid = threadIdx.x, l = tid & 63, wv = tid >> 6;
  const int wm = wv >> 1, wn = wv & 1;
  const int r16 = l & 15, g4 = l >> 4;
  const int m0 = blockIdx.x * 128, n0 = blockIdx.y * 128;
  const int sl = (tid & 3) ^ ((tid >> 3) & 3);
  const short* aS = A + (size_t)(m0 + (tid >> 2)) * 1024 + sl * 8;
  const short* bS = BT + (size_t)(n0 + (tid >> 2)) * 1024 + sl * 8;
  const int sw = (g4 ^ ((r16 >> 1) & 3)) * 16;

  f32x4 acc[4][4];
#pragma unroll
  for (int i = 0; i < 4; ++i)
#pragma unroll
    for (int j = 0; j < 4; ++j) acc[i][j] = f32x4{0.f, 0.f, 0.f, 0.f};

#define STAGEP(kt, bf)                                                      \
  {                                                                         \
    const int k0_ = (kt) * 32;                                              \
    gload16(aS + k0_, lds + (bf) * 16384 + tid * 16);                       \
    gload16(aS + 65536 + k0_, lds + (bf) * 16384 + 4096 + tid * 16);        \
    gload16(bS + k0_, lds + (bf) * 16384 + 8192 + tid * 16);                \
    gload16(bS + 65536 + k0_, lds + (bf) * 16384 + 12288 + tid * 16);       \
  }

  STAGEP(0, 0); STAGEP(1, 1); STAGEP(2, 2);

  for (int kt = 0; kt < 32; ++kt) {
    if (kt < 30) WAITV(8);
    else if (kt == 30) WAITV(4);
    else WAITV(0);
    BARRIER();
    if (kt + 3 < 32) STAGEP(kt + 3, (kt + 3) & 3);
    const char* aT = lds + (kt & 3) * 16384;
    const char* bT = aT + 8192;
    bf16x8 af[4], bfr[4];
#pragma unroll
    for (int mi = 0; mi < 4; ++mi)
      af[mi] = *(const bf16x8*)(aT + (wm * 64 + mi * 16 + r16) * 64 + sw);
#pragma unroll
    for (int ni = 0; ni < 4; ++ni)
      bfr[ni] = *(const bf16x8*)(bT + (wn * 64 + ni * 16 + r16) * 64 + sw);
    __builtin_amdgcn_s_setprio(1);
#pragma unroll
    for (int mi = 0; mi < 4; ++mi)
#pragma unroll
      for (int ni = 0; ni < 4; ++ni)
        acc[mi][ni] = __builtin_amdgcn_mfma_f32_16x16x32_bf16(af[mi], bfr[ni], acc[mi][ni], 0, 0, 0);
    __builtin_amdgcn_s_setprio(0);
  }
#undef STAGEP

  if (which) {
    // vpt[b][col][kk] = acc + sF[kk]*bv[col]  (transposed store)
#pragma unroll
    for (int i = 0; i < 4; ++i)
#pragma unroll
      for (int j = 0; j < 4; ++j) {
        int row = m0 + wm * 64 + i * 16 + g4 * 4;   // global (b,kk) row
        int col = n0 + wn * 64 + j * 16 + r16;
        int bb = row >> 10;
        float bv = bias[col];
        bf16x4 ov;
#pragma unroll
        for (int q = 0; q < 4; ++q)
          ov[q] = f2bf(acc[i][j][q] + rs[(row + q) & 1023] * bv);
        *reinterpret_cast<bf16x4*>(
            &vpt[(((size_t)bb << 10) + col) * 1024 + (row & 1023)]) = ov;
      }
  } else {
    // kp[row][col] = 0.125*log2e*(acc + sE[kk]*bk[col])  -> S arrives in exp2 domain
    const float KSCALE = 0.125f * 1.4426950408889634f;
#pragma unroll
    for (int i = 0; i < 4; ++i)
#pragma unroll
      for (int j = 0; j < 4; ++j) {
        int row = m0 + wm * 64 + i * 16 + g4 * 4;
        int col = n0 + wn * 64 + j * 16 + r16;
        float bv = bias[col];
#pragma unroll
        for (int q = 0; q < 4; ++q)
          kp[(size_t)(row + q) * 1024 + col] =
              f2bf((acc[i][j][q] + rs[(row + q) & 1023] * bv) * KSCALE);
      }
  }
}

// ---------------- Flash attention: swapped 32x32x16, no-max exp2 softmax,
//                  T14 async stage split; 3 blocks/CU (76 VGPR, no spills) ----------
__global__ __launch_bounds__(256, 3) void k_attn(const short* __restrict__ qb,
                                                 const short* __restrict__ kp,
                                                 const short* __restrict__ vpt,
                                                 short* __restrict__ y) {
  __shared__ __align__(16) char KsB[128 * 128];   // [kk][d] swizzled, 16 KB
  __shared__ __align__(16) char VtB[64 * 256];    // [d][kk] swizzled, 16 KB
  const int tid = threadIdx.x, lane = tid & 63, w = tid >> 6;
  const int r32 = lane & 31, hi = lane >> 5;
  const int iblk = 31 - blockIdx.x;     // heavy blocks first
  const int bh = blockIdx.y, b = bh >> 4, h = bh & 15;
  const int t0 = iblk * 128;
  const int tl = w * 32 + r32;          // local row
  const int T = t0 + tl;                // global row (within b)

  bf16x8 qf[4];
#pragma unroll
  for (int kd = 0; kd < 4; ++kd)
    qf[kd] = *reinterpret_cast<const bf16x8*>(
        &qb[(size_t)(b * 4096 + T) * 1024 + h * 64 + kd * 16 + hi * 8]);

  f32x16 o[2];
#pragma unroll
  for (int i = 0; i < 16; ++i) { o[0][i] = 0.f; o[1][i] = 0.f; }
  float lrun = 0.f;

  const short* kpb = kp + ((size_t)b << 20) + h * 64;             // [kk][c]
  const short* vtb = vpt + (((size_t)b << 10) + h * 64) * 1024;   // [c][kk]

  const int kkl_ = tid >> 3, c8 = tid & 7;
  const int dl_ = tid >> 4, c16 = tid & 15;
  bf16x8 kreg[4], vreg[4];

#define LOADT(jt)                                                              \
  {                                                                            \
    const int kk0_ = (jt) * 128;                                               \
    _Pragma("unroll") for (int it = 0; it < 4; ++it) {                         \
      kreg[it] = *reinterpret_cast<const bf16x8*>(                             \
          &kpb[(size_t)(kk0_ + it * 32 + kkl_) * 1024 + c8 * 8]);              \
      vreg[it] = *reinterpret_cast<const bf16x8*>(                             \
          &vtb[(size_t)(it * 16 + dl_) * 1024 + kk0_ + c16 * 8]);              \
    }                                                                          \
  }

  LOADT(0);

  const int ntiles = (iblk + 1 < 8) ? (iblk + 1) : 8;
  for (int jt = 0; jt < ntiles; ++jt) {
    WAITV(0);        // prefetched regs valid
    BARRIER();       // all waves done reading previous tile's LDS
#pragma unroll
    for (int it = 0; it < 4; ++it) {
      int kk = it * 32 + kkl_;
      *reinterpret_cast<bf16x8*>(&KsB[kk * 128 + ((c8 * 16) ^ ((kk & 7) << 4))]) = kreg[it];
      int d = it * 16 + dl_;
      *reinterpret_cast<bf16x8*>(&VtB[d * 256 + ((c16 * 16) ^ ((d & 7) << 4))]) = vreg[it];
    }
    __syncthreads();                    // writes visible
    if (jt + 1 < ntiles) LOADT(jt + 1); // async: latency hides under compute below

#pragma unroll
    for (int st = 0; st < 2; ++st) {          // 64-kk sub-tiles
      f32x16 s[2];
#pragma unroll
      for (int i = 0; i < 16; ++i) { s[0][i] = 0.f; s[1][i] = 0.f; }
#pragma unroll
      for (int ni = 0; ni < 2; ++ni) {
        int row = (st * 2 + ni) * 32 + r32;
#pragma unroll
        for (int kd = 0; kd < 4; ++kd) {
          bf16x8 kf = *reinterpret_cast<const bf16x8*>(
              &KsB[row * 128 + ((kd * 32 + hi * 16) ^ ((row & 7) << 4))]);
          s[ni] = __builtin_amdgcn_mfma_f32_32x32x16_bf16(kf, qf[kd], s[ni], 0, 0, 0);
        }
      }

      if (jt == iblk) {  // causal mask on diagonal tile
#pragma unroll
        for (int ni = 0; ni < 2; ++ni)
#pragma unroll
          for (int j = 0; j < 16; ++j) {
            int kkl = (st * 2 + ni) * 32 + (j & 3) + 8 * (j >> 2) + 4 * hi;
            if (kkl > tl) s[ni][j] = -1e30f;
          }
      }

      // --- no-max softmax, exp2 domain (log2e folded into kp): P = exp2(S)
      float r0 = 0.f, r1 = 0.f, r2 = 0.f, r3 = 0.f;
#pragma unroll
      for (int j = 0; j < 16; j += 2) {
        float e0 = __builtin_amdgcn_exp2f(s[0][j]);
        float e1 = __builtin_amdgcn_exp2f(s[0][j + 1]);
        float e2 = __builtin_amdgcn_exp2f(s[1][j]);
        float e3 = __builtin_amdgcn_exp2f(s[1][j + 1]);
        s[0][j] = e0; s[0][j + 1] = e1; s[1][j] = e2; s[1][j + 1] = e3;
        r0 += e0; r1 += e1; r2 += e2; r3 += e3;
      }
      float rsum = (r0 + r1) + (r2 + r3);
      rsum += __shfl_xor(rsum, 32, 64);
      lrun += rsum;

      // --- pack P -> bf16 B-frags (cvtpk + permlane32_swap) and PV MFMA
#pragma unroll
      for (int kbl = 0; kbl < 4; ++kbl) {
        const int ni = kbl >> 1, jb = (kbl & 1) * 8;
        int lo0 = cvtpk(s[ni][jb + 0], s[ni][jb + 1]);
        int lo1 = cvtpk(s[ni][jb + 2], s[ni][jb + 3]);
        int hi0 = cvtpk(s[ni][jb + 4], s[ni][jb + 5]);
        int hi1 = cvtpk(s[ni][jb + 6], s[ni][jb + 7]);
        asm("v_permlane32_swap_b32 %0, %1" : "+v"(lo0), "+v"(hi0));
        asm("v_permlane32_swap_b32 %0, %1" : "+v"(lo1), "+v"(hi1));
        i32x4 pw; pw[0] = lo0; pw[1] = lo1; pw[2] = hi0; pw[3] = hi1;
        bf16x8 pf = __builtin_bit_cast(bf16x8, pw);
        const int kb = st * 4 + kbl;
#pragma unroll
        for (int mo = 0; mo < 2; ++mo) {
          int row = mo * 32 + r32;
          bf16x8 vf = *reinterpret_cast<const bf16x8*>(
              &VtB[row * 256 + ((kb * 32 + hi * 16) ^ ((row & 7) << 4))]);
          o[mo] = __builtin_amdgcn_mfma_f32_32x32x16_bf16(vf, pf, o[mo], 0, 0, 0);
        }
      }
    }
  }

  float inv = 1.0f / lrun;
#pragma unroll
  for (int mo = 0; mo < 2; ++mo)
#pragma unroll
    for (int rq = 0; rq < 4; ++rq) {
      bf16x4 ov;
#pragma unroll
      for (int c = 0; c < 4; ++c) ov[c] = f2bf(o[mo][rq * 4 + c] * inv);
      *reinterpret_cast<bf16x4*>(
          &y[(size_t)(b * 4096 + T) * 1024 + h * 64 + mo * 32 + rq * 8 + hi * 4]) = ov;
    }
#undef LOADT
}

// ---------------- GEMM2: out = y @ W_proj + b (128x128, BK=32, quad-buffered) --------
__global__ __launch_bounds__(256, 2) void k_gemm_out(const short* __restrict__ A,
                                                     const short* __restrict__ BT,
                                                     const float* __restrict__ bias,
                                                     float* __restrict__ C) {
  __shared__ __align__(16) char lds[4 * 16384];
  const int tid = threadIdx.x, l = tid & 63, wv = tid >> 6;
  const int wm = wv >> 1, wn = wv & 1;
  const int r16 = l & 15, g4 = l >> 4;
  const int m0 = blockIdx.x * 128, n0 = blockIdx.y * 128;
  const int sl = (tid & 3) ^ ((tid >> 3) & 3);
  const short* aS = A + (size_t)(m0 + (tid >> 2)) * 1024 + sl * 8;
  const short* bS = BT + (size_t)(n0 + (tid >> 2)) * 1024 + sl * 8;
  const int sw = (g4 ^ ((r16 >> 1) & 3)) * 16;

  f32x4 acc[4][4];
#pragma unroll
  for (int i = 0; i < 4; ++i)
#pragma unroll
    for (int j = 0; j < 4; ++j) acc[i][j] = f32x4{0.f, 0.f, 0.f, 0.f};

#define STAGE3(kt, bf)                                                      \
  {                                                                         \
    const int k0_ = (kt) * 32;                                              \
    gload16(aS + k0_, lds + (bf) * 16384 + tid * 16);                       \
    gload16(aS + 65536 + k0_, lds + (bf) * 16384 + 4096 + tid * 16);        \
    gload16(bS + k0_, lds + (bf) * 16384 + 8192 + tid * 16);                \
    gload16(bS + 65536 + k0_, lds + (bf) * 16384 + 12288 + tid * 16);       \
  }

  STAGE3(0, 0); STAGE3(1, 1); STAGE3(2, 2);

  for (int kt = 0; kt < 32; ++kt) {
    if (kt < 30) WAITV(8);
    else if (kt == 30) WAITV(4);
    else WAITV(0);
    BARRIER();
    if (kt + 3 < 32) STAGE3(kt + 3, (kt + 3) & 3);
    const char* aT = lds + (kt & 3) * 16384;
    const char* bT = aT + 8192;
    bf16x8 af[4], bfr[4];
#pragma unroll
    for (int mi = 0; mi < 4; ++mi)
      af[mi] = *(const bf16x8*)(aT + (wm * 64 + mi * 16 + r16) * 64 + sw);
#pragma unroll
    for (int ni = 0; ni < 4; ++ni)
      bfr[ni] = *(const bf16x8*)(bT + (wn * 64 + ni * 16 + r16) * 64 + sw);
    __builtin_amdgcn_s_setprio(1);
#pragma unroll
    for (int mi = 0; mi < 4; ++mi)
#pragma unroll
      for (int ni = 0; ni < 4; ++ni)
        acc[mi][ni] = __builtin_amdgcn_mfma_f32_16x16x32_bf16(af[mi], bfr[ni], acc[mi][ni], 0, 0, 0);
    __builtin_amdgcn_s_setprio(0);
  }
#undef STAGE3

#pragma unroll
  for (int i = 0; i < 4; ++i)
#pragma unroll
    for (int j = 0; j < 4; ++j) {
      int row = m0 + wm * 64 + i * 16 + g4 * 4;
      int col = n0 + wn * 64 + j * 16 + r16;
      float bv = bias[col];
#pragma unroll
      for (int q = 0; q < 4; ++q)
        C[(size_t)(row + q) * 1024 + col] = acc[i][j][q] + bv;
    }
}

extern "C" void kernel_launch(void* const* d_in, const int* in_sizes, int n_in,
                              void* d_out, int out_size, void* d_ws, size_t ws_size,
                              hipStream_t stream) {
  const float* x      = (const float*)d_in[0];
  const float* W_attn = (const float*)d_in[1];
  const float* b_attn = (const float*)d_in[2];
  const float* W_proj = (const float*)d_in[3];
  const float* b_proj = (const float*)d_in[4];
  const float* E      = (const float*)d_in[5];
  const float* F      = (const float*)d_in[6];
  float* out = (float*)d_out;

  char* ws = (char*)d_ws;
  short* xb  = (short*)(ws + 0);          //  32 MB: x bf16            (16384x1024)
  short* WaT = (short*)(ws + 33554432);   //   6 MB: W_attn^T bf16     (3072x1024)
  short* WpT = (short*)(ws + 39845888);   //   2 MB: W_proj^T bf16     (1024x1024)
  short* Et  = (short*)(ws + 41943040);   //   8 MB: E^T bf16          (1024x4096)
  short* Ft  = (short*)(ws + 50331648);   //   8 MB: F^T bf16          (1024x4096)
  short* qb  = (short*)(ws + 58720256);   //  32 MB: q bf16            (16384x1024)
  short* xTb = (short*)(ws + 92274688);   //  32 MB: x^T bf16          (4x1024x4096)
  short* xEk = (short*)(ws + 125829120);  //   8 MB: E^T@x bf16        (4x1024x1024)
  short* xEv = (short*)(ws + 134217728);  //   8 MB: F^T@x bf16        (4x1024x1024)
  short* kp  = (short*)(ws + 142606336);  //   8 MB: k_proj bf16       (4x1024x1024)
  short* vpt = (short*)(ws + 150994944);  //   8 MB: v_proj^T bf16     (4x1024x1024)
  short* yb  = (short*)(ws + 159383552);  //  32 MB: attn out bf16     (16384x1024)
  float* sE  = (float*)(ws + 192937984);  //   4 KB: colsum(E)
  float* sF  = (float*)(ws + 192942080);  //   4 KB: colsum(F)
  float* part= (float*)(ws + 192946176);  // 512 KB: colsum partials (2x64x1024)

  k_convert<<<16384, 256, 0, stream>>>(x, xb, 16777216);
  k_transpose_cvt<<<dim3(96, 32), 256, 0, stream>>>(W_attn, WaT, 1024, 3072);
  k_transpose_cvt<<<dim3(32, 32), 256, 0, stream>>>(W_proj, WpT, 1024, 1024);
  k_transpose_cvt<<<dim3(32, 128), 256, 0, stream>>>(E, Et, 4096, 1024);
  k_transpose_cvt<<<dim3(32, 128), 256, 0, stream>>>(F, Ft, 4096, 1024);
  for (int b = 0; b < 4; ++b)
    k_transpose_cvt<<<dim3(32, 128), 256, 0, stream>>>(
        x + (size_t)b * 4096 * 1024, xTb + (size_t)b * 1024 * 4096, 4096, 1024);
  k_colsum1<<<dim3(4, 64, 2), 256, 0, stream>>>(E, F, part);
  k_colsum2<<<8, 256, 0, stream>>>(part, sE, sF);

  k_gemm_q<<<256, 512, 0, stream>>>(xb, WaT, b_attn, qb);
  k_proj<<<dim3(8, 8, 8), 256, 0, stream>>>(Et, Ft, xTb, xEk, xEv);
  k_kpvp<<<dim3(32, 8, 2), 256, 0, stream>>>(xEk, xEv, WaT, b_attn, sE, sF, kp, vpt);
  k_attn<<<dim3(32, 64), 256, 0, stream>>>(qb, kp, vpt, yb);
  k_gemm_out<<<dim3(128, 8), 256, 0, stream>>>(yb, WpT, b_proj, out);
}

// Round 16
// 355.123 us; speedup vs baseline: 1.1815x; 1.0309x over previous
//
#include <hip/hip_runtime.h>
#include <stdint.h>

typedef short bf16x8 __attribute__((ext_vector_type(8)));
typedef short bf16x4 __attribute__((ext_vector_type(4)));
typedef float f32x4 __attribute__((ext_vector_type(4)));
typedef float f32x16 __attribute__((ext_vector_type(16)));
typedef int i32x4 __attribute__((ext_vector_type(4)));

__device__ __forceinline__ short f2bf(float f) {
  union { float f; uint32_t u; } v; v.f = f;
  uint32_t r = (v.u + 0x7FFFu + ((v.u >> 16) & 1u)) >> 16;
  return (short)(uint16_t)r;
}

__device__ __forceinline__ int cvtpk(float lo, float hi) {
  int r;
  asm("v_cvt_pk_bf16_f32 %0, %1, %2" : "=v"(r) : "v"(lo), "v"(hi));
  return r;
}

// async global->LDS, 16B per lane; LDS dest must be linear in lane order
__device__ __forceinline__ void gload16(const void* g, void* l) {
  __builtin_amdgcn_global_load_lds(
      (const __attribute__((address_space(1))) unsigned int*)g,
      (__attribute__((address_space(3))) unsigned int*)l, 16, 0, 0);
}

#define WAITV(n) asm volatile("s_waitcnt vmcnt(" #n ")" ::: "memory")
#define BARRIER()                          \
  do {                                     \
    __builtin_amdgcn_s_barrier();          \
    asm volatile("" ::: "memory");         \
  } while (0)

// ---------------- elementwise f32 -> bf16 ----------------
__global__ __launch_bounds__(256) void k_convert(const float* __restrict__ in,
                                                 short* __restrict__ out, int n) {
  int i = (blockIdx.x * 256 + threadIdx.x) * 4;
  if (i >= n) return;
  float4 v = *reinterpret_cast<const float4*>(in + i);
  bf16x4 o; o[0] = f2bf(v.x); o[1] = f2bf(v.y); o[2] = f2bf(v.z); o[3] = f2bf(v.w);
  *reinterpret_cast<bf16x4*>(out + i) = o;
}

// ---------------- transpose + convert: out[C][R] = bf16(in[R][C]) ----------------
__global__ __launch_bounds__(256) void k_transpose_cvt(const float* __restrict__ in,
                                                       short* __restrict__ out,
                                                       int R, int C) {
  __shared__ float tile[32][33];
  int r0 = blockIdx.y * 32, c0 = blockIdx.x * 32;
  int tx = threadIdx.x & 31, ty = threadIdx.x >> 5;
#pragma unroll
  for (int j = 0; j < 4; ++j)
    tile[ty + j * 8][tx] = in[(size_t)(r0 + ty + j * 8) * C + c0 + tx];
  __syncthreads();
#pragma unroll
  for (int j = 0; j < 4; ++j)
    out[(size_t)(c0 + ty + j * 8) * R + r0 + tx] = f2bf(tile[tx][ty + j * 8]);
}

// ---------------- column sums, two-stage deterministic reduction ----------------
__global__ __launch_bounds__(256) void k_colsum1(const float* __restrict__ E,
                                                 const float* __restrict__ F,
                                                 float* __restrict__ partial) {
  const int c = blockIdx.x * 256 + threadIdx.x;
  const int tc = blockIdx.y, which = blockIdx.z;
  const float* src = (which ? F : E) + (size_t)(tc * 64) * 1024 + c;
  float s = 0.f;
#pragma unroll 8
  for (int t = 0; t < 64; ++t) s += src[(size_t)t * 1024];
  partial[((size_t)which * 64 + tc) * 1024 + c] = s;
}

__global__ __launch_bounds__(256) void k_colsum2(const float* __restrict__ partial,
                                                 float* __restrict__ sE,
                                                 float* __restrict__ sF) {
  const int bid = blockIdx.x;
  const int which = bid >> 2, c = (bid & 3) * 256 + threadIdx.x;
  const float* p = partial + (size_t)which * 64 * 1024 + c;
  float s = 0.f;
#pragma unroll 8
  for (int t = 0; t < 64; ++t) s += p[(size_t)t * 1024];
  (which ? sF : sE)[c] = s;
}

// ---------------- GEMM_q: qb = x @ Wq + bq  (256x256, BK=32, quad-buffered) ----------
__global__ __launch_bounds__(512, 2) void k_gemm_q(const short* __restrict__ A,
                                                   const short* __restrict__ BT,
                                                   const float* __restrict__ bias,
                                                   short* __restrict__ qb) {
  __shared__ __align__(16) char lds[4 * 32768];
  const int tid = threadIdx.x, l = tid & 63, wv = tid >> 6;
  const int wm = wv >> 2, wn = wv & 3;
  const int r16 = l & 15, g4 = l >> 4;
  const int orig = blockIdx.x;
  const int xcd = orig & 7, loc = orig >> 3;
  const int m0 = (xcd * 8 + (loc & 7)) * 256, n0 = (loc >> 3) * 256;
  const int sl = (tid & 3) ^ ((tid >> 3) & 3);
  const short* aS = A + (size_t)(m0 + (tid >> 2)) * 1024 + sl * 8;
  const short* bS = BT + (size_t)(n0 + (tid >> 2)) * 1024 + sl * 8;
  const int sw = (g4 ^ ((r16 >> 1) & 3)) * 16;

  f32x4 acc[8][4];
#pragma unroll
  for (int i = 0; i < 8; ++i)
#pragma unroll
    for (int j = 0; j < 4; ++j) acc[i][j] = f32x4{0.f, 0.f, 0.f, 0.f};

#define STAGEQ(kt, bf)                                                      \
  {                                                                         \
    const int k0_ = (kt) * 32;                                              \
    gload16(aS + k0_, lds + (bf) * 32768 + tid * 16);                       \
    gload16(aS + 131072 + k0_, lds + (bf) * 32768 + 8192 + tid * 16);       \
    gload16(bS + k0_, lds + (bf) * 32768 + 16384 + tid * 16);               \
    gload16(bS + 131072 + k0_, lds + (bf) * 32768 + 24576 + tid * 16);      \
  }

  STAGEQ(0, 0); STAGEQ(1, 1); STAGEQ(2, 2);

  for (int kt = 0; kt < 32; ++kt) {
    if (kt < 30) WAITV(8);
    else if (kt == 30) WAITV(4);
    else WAITV(0);
    BARRIER();
    if (kt + 3 < 32) STAGEQ(kt + 3, (kt + 3) & 3);
    const char* aT = lds + (kt & 3) * 32768;
    const char* bT = aT + 16384;
    bf16x8 af[8], bfr[4];
#pragma unroll
    for (int mi = 0; mi < 8; ++mi)
      af[mi] = *(const bf16x8*)(aT + (wm * 128 + mi * 16 + r16) * 64 + sw);
#pragma unroll
    for (int ni = 0; ni < 4; ++ni)
      bfr[ni] = *(const bf16x8*)(bT + (wn * 64 + ni * 16 + r16) * 64 + sw);
    __builtin_amdgcn_s_setprio(1);
#pragma unroll
    for (int mi = 0; mi < 8; ++mi)
#pragma unroll
      for (int ni = 0; ni < 4; ++ni)
        acc[mi][ni] = __builtin_amdgcn_mfma_f32_16x16x32_bf16(af[mi], bfr[ni], acc[mi][ni], 0, 0, 0);
    __builtin_amdgcn_s_setprio(0);
  }
#undef STAGEQ

#pragma unroll
  for (int i = 0; i < 8; ++i)
#pragma unroll
    for (int j = 0; j < 4; ++j) {
      int row = m0 + wm * 128 + i * 16 + g4 * 4;
      int col = n0 + wn * 64 + j * 16 + r16;
      float bv = bias[col];
#pragma unroll
      for (int q = 0; q < 4; ++q)
        qb[(size_t)(row + q) * 1024 + col] = f2bf(acc[i][j][q] + bv);
    }
}

// ---------------- xE GEMM (128x128, BK=32, quad-buffered, K=4096) ----------------
__global__ __launch_bounds__(256, 2) void k_proj(const short* __restrict__ Et,
                                                 const short* __restrict__ Ft,
                                                 const short* __restrict__ xT,
                                                 short* __restrict__ xEk,
                                                 short* __restrict__ xEv) {
  const int z = blockIdx.z, b = z >> 1, which = z & 1;
  const short* __restrict__ AT = which ? Ft : Et;
  const short* __restrict__ BTp = xT + ((size_t)b << 10) * 4096;
  short* __restrict__ outp = which ? xEv : xEk;
  __shared__ __align__(16) char lds[4 * 16384];
  const int tid = threadIdx.x, l = tid & 63, wv = tid >> 6;
  const int wm = wv >> 1, wn = wv & 1;
  const int r16 = l & 15, g4 = l >> 4;
  const int m0 = blockIdx.x * 128, n0 = blockIdx.y * 128;
  const int sl = (tid & 3) ^ ((tid >> 3) & 3);
  const short* aS = AT + (size_t)(m0 + (tid >> 2)) * 4096 + sl * 8;
  const short* bS = BTp + (size_t)(n0 + (tid >> 2)) * 4096 + sl * 8;
  const int sw = (g4 ^ ((r16 >> 1) & 3)) * 16;

  f32x4 acc[4][4];
#pragma unroll
  for (int i = 0; i < 4; ++i)
#pragma unroll
    for (int j = 0; j < 4; ++j) acc[i][j] = f32x4{0.f, 0.f, 0.f, 0.f};

#define STAGE2(kt, bf)                                                      \
  {                                                                         \
    const int k0_ = (kt) * 32;                                              \
    gload16(aS + k0_, lds + (bf) * 16384 + tid * 16);                       \
    gload16(aS + 262144 + k0_, lds + (bf) * 16384 + 4096 + tid * 16);       \
    gload16(bS + k0_, lds + (bf) * 16384 + 8192 + tid * 16);                \
    gload16(bS + 262144 + k0_, lds + (bf) * 16384 + 12288 + tid * 16);      \
  }

  STAGE2(0, 0); STAGE2(1, 1); STAGE2(2, 2);

  for (int kt = 0; kt < 128; ++kt) {
    if (kt < 126) WAITV(8);
    else if (kt == 126) WAITV(4);
    else WAITV(0);
    BARRIER();
    if (kt + 3 < 128) STAGE2(kt + 3, (kt + 3) & 3);
    const char* aT = lds + (kt & 3) * 16384;
    const char* bT = aT + 8192;
    bf16x8 af[4], bfr[4];
#pragma unroll
    for (int mi = 0; mi < 4; ++mi)
      af[mi] = *(const bf16x8*)(aT + (wm * 64 + mi * 16 + r16) * 64 + sw);
#pragma unroll
    for (int ni = 0; ni < 4; ++ni)
      bfr[ni] = *(const bf16x8*)(bT + (wn * 64 + ni * 16 + r16) * 64 + sw);
    __builtin_amdgcn_s_setprio(1);
#pragma unroll
    for (int mi = 0; mi < 4; ++mi)
#pragma unroll
      for (int ni = 0; ni < 4; ++ni)
        acc[mi][ni] = __builtin_amdgcn_mfma_f32_16x16x32_bf16(af[mi], bfr[ni], acc[mi][ni], 0, 0, 0);
    __builtin_amdgcn_s_setprio(0);
  }
#undef STAGE2

#pragma unroll
  for (int i = 0; i < 4; ++i)
#pragma unroll
    for (int j = 0; j < 4; ++j) {
      int row = m0 + wm * 64 + i * 16 + g4 * 4;   // kk
      int col = n0 + wn * 64 + j * 16 + r16;      // c
#pragma unroll
      for (int q = 0; q < 4; ++q)
        outp[((size_t)(b * 1024) + row + q) * 1024 + col] = f2bf(acc[i][j][q]);
    }
}

// ---------------- kp/vp GEMM: kp = (0.125*log2e)*(xEk@Wk + sE*bk); vpt transposed ----
__global__ __launch_bounds__(256, 2) void k_kpvp(const short* __restrict__ xEk,
                                                 const short* __restrict__ xEv,
                                                 const short* __restrict__ WaT,
                                                 const float* __restrict__ b_attn,
                                                 const float* __restrict__ sE,
                                                 const float* __restrict__ sF,
                                                 short* __restrict__ kp,
                                                 short* __restrict__ vpt) {
  const int which = blockIdx.z;
  const short* __restrict__ A = which ? xEv : xEk;
  const short* __restrict__ BT = WaT + (size_t)(1024 + which * 1024) * 1024;
  const float* __restrict__ bias = b_attn + 1024 + which * 1024;
  const float* __restrict__ rs = which ? sF : sE;
  __shared__ __align__(16) char lds[4 * 16384];
  const int tid = threadIdx.x, l = tid & 63, wv = tid >> 6;
  const int wm = wv >> 1, wn = wv & 1;
  const int r16 = l & 15, g4 = l >> 4;
  const int m0 = blockIdx.x * 128, n0 = blockIdx.y * 128;
  const int sl = (tid & 3) ^ ((tid >> 3) & 3);
  const short* aS = A + (size_t)(m0 + (tid >> 2)) * 1024 + sl * 8;
  const short* bS = BT + (size_t)(n0 + (tid >> 2)) * 1024 + sl * 8;
  const int sw = (g4 ^ ((r16 >> 1) & 3)) * 16;

  f32x4 acc[4][4];
#pragma unroll
  for (int i = 0; i < 4; ++i)
#pragma unroll
    for (int j = 0; j < 4; ++j) acc[i][j] = f32x4{0.f, 0.f, 0.f, 0.f};

#define STAGEP(kt, bf)                                                      \
  {                                                                         \
    const int k0_ = (kt) * 32;                                              \
    gload16(aS + k0_, lds + (bf) * 16384 + tid * 16);                       \
    gload16(aS + 65536 + k0_, lds + (bf) * 16384 + 4096 + tid * 16);        \
    gload16(bS + k0_, lds + (bf) * 16384 + 8192 + tid * 16);                \
    gload16(bS + 65536 + k0_, lds + (bf) * 16384 + 12288 + tid * 16);       \
  }

  STAGEP(0, 0); STAGEP(1, 1); STAGEP(2, 2);

  for (int kt = 0; kt < 32; ++kt) {
    if (kt < 30) WAITV(8);
    else if (kt == 30) WAITV(4);
    else WAITV(0);
    BARRIER();
    if (kt + 3 < 32) STAGEP(kt + 3, (kt + 3) & 3);
    const char* aT = lds + (kt & 3) * 16384;
    const char* bT = aT + 8192;
    bf16x8 af[4], bfr[4];
#pragma unroll
    for (int mi = 0; mi < 4; ++mi)
      af[mi] = *(const bf16x8*)(aT + (wm * 64 + mi * 16 + r16) * 64 + sw);
#pragma unroll
    for (int ni = 0; ni < 4; ++ni)
      bfr[ni] = *(const bf16x8*)(bT + (wn * 64 + ni * 16 + r16) * 64 + sw);
    __builtin_amdgcn_s_setprio(1);
#pragma unroll
    for (int mi = 0; mi < 4; ++mi)
#pragma unroll
      for (int ni = 0; ni < 4; ++ni)
        acc[mi][ni] = __builtin_amdgcn_mfma_f32_16x16x32_bf16(af[mi], bfr[ni], acc[mi][ni], 0, 0, 0);
    __builtin_amdgcn_s_setprio(0);
  }
#undef STAGEP

  if (which) {
    // vpt[b][col][kk] = acc + sF[kk]*bv[col]  (transposed store)
#pragma unroll
    for (int i = 0; i < 4; ++i)
#pragma unroll
      for (int j = 0; j < 4; ++j) {
        int row = m0 + wm * 64 + i * 16 + g4 * 4;   // global (b,kk) row
        int col = n0 + wn * 64 + j * 16 + r16;
        int bb = row >> 10;
        float bv = bias[col];
        bf16x4 ov;
#pragma unroll
        for (int q = 0; q < 4; ++q)
          ov[q] = f2bf(acc[i][j][q] + rs[(row + q) & 1023] * bv);
        *reinterpret_cast<bf16x4*>(
            &vpt[(((size_t)bb << 10) + col) * 1024 + (row & 1023)]) = ov;
      }
  } else {
    // kp[row][col] = 0.125*log2e*(acc + sE[kk]*bk[col])  -> S arrives in exp2 domain
    const float KSCALE = 0.125f * 1.4426950408889634f;
#pragma unroll
    for (int i = 0; i < 4; ++i)
#pragma unroll
      for (int j = 0; j < 4; ++j) {
        int row = m0 + wm * 64 + i * 16 + g4 * 4;
        int col = n0 + wn * 64 + j * 16 + r16;
        float bv = bias[col];
#pragma unroll
        for (int q = 0; q < 4; ++q)
          kp[(size_t)(row + q) * 1024 + col] =
              f2bf((acc[i][j][q] + rs[(row + q) & 1023] * bv) * KSCALE);
      }
  }
}

// ---------------- Flash attention: swapped 32x32x16, no-max exp2 softmax,
//                  T14 async stage split; 3 blocks/CU; lane-local lrun ----------
__global__ __launch_bounds__(256, 3) void k_attn(const short* __restrict__ qb,
                                                 const short* __restrict__ kp,
                                                 const short* __restrict__ vpt,
                                                 short* __restrict__ y) {
  __shared__ __align__(16) char KsB[128 * 128];   // [kk][d] swizzled, 16 KB
  __shared__ __align__(16) char VtB[64 * 256];    // [d][kk] swizzled, 16 KB
  const int tid = threadIdx.x, lane = tid & 63, w = tid >> 6;
  const int r32 = lane & 31, hi = lane >> 5;
  const int iblk = 31 - blockIdx.x;     // heavy blocks first
  const int bh = blockIdx.y, b = bh >> 4, h = bh & 15;
  const int t0 = iblk * 128;
  const int tl = w * 32 + r32;          // local row
  const int T = t0 + tl;                // global row (within b)

  bf16x8 qf[4];
#pragma unroll
  for (int kd = 0; kd < 4; ++kd)
    qf[kd] = *reinterpret_cast<const bf16x8*>(
        &qb[(size_t)(b * 4096 + T) * 1024 + h * 64 + kd * 16 + hi * 8]);

  f32x16 o[2];
#pragma unroll
  for (int i = 0; i < 16; ++i) { o[0][i] = 0.f; o[1][i] = 0.f; }
  float lrun = 0.f;   // lane-local half-sum; partner folded in epilogue

  const short* kpb = kp + ((size_t)b << 20) + h * 64;             // [kk][c]
  const short* vtb = vpt + (((size_t)b << 10) + h * 64) * 1024;   // [c][kk]

  const int kkl_ = tid >> 3, c8 = tid & 7;
  const int dl_ = tid >> 4, c16 = tid & 15;
  bf16x8 kreg[4], vreg[4];

#define LOADT(jt)                                                              \
  {                                                                            \
    const int kk0_ = (jt) * 128;                                               \
    _Pragma("unroll") for (int it = 0; it < 4; ++it) {                         \
      kreg[it] = *reinterpret_cast<const bf16x8*>(                             \
          &kpb[(size_t)(kk0_ + it * 32 + kkl_) * 1024 + c8 * 8]);              \
      vreg[it] = *reinterpret_cast<const bf16x8*>(                             \
          &vtb[(size_t)(it * 16 + dl_) * 1024 + kk0_ + c16 * 8]);              \
    }                                                                          \
  }

  LOADT(0);

  const int ntiles = (iblk + 1 < 8) ? (iblk + 1) : 8;
  for (int jt = 0; jt < ntiles; ++jt) {
    WAITV(0);        // prefetched regs valid
    BARRIER();       // all waves done reading previous tile's LDS
#pragma unroll
    for (int it = 0; it < 4; ++it) {
      int kk = it * 32 + kkl_;
      *reinterpret_cast<bf16x8*>(&KsB[kk * 128 + ((c8 * 16) ^ ((kk & 7) << 4))]) = kreg[it];
      int d = it * 16 + dl_;
      *reinterpret_cast<bf16x8*>(&VtB[d * 256 + ((c16 * 16) ^ ((d & 7) << 4))]) = vreg[it];
    }
    __syncthreads();                    // writes visible
    if (jt + 1 < ntiles) LOADT(jt + 1); // async: latency hides under compute below

#pragma unroll
    for (int st = 0; st < 2; ++st) {          // 64-kk sub-tiles
      f32x16 s[2];
#pragma unroll
      for (int i = 0; i < 16; ++i) { s[0][i] = 0.f; s[1][i] = 0.f; }
#pragma unroll
      for (int ni = 0; ni < 2; ++ni) {
        int row = (st * 2 + ni) * 32 + r32;
#pragma unroll
        for (int kd = 0; kd < 4; ++kd) {
          bf16x8 kf = *reinterpret_cast<const bf16x8*>(
              &KsB[row * 128 + ((kd * 32 + hi * 16) ^ ((row & 7) << 4))]);
          s[ni] = __builtin_amdgcn_mfma_f32_32x32x16_bf16(kf, qf[kd], s[ni], 0, 0, 0);
        }
      }

      if (jt == iblk) {  // causal mask on diagonal tile
#pragma unroll
        for (int ni = 0; ni < 2; ++ni)
#pragma unroll
          for (int j = 0; j < 16; ++j) {
            int kkl = (st * 2 + ni) * 32 + (j & 3) + 8 * (j >> 2) + 4 * hi;
            if (kkl > tl) s[ni][j] = -1e30f;
          }
      }

      // --- no-max softmax, exp2 domain: P = exp2(S); lane-local sum only
      float r0 = 0.f, r1 = 0.f, r2 = 0.f, r3 = 0.f;
#pragma unroll
      for (int j = 0; j < 16; j += 2) {
        float e0 = __builtin_amdgcn_exp2f(s[0][j]);
        float e1 = __builtin_amdgcn_exp2f(s[0][j + 1]);
        float e2 = __builtin_amdgcn_exp2f(s[1][j]);
        float e3 = __builtin_amdgcn_exp2f(s[1][j + 1]);
        s[0][j] = e0; s[0][j + 1] = e1; s[1][j] = e2; s[1][j + 1] = e3;
        r0 += e0; r1 += e1; r2 += e2; r3 += e3;
      }
      lrun += (r0 + r1) + (r2 + r3);

      // --- pack P -> bf16 B-frags (cvtpk + permlane32_swap) and PV MFMA
#pragma unroll
      for (int kbl = 0; kbl < 4; ++kbl) {
        const int ni = kbl >> 1, jb = (kbl & 1) * 8;
        int lo0 = cvtpk(s[ni][jb + 0], s[ni][jb + 1]);
        int lo1 = cvtpk(s[ni][jb + 2], s[ni][jb + 3]);
        int hi0 = cvtpk(s[ni][jb + 4], s[ni][jb + 5]);
        int hi1 = cvtpk(s[ni][jb + 6], s[ni][jb + 7]);
        asm("v_permlane32_swap_b32 %0, %1" : "+v"(lo0), "+v"(hi0));
        asm("v_permlane32_swap_b32 %0, %1" : "+v"(lo1), "+v"(hi1));
        i32x4 pw; pw[0] = lo0; pw[1] = lo1; pw[2] = hi0; pw[3] = hi1;
        bf16x8 pf = __builtin_bit_cast(bf16x8, pw);
        const int kb = st * 4 + kbl;
#pragma unroll
        for (int mo = 0; mo < 2; ++mo) {
          int row = mo * 32 + r32;
          bf16x8 vf = *reinterpret_cast<const bf16x8*>(
              &VtB[row * 256 + ((kb * 32 + hi * 16) ^ ((row & 7) << 4))]);
          o[mo] = __builtin_amdgcn_mfma_f32_32x32x16_bf16(vf, pf, o[mo], 0, 0, 0);
        }
      }
    }
  }

  // fold partner lane's half-sum once
  float ltot = lrun + __shfl_xor(lrun, 32, 64);
  float inv = 1.0f / ltot;
#pragma unroll
  for (int mo = 0; mo < 2; ++mo)
#pragma unroll
    for (int rq = 0; rq < 4; ++rq) {
      bf16x4 ov;
#pragma unroll
      for (int c = 0; c < 4; ++c) ov[c] = f2bf(o[mo][rq * 4 + c] * inv);
      *reinterpret_cast<bf16x4*>(
          &y[(size_t)(b * 4096 + T) * 1024 + h * 64 + mo * 32 + rq * 8 + hi * 4]) = ov;
    }
#undef LOADT
}

// ---------------- GEMM2: out = y @ W_proj + b (256x256, BK=32, quad-buffered) --------
__global__ __launch_bounds__(512, 2) void k_gemm_out(const short* __restrict__ A,
                                                     const short* __restrict__ BT,
                                                     const float* __restrict__ bias,
                                                     float* __restrict__ C) {
  __shared__ __align__(16) char lds[4 * 32768];
  const int tid = threadIdx.x, l = tid & 63, wv = tid >> 6;
  const int wm = wv >> 2, wn = wv & 3;
  const int r16 = l & 15, g4 = l >> 4;
  // L2-banded bijective mapping: 256 blocks = 8 xcd * (8 m-in-band * 4 n)
  const int orig = blockIdx.x;
  const int xcd = orig & 7, loc = orig >> 3;
  const int m0 = (xcd * 8 + (loc & 7)) * 256, n0 = (loc >> 3) * 256;
  const int sl = (tid & 3) ^ ((tid >> 3) & 3);
  const short* aS = A + (size_t)(m0 + (tid >> 2)) * 1024 + sl * 8;
  const short* bS = BT + (size_t)(n0 + (tid >> 2)) * 1024 + sl * 8;
  const int sw = (g4 ^ ((r16 >> 1) & 3)) * 16;

  f32x4 acc[8][4];
#pragma unroll
  for (int i = 0; i < 8; ++i)
#pragma unroll
    for (int j = 0; j < 4; ++j) acc[i][j] = f32x4{0.f, 0.f, 0.f, 0.f};

#define STAGE3(kt, bf)                                                      \
  {                                                                         \
    const int k0_ = (kt) * 32;                                              \
    gload16(aS + k0_, lds + (bf) * 32768 + tid * 16);                       \
    gload16(aS + 131072 + k0_, lds + (bf) * 32768 + 8192 + tid * 16);       \
    gload16(bS + k0_, lds + (bf) * 32768 + 16384 + tid * 16);               \
    gload16(bS + 131072 + k0_, lds + (bf) * 32768 + 24576 + tid * 16);      \
  }

  STAGE3(0, 0); STAGE3(1, 1); STAGE3(2, 2);

  for (int kt = 0; kt < 32; ++kt) {
    if (kt < 30) WAITV(8);
    else if (kt == 30) WAITV(4);
    else WAITV(0);
    BARRIER();
    if (kt + 3 < 32) STAGE3(kt + 3, (kt + 3) & 3);
    const char* aT = lds + (kt & 3) * 32768;
    const char* bT = aT + 16384;
    bf16x8 af[8], bfr[4];
#pragma unroll
    for (int mi = 0; mi < 8; ++mi)
      af[mi] = *(const bf16x8*)(aT + (wm * 128 + mi * 16 + r16) * 64 + sw);
#pragma unroll
    for (int ni = 0; ni < 4; ++ni)
      bfr[ni] = *(const bf16x8*)(bT + (wn * 64 + ni * 16 + r16) * 64 + sw);
    __builtin_amdgcn_s_setprio(1);
#pragma unroll
    for (int mi = 0; mi < 8; ++mi)
#pragma unroll
      for (int ni = 0; ni < 4; ++ni)
        acc[mi][ni] = __builtin_amdgcn_mfma_f32_16x16x32_bf16(af[mi], bfr[ni], acc[mi][ni], 0, 0, 0);
    __builtin_amdgcn_s_setprio(0);
  }
#undef STAGE3

#pragma unroll
  for (int i = 0; i < 8; ++i)
#pragma unroll
    for (int j = 0; j < 4; ++j) {
      int row = m0 + wm * 128 + i * 16 + g4 * 4;
      int col = n0 + wn * 64 + j * 16 + r16;
      float bv = bias[col];
#pragma unroll
      for (int q = 0; q < 4; ++q)
        C[(size_t)(row + q) * 1024 + col] = acc[i][j][q] + bv;
    }
}

extern "C" void kernel_launch(void* const* d_in, const int* in_sizes, int n_in,
                              void* d_out, int out_size, void* d_ws, size_t ws_size,
                              hipStream_t stream) {
  const float* x      = (const float*)d_in[0];
  const float* W_attn = (const float*)d_in[1];
  const float* b_attn = (const float*)d_in[2];
  const float* W_proj = (const float*)d_in[3];
  const float* b_proj = (const float*)d_in[4];
  const float* E      = (const float*)d_in[5];
  const float* F      = (const float*)d_in[6];
  float* out = (float*)d_out;

  char* ws = (char*)d_ws;
  short* xb  = (short*)(ws + 0);          //  32 MB: x bf16            (16384x1024)
  short* WaT = (short*)(ws + 33554432);   //   6 MB: W_attn^T bf16     (3072x1024)
  short* WpT = (short*)(ws + 39845888);   //   2 MB: W_proj^T bf16     (1024x1024)
  short* Et  = (short*)(ws + 41943040);   //   8 MB: E^T bf16          (1024x4096)
  short* Ft  = (short*)(ws + 50331648);   //   8 MB: F^T bf16          (1024x4096)
  short* qb  = (short*)(ws + 58720256);   //  32 MB: q bf16            (16384x1024)
  short* xTb = (short*)(ws + 92274688);   //  32 MB: x^T bf16          (4x1024x4096)
  short* xEk = (short*)(ws + 125829120);  //   8 MB: E^T@x bf16        (4x1024x1024)
  short* xEv = (short*)(ws + 134217728);  //   8 MB: F^T@x bf16        (4x1024x1024)
  short* kp  = (short*)(ws + 142606336);  //   8 MB: k_proj bf16       (4x1024x1024)
  short* vpt = (short*)(ws + 150994944);  //   8 MB: v_proj^T bf16     (4x1024x1024)
  short* yb  = (short*)(ws + 159383552);  //  32 MB: attn out bf16     (16384x1024)
  float* sE  = (float*)(ws + 192937984);  //   4 KB: colsum(E)
  float* sF  = (float*)(ws + 192942080);  //   4 KB: colsum(F)
  float* part= (float*)(ws + 192946176);  // 512 KB: colsum partials (2x64x1024)

  k_convert<<<16384, 256, 0, stream>>>(x, xb, 16777216);
  k_transpose_cvt<<<dim3(96, 32), 256, 0, stream>>>(W_attn, WaT, 1024, 3072);
  k_transpose_cvt<<<dim3(32, 32), 256, 0, stream>>>(W_proj, WpT, 1024, 1024);
  k_transpose_cvt<<<dim3(32, 128), 256, 0, stream>>>(E, Et, 4096, 1024);
  k_transpose_cvt<<<dim3(32, 128), 256, 0, stream>>>(F, Ft, 4096, 1024);
  for (int b = 0; b < 4; ++b)
    k_transpose_cvt<<<dim3(32, 128), 256, 0, stream>>>(
        x + (size_t)b * 4096 * 1024, xTb + (size_t)b * 1024 * 4096, 4096, 1024);
  k_colsum1<<<dim3(4, 64, 2), 256, 0, stream>>>(E, F, part);
  k_colsum2<<<8, 256, 0, stream>>>(part, sE, sF);

  k_gemm_q<<<256, 512, 0, stream>>>(xb, WaT, b_attn, qb);
  k_proj<<<dim3(8, 8, 8), 256, 0, stream>>>(Et, Ft, xTb, xEk, xEv);
  k_kpvp<<<dim3(32, 8, 2), 256, 0, stream>>>(xEk, xEv, WaT, b_attn, sE, sF, kp, vpt);
  k_attn<<<dim3(32, 64), 256, 0, stream>>>(qb, kp, vpt, yb);
  k_gemm_out<<<256, 512, 0, stream>>>(yb, WpT, b_proj, out);
}

// Round 17
// 332.272 us; speedup vs baseline: 1.2628x; 1.0688x over previous
//
#include <hip/hip_runtime.h>
#include <stdint.h>

typedef short bf16x8 __attribute__((ext_vector_type(8)));
typedef short bf16x4 __attribute__((ext_vector_type(4)));
typedef float f32x4 __attribute__((ext_vector_type(4)));
typedef float f32x16 __attribute__((ext_vector_type(16)));
typedef int i32x4 __attribute__((ext_vector_type(4)));

__device__ __forceinline__ short f2bf(float f) {
  union { float f; uint32_t u; } v; v.f = f;
  uint32_t r = (v.u + 0x7FFFu + ((v.u >> 16) & 1u)) >> 16;
  return (short)(uint16_t)r;
}

__device__ __forceinline__ int cvtpk(float lo, float hi) {
  int r;
  asm("v_cvt_pk_bf16_f32 %0, %1, %2" : "=v"(r) : "v"(lo), "v"(hi));
  return r;
}

// async global->LDS, 16B per lane; LDS dest must be linear in lane order
__device__ __forceinline__ void gload16(const void* g, void* l) {
  __builtin_amdgcn_global_load_lds(
      (const __attribute__((address_space(1))) unsigned int*)g,
      (__attribute__((address_space(3))) unsigned int*)l, 16, 0, 0);
}

#define WAITV(n) asm volatile("s_waitcnt vmcnt(" #n ")" ::: "memory")
#define BARRIER()                          \
  do {                                     \
    __builtin_amdgcn_s_barrier();          \
    asm volatile("" ::: "memory");         \
  } while (0)

// ---------------- fused: xb = bf16(x), xT = bf16(x)^T (per batch) ----------------
__global__ __launch_bounds__(256) void k_cvt_tr(const float* __restrict__ in,
                                                short* __restrict__ xb,
                                                short* __restrict__ xT) {
  __shared__ short tile[32][34];   // [col][row], odd dword stride -> no conflicts
  const int b = blockIdx.z;
  const int t0 = blockIdx.y * 32, c0 = blockIdx.x * 32;
  const int tx = threadIdx.x & 31, ty = threadIdx.x >> 5;
  const float* src = in + ((size_t)b * 4096 + t0) * 1024 + c0;
  short* dstA = xb + ((size_t)b * 4096 + t0) * 1024 + c0;
#pragma unroll
  for (int j = 0; j < 4; ++j) {
    int r = ty + j * 8;
    short bv = f2bf(src[(size_t)r * 1024 + tx]);
    dstA[(size_t)r * 1024 + tx] = bv;
    tile[tx][r] = bv;
  }
  __syncthreads();
  short* dstT = xT + ((size_t)b * 1024 + c0) * 4096 + t0;
#pragma unroll
  for (int j = 0; j < 4; ++j) {
    int c = ty + j * 8;
    dstT[(size_t)c * 4096 + tx] = tile[c][tx];
  }
}

// ---------------- transpose + convert: out[C][R] = bf16(in[R][C]) ----------------
__global__ __launch_bounds__(256) void k_transpose_cvt(const float* __restrict__ in,
                                                       short* __restrict__ out,
                                                       int R, int C) {
  __shared__ float tile[32][33];
  int r0 = blockIdx.y * 32, c0 = blockIdx.x * 32;
  int tx = threadIdx.x & 31, ty = threadIdx.x >> 5;
#pragma unroll
  for (int j = 0; j < 4; ++j)
    tile[ty + j * 8][tx] = in[(size_t)(r0 + ty + j * 8) * C + c0 + tx];
  __syncthreads();
#pragma unroll
  for (int j = 0; j < 4; ++j)
    out[(size_t)(c0 + ty + j * 8) * R + r0 + tx] = f2bf(tile[tx][ty + j * 8]);
}

// ---------------- column sums, two-stage deterministic reduction ----------------
__global__ __launch_bounds__(256) void k_colsum1(const float* __restrict__ E,
                                                 const float* __restrict__ F,
                                                 float* __restrict__ partial) {
  const int c = blockIdx.x * 256 + threadIdx.x;
  const int tc = blockIdx.y, which = blockIdx.z;
  const float* src = (which ? F : E) + (size_t)(tc * 64) * 1024 + c;
  float s = 0.f;
#pragma unroll 8
  for (int t = 0; t < 64; ++t) s += src[(size_t)t * 1024];
  partial[((size_t)which * 64 + tc) * 1024 + c] = s;
}

__global__ __launch_bounds__(256) void k_colsum2(const float* __restrict__ partial,
                                                 float* __restrict__ sE,
                                                 float* __restrict__ sF) {
  const int bid = blockIdx.x;
  const int which = bid >> 2, c = (bid & 3) * 256 + threadIdx.x;
  const float* p = partial + (size_t)which * 64 * 1024 + c;
  float s = 0.f;
#pragma unroll 8
  for (int t = 0; t < 64; ++t) s += p[(size_t)t * 1024];
  (which ? sF : sE)[c] = s;
}

// ---------------- GEMM_q: qb = x @ Wq + bq  (256x256, BK=32, quad-buffered) ----------
__global__ __launch_bounds__(512, 2) void k_gemm_q(const short* __restrict__ A,
                                                   const short* __restrict__ BT,
                                                   const float* __restrict__ bias,
                                                   short* __restrict__ qb) {
  __shared__ __align__(16) char lds[4 * 32768];
  const int tid = threadIdx.x, l = tid & 63, wv = tid >> 6;
  const int wm = wv >> 2, wn = wv & 3;
  const int r16 = l & 15, g4 = l >> 4;
  const int orig = blockIdx.x;
  const int xcd = orig & 7, loc = orig >> 3;
  const int m0 = (xcd * 8 + (loc & 7)) * 256, n0 = (loc >> 3) * 256;
  const int sl = (tid & 3) ^ ((tid >> 3) & 3);
  const short* aS = A + (size_t)(m0 + (tid >> 2)) * 1024 + sl * 8;
  const short* bS = BT + (size_t)(n0 + (tid >> 2)) * 1024 + sl * 8;
  const int sw = (g4 ^ ((r16 >> 1) & 3)) * 16;

  f32x4 acc[8][4];
#pragma unroll
  for (int i = 0; i < 8; ++i)
#pragma unroll
    for (int j = 0; j < 4; ++j) acc[i][j] = f32x4{0.f, 0.f, 0.f, 0.f};

#define STAGEQ(kt, bf)                                                      \
  {                                                                         \
    const int k0_ = (kt) * 32;                                              \
    gload16(aS + k0_, lds + (bf) * 32768 + tid * 16);                       \
    gload16(aS + 131072 + k0_, lds + (bf) * 32768 + 8192 + tid * 16);       \
    gload16(bS + k0_, lds + (bf) * 32768 + 16384 + tid * 16);               \
    gload16(bS + 131072 + k0_, lds + (bf) * 32768 + 24576 + tid * 16);      \
  }

  STAGEQ(0, 0); STAGEQ(1, 1); STAGEQ(2, 2);

  for (int kt = 0; kt < 32; ++kt) {
    if (kt < 30) WAITV(8);
    else if (kt == 30) WAITV(4);
    else WAITV(0);
    BARRIER();
    if (kt + 3 < 32) STAGEQ(kt + 3, (kt + 3) & 3);
    const char* aT = lds + (kt & 3) * 32768;
    const char* bT = aT + 16384;
    bf16x8 af[8], bfr[4];
#pragma unroll
    for (int mi = 0; mi < 8; ++mi)
      af[mi] = *(const bf16x8*)(aT + (wm * 128 + mi * 16 + r16) * 64 + sw);
#pragma unroll
    for (int ni = 0; ni < 4; ++ni)
      bfr[ni] = *(const bf16x8*)(bT + (wn * 64 + ni * 16 + r16) * 64 + sw);
    __builtin_amdgcn_s_setprio(1);
#pragma unroll
    for (int mi = 0; mi < 8; ++mi)
#pragma unroll
      for (int ni = 0; ni < 4; ++ni)
        acc[mi][ni] = __builtin_amdgcn_mfma_f32_16x16x32_bf16(af[mi], bfr[ni], acc[mi][ni], 0, 0, 0);
    __builtin_amdgcn_s_setprio(0);
  }
#undef STAGEQ

#pragma unroll
  for (int i = 0; i < 8; ++i)
#pragma unroll
    for (int j = 0; j < 4; ++j) {
      int row = m0 + wm * 128 + i * 16 + g4 * 4;
      int col = n0 + wn * 64 + j * 16 + r16;
      float bv = bias[col];
#pragma unroll
      for (int q = 0; q < 4; ++q)
        qb[(size_t)(row + q) * 1024 + col] = f2bf(acc[i][j][q] + bv);
    }
}

// ---------------- xE GEMM (128x128, BK=32, quad-buffered, K=4096) ----------------
__global__ __launch_bounds__(256, 2) void k_proj(const short* __restrict__ Et,
                                                 const short* __restrict__ Ft,
                                                 const short* __restrict__ xT,
                                                 short* __restrict__ xEk,
                                                 short* __restrict__ xEv) {
  const int z = blockIdx.z, b = z >> 1, which = z & 1;
  const short* __restrict__ AT = which ? Ft : Et;
  const short* __restrict__ BTp = xT + ((size_t)b << 10) * 4096;
  short* __restrict__ outp = which ? xEv : xEk;
  __shared__ __align__(16) char lds[4 * 16384];
  const int tid = threadIdx.x, l = tid & 63, wv = tid >> 6;
  const int wm = wv >> 1, wn = wv & 1;
  const int r16 = l & 15, g4 = l >> 4;
  const int m0 = blockIdx.x * 128, n0 = blockIdx.y * 128;
  const int sl = (tid & 3) ^ ((tid >> 3) & 3);
  const short* aS = AT + (size_t)(m0 + (tid >> 2)) * 4096 + sl * 8;
  const short* bS = BTp + (size_t)(n0 + (tid >> 2)) * 4096 + sl * 8;
  const int sw = (g4 ^ ((r16 >> 1) & 3)) * 16;

  f32x4 acc[4][4];
#pragma unroll
  for (int i = 0; i < 4; ++i)
#pragma unroll
    for (int j = 0; j < 4; ++j) acc[i][j] = f32x4{0.f, 0.f, 0.f, 0.f};

#define STAGE2(kt, bf)                                                      \
  {                                                                         \
    const int k0_ = (kt) * 32;                                              \
    gload16(aS + k0_, lds + (bf) * 16384 + tid * 16);                       \
    gload16(aS + 262144 + k0_, lds + (bf) * 16384 + 4096 + tid * 16);       \
    gload16(bS + k0_, lds + (bf) * 16384 + 8192 + tid * 16);                \
    gload16(bS + 262144 + k0_, lds + (bf) * 16384 + 12288 + tid * 16);      \
  }

  STAGE2(0, 0); STAGE2(1, 1); STAGE2(2, 2);

  for (int kt = 0; kt < 128; ++kt) {
    if (kt < 126) WAITV(8);
    else if (kt == 126) WAITV(4);
    else WAITV(0);
    BARRIER();
    if (kt + 3 < 128) STAGE2(kt + 3, (kt + 3) & 3);
    const char* aT = lds + (kt & 3) * 16384;
    const char* bT = aT + 8192;
    bf16x8 af[4], bfr[4];
#pragma unroll
    for (int mi = 0; mi < 4; ++mi)
      af[mi] = *(const bf16x8*)(aT + (wm * 64 + mi * 16 + r16) * 64 + sw);
#pragma unroll
    for (int ni = 0; ni < 4; ++ni)
      bfr[ni] = *(const bf16x8*)(bT + (wn * 64 + ni * 16 + r16) * 64 + sw);
    __builtin_amdgcn_s_setprio(1);
#pragma unroll
    for (int mi = 0; mi < 4; ++mi)
#pragma unroll
      for (int ni = 0; ni < 4; ++ni)
        acc[mi][ni] = __builtin_amdgcn_mfma_f32_16x16x32_bf16(af[mi], bfr[ni], acc[mi][ni], 0, 0, 0);
    __builtin_amdgcn_s_setprio(0);
  }
#undef STAGE2

#pragma unroll
  for (int i = 0; i < 4; ++i)
#pragma unroll
    for (int j = 0; j < 4; ++j) {
      int row = m0 + wm * 64 + i * 16 + g4 * 4;   // kk
      int col = n0 + wn * 64 + j * 16 + r16;      // c
#pragma unroll
      for (int q = 0; q < 4; ++q)
        outp[((size_t)(b * 1024) + row + q) * 1024 + col] = f2bf(acc[i][j][q]);
    }
}

// ---------------- kp/vp GEMM: kp = (0.125*log2e)*(xEk@Wk + sE*bk); vpt transposed ----
__global__ __launch_bounds__(256, 2) void k_kpvp(const short* __restrict__ xEk,
                                                 const short* __restrict__ xEv,
                                                 const short* __restrict__ WaT,
                                                 const float* __restrict__ b_attn,
                                                 const float* __restrict__ sE,
                                                 const float* __restrict__ sF,
                                                 short* __restrict__ kp,
                                                 short* __restrict__ vpt) {
  const int which = blockIdx.z;
  const short* __restrict__ A = which ? xEv : xEk;
  const short* __restrict__ BT = WaT + (size_t)(1024 + which * 1024) * 1024;
  const float* __restrict__ bias = b_attn + 1024 + which * 1024;
  const float* __restrict__ rs = which ? sF : sE;
  __shared__ __align__(16) char lds[4 * 16384];
  const int tid = threadIdx.x, l = tid & 63, wv = tid >> 6;
  const int wm = wv >> 1, wn = wv & 1;
  const int r16 = l & 15, g4 = l >> 4;
  const int m0 = blockIdx.x * 128, n0 = blockIdx.y * 128;
  const int sl = (tid & 3) ^ ((tid >> 3) & 3);
  const short* aS = A + (size_t)(m0 + (tid >> 2)) * 1024 + sl * 8;
  const short* bS = BT + (size_t)(n0 + (tid >> 2)) * 1024 + sl * 8;
  const int sw = (g4 ^ ((r16 >> 1) & 3)) * 16;

  f32x4 acc[4][4];
#pragma unroll
  for (int i = 0; i < 4; ++i)
#pragma unroll
    for (int j = 0; j < 4; ++j) acc[i][j] = f32x4{0.f, 0.f, 0.f, 0.f};

#define STAGEP(kt, bf)                                                      \
  {                                                                         \
    const int k0_ = (kt) * 32;                                              \
    gload16(aS + k0_, lds + (bf) * 16384 + tid * 16);                       \
    gload16(aS + 65536 + k0_, lds + (bf) * 16384 + 4096 + tid * 16);        \
    gload16(bS + k0_, lds + (bf) * 16384 + 8192 + tid * 16);                \
    gload16(bS + 65536 + k0_, lds + (bf) * 16384 + 12288 + tid * 16);       \
  }

  STAGEP(0, 0); STAGEP(1, 1); STAGEP(2, 2);

  for (int kt = 0; kt < 32; ++kt) {
    if (kt < 30) WAITV(8);
    else if (kt == 30) WAITV(4);
    else WAITV(0);
    BARRIER();
    if (kt + 3 < 32) STAGEP(kt + 3, (kt + 3) & 3);
    const char* aT = lds + (kt & 3) * 16384;
    const char* bT = aT + 8192;
    bf16x8 af[4], bfr[4];
#pragma unroll
    for (int mi = 0; mi < 4; ++mi)
      af[mi] = *(const bf16x8*)(aT + (wm * 64 + mi * 16 + r16) * 64 + sw);
#pragma unroll
    for (int ni = 0; ni < 4; ++ni)
      bfr[ni] = *(const bf16x8*)(bT + (wn * 64 + ni * 16 + r16) * 64 + sw);
    __builtin_amdgcn_s_setprio(1);
#pragma unroll
    for (int mi = 0; mi < 4; ++mi)
#pragma unroll
      for (int ni = 0; ni < 4; ++ni)
        acc[mi][ni] = __builtin_amdgcn_mfma_f32_16x16x32_bf16(af[mi], bfr[ni], acc[mi][ni], 0, 0, 0);
    __builtin_amdgcn_s_setprio(0);
  }
#undef STAGEP

  if (which) {
    // vpt[b][col][kk] = acc + sF[kk]*bv[col]  (transposed store)
#pragma unroll
    for (int i = 0; i < 4; ++i)
#pragma unroll
      for (int j = 0; j < 4; ++j) {
        int row = m0 + wm * 64 + i * 16 + g4 * 4;   // global (b,kk) row
        int col = n0 + wn * 64 + j * 16 + r16;
        int bb = row >> 10;
        float bv = bias[col];
        bf16x4 ov;
#pragma unroll
        for (int q = 0; q < 4; ++q)
          ov[q] = f2bf(acc[i][j][q] + rs[(row + q) & 1023] * bv);
        *reinterpret_cast<bf16x4*>(
            &vpt[(((size_t)bb << 10) + col) * 1024 + (row & 1023)]) = ov;
      }
  } else {
    // kp[row][col] = 0.125*log2e*(acc + sE[kk]*bk[col])  -> S arrives in exp2 domain
    const float KSCALE = 0.125f * 1.4426950408889634f;
#pragma unroll
    for (int i = 0; i < 4; ++i)
#pragma unroll
      for (int j = 0; j < 4; ++j) {
        int row = m0 + wm * 64 + i * 16 + g4 * 4;
        int col = n0 + wn * 64 + j * 16 + r16;
        float bv = bias[col];
#pragma unroll
        for (int q = 0; q < 4; ++q)
          kp[(size_t)(row + q) * 1024 + col] =
              f2bf((acc[i][j][q] + rs[(row + q) & 1023] * bv) * KSCALE);
      }
  }
}

// ---------------- Flash attention: swapped 32x32x16, no-max exp2 softmax,
//                  T14 async stage split; 3 blocks/CU (R15 proven config) ----------
__global__ __launch_bounds__(256, 3) void k_attn(const short* __restrict__ qb,
                                                 const short* __restrict__ kp,
                                                 const short* __restrict__ vpt,
                                                 short* __restrict__ y) {
  __shared__ __align__(16) char KsB[128 * 128];   // [kk][d] swizzled, 16 KB
  __shared__ __align__(16) char VtB[64 * 256];    // [d][kk] swizzled, 16 KB
  const int tid = threadIdx.x, lane = tid & 63, w = tid >> 6;
  const int r32 = lane & 31, hi = lane >> 5;
  const int iblk = 31 - blockIdx.x;     // heavy blocks first
  const int bh = blockIdx.y, b = bh >> 4, h = bh & 15;
  const int t0 = iblk * 128;
  const int tl = w * 32 + r32;          // local row
  const int T = t0 + tl;                // global row (within b)

  bf16x8 qf[4];
#pragma unroll
  for (int kd = 0; kd < 4; ++kd)
    qf[kd] = *reinterpret_cast<const bf16x8*>(
        &qb[(size_t)(b * 4096 + T) * 1024 + h * 64 + kd * 16 + hi * 8]);

  f32x16 o[2];
#pragma unroll
  for (int i = 0; i < 16; ++i) { o[0][i] = 0.f; o[1][i] = 0.f; }
  float lrun = 0.f;

  const short* kpb = kp + ((size_t)b << 20) + h * 64;             // [kk][c]
  const short* vtb = vpt + (((size_t)b << 10) + h * 64) * 1024;   // [c][kk]

  const int kkl_ = tid >> 3, c8 = tid & 7;
  const int dl_ = tid >> 4, c16 = tid & 15;
  bf16x8 kreg[4], vreg[4];

#define LOADT(jt)                                                              \
  {                                                                            \
    const int kk0_ = (jt) * 128;                                               \
    _Pragma("unroll") for (int it = 0; it < 4; ++it) {                         \
      kreg[it] = *reinterpret_cast<const bf16x8*>(                             \
          &kpb[(size_t)(kk0_ + it * 32 + kkl_) * 1024 + c8 * 8]);              \
      vreg[it] = *reinterpret_cast<const bf16x8*>(                             \
          &vtb[(size_t)(it * 16 + dl_) * 1024 + kk0_ + c16 * 8]);              \
    }                                                                          \
  }

  LOADT(0);

  const int ntiles = (iblk + 1 < 8) ? (iblk + 1) : 8;
  for (int jt = 0; jt < ntiles; ++jt) {
    WAITV(0);        // prefetched regs valid
    BARRIER();       // all waves done reading previous tile's LDS
#pragma unroll
    for (int it = 0; it < 4; ++it) {
      int kk = it * 32 + kkl_;
      *reinterpret_cast<bf16x8*>(&KsB[kk * 128 + ((c8 * 16) ^ ((kk & 7) << 4))]) = kreg[it];
      int d = it * 16 + dl_;
      *reinterpret_cast<bf16x8*>(&VtB[d * 256 + ((c16 * 16) ^ ((d & 7) << 4))]) = vreg[it];
    }
    __syncthreads();                    // writes visible
    if (jt + 1 < ntiles) LOADT(jt + 1); // async: latency hides under compute below

#pragma unroll
    for (int st = 0; st < 2; ++st) {          // 64-kk sub-tiles
      f32x16 s[2];
#pragma unroll
      for (int i = 0; i < 16; ++i) { s[0][i] = 0.f; s[1][i] = 0.f; }
#pragma unroll
      for (int ni = 0; ni < 2; ++ni) {
        int row = (st * 2 + ni) * 32 + r32;
#pragma unroll
        for (int kd = 0; kd < 4; ++kd) {
          bf16x8 kf = *reinterpret_cast<const bf16x8*>(
              &KsB[row * 128 + ((kd * 32 + hi * 16) ^ ((row & 7) << 4))]);
          s[ni] = __builtin_amdgcn_mfma_f32_32x32x16_bf16(kf, qf[kd], s[ni], 0, 0, 0);
        }
      }

      if (jt == iblk) {  // causal mask on diagonal tile
#pragma unroll
        for (int ni = 0; ni < 2; ++ni)
#pragma unroll
          for (int j = 0; j < 16; ++j) {
            int kkl = (st * 2 + ni) * 32 + (j & 3) + 8 * (j >> 2) + 4 * hi;
            if (kkl > tl) s[ni][j] = -1e30f;
          }
      }

      // --- no-max softmax, exp2 domain (log2e folded into kp): P = exp2(S)
      float r0 = 0.f, r1 = 0.f, r2 = 0.f, r3 = 0.f;
#pragma unroll
      for (int j = 0; j < 16; j += 2) {
        float e0 = __builtin_amdgcn_exp2f(s[0][j]);
        float e1 = __builtin_amdgcn_exp2f(s[0][j + 1]);
        float e2 = __builtin_amdgcn_exp2f(s[1][j]);
        float e3 = __builtin_amdgcn_exp2f(s[1][j + 1]);
        s[0][j] = e0; s[0][j + 1] = e1; s[1][j] = e2; s[1][j + 1] = e3;
        r0 += e0; r1 += e1; r2 += e2; r3 += e3;
      }
      float rsum = (r0 + r1) + (r2 + r3);
      rsum += __shfl_xor(rsum, 32, 64);
      lrun += rsum;

      // --- pack P -> bf16 B-frags (cvtpk + permlane32_swap) and PV MFMA
#pragma unroll
      for (int kbl = 0; kbl < 4; ++kbl) {
        const int ni = kbl >> 1, jb = (kbl & 1) * 8;
        int lo0 = cvtpk(s[ni][jb + 0], s[ni][jb + 1]);
        int lo1 = cvtpk(s[ni][jb + 2], s[ni][jb + 3]);
        int hi0 = cvtpk(s[ni][jb + 4], s[ni][jb + 5]);
        int hi1 = cvtpk(s[ni][jb + 6], s[ni][jb + 7]);
        asm("v_permlane32_swap_b32 %0, %1" : "+v"(lo0), "+v"(hi0));
        asm("v_permlane32_swap_b32 %0, %1" : "+v"(lo1), "+v"(hi1));
        i32x4 pw; pw[0] = lo0; pw[1] = lo1; pw[2] = hi0; pw[3] = hi1;
        bf16x8 pf = __builtin_bit_cast(bf16x8, pw);
        const int kb = st * 4 + kbl;
#pragma unroll
        for (int mo = 0; mo < 2; ++mo) {
          int row = mo * 32 + r32;
          bf16x8 vf = *reinterpret_cast<const bf16x8*>(
              &VtB[row * 256 + ((kb * 32 + hi * 16) ^ ((row & 7) << 4))]);
          o[mo] = __builtin_amdgcn_mfma_f32_32x32x16_bf16(vf, pf, o[mo], 0, 0, 0);
        }
      }
    }
  }

  float inv = 1.0f / lrun;
#pragma unroll
  for (int mo = 0; mo < 2; ++mo)
#pragma unroll
    for (int rq = 0; rq < 4; ++rq) {
      bf16x4 ov;
#pragma unroll
      for (int c = 0; c < 4; ++c) ov[c] = f2bf(o[mo][rq * 4 + c] * inv);
      *reinterpret_cast<bf16x4*>(
          &y[(size_t)(b * 4096 + T) * 1024 + h * 64 + mo * 32 + rq * 8 + hi * 4]) = ov;
    }
#undef LOADT
}

// ---------------- GEMM2: out = y @ W_proj + b (256x256, BK=32, quad-buffered) --------
__global__ __launch_bounds__(512, 2) void k_gemm_out(const short* __restrict__ A,
                                                     const short* __restrict__ BT,
                                                     const float* __restrict__ bias,
                                                     float* __restrict__ C) {
  __shared__ __align__(16) char lds[4 * 32768];
  const int tid = threadIdx.x, l = tid & 63, wv = tid >> 6;
  const int wm = wv >> 2, wn = wv & 3;
  const int r16 = l & 15, g4 = l >> 4;
  const int orig = blockIdx.x;
  const int xcd = orig & 7, loc = orig >> 3;
  const int m0 = (xcd * 8 + (loc & 7)) * 256, n0 = (loc >> 3) * 256;
  const int sl = (tid & 3) ^ ((tid >> 3) & 3);
  const short* aS = A + (size_t)(m0 + (tid >> 2)) * 1024 + sl * 8;
  const short* bS = BT + (size_t)(n0 + (tid >> 2)) * 1024 + sl * 8;
  const int sw = (g4 ^ ((r16 >> 1) & 3)) * 16;

  f32x4 acc[8][4];
#pragma unroll
  for (int i = 0; i < 8; ++i)
#pragma unroll
    for (int j = 0; j < 4; ++j) acc[i][j] = f32x4{0.f, 0.f, 0.f, 0.f};

#define STAGE3(kt, bf)                                                      \
  {                                                                         \
    const int k0_ = (kt) * 32;                                              \
    gload16(aS + k0_, lds + (bf) * 32768 + tid * 16);                       \
    gload16(aS + 131072 + k0_, lds + (bf) * 32768 + 8192 + tid * 16);       \
    gload16(bS + k0_, lds + (bf) * 32768 + 16384 + tid * 16);               \
    gload16(bS + 131072 + k0_, lds + (bf) * 32768 + 24576 + tid * 16);      \
  }

  STAGE3(0, 0); STAGE3(1, 1); STAGE3(2, 2);

  for (int kt = 0; kt < 32; ++kt) {
    if (kt < 30) WAITV(8);
    else if (kt == 30) WAITV(4);
    else WAITV(0);
    BARRIER();
    if (kt + 3 < 32) STAGE3(kt + 3, (kt + 3) & 3);
    const char* aT = lds + (kt & 3) * 32768;
    const char* bT = aT + 16384;
    bf16x8 af[8], bfr[4];
#pragma unroll
    for (int mi = 0; mi < 8; ++mi)
      af[mi] = *(const bf16x8*)(aT + (wm * 128 + mi * 16 + r16) * 64 + sw);
#pragma unroll
    for (int ni = 0; ni < 4; ++ni)
      bfr[ni] = *(const bf16x8*)(bT + (wn * 64 + ni * 16 + r16) * 64 + sw);
    __builtin_amdgcn_s_setprio(1);
#pragma unroll
    for (int mi = 0; mi < 8; ++mi)
#pragma unroll
      for (int ni = 0; ni < 4; ++ni)
        acc[mi][ni] = __builtin_amdgcn_mfma_f32_16x16x32_bf16(af[mi], bfr[ni], acc[mi][ni], 0, 0, 0);
    __builtin_amdgcn_s_setprio(0);
  }
#undef STAGE3

#pragma unroll
  for (int i = 0; i < 8; ++i)
#pragma unroll
    for (int j = 0; j < 4; ++j) {
      int row = m0 + wm * 128 + i * 16 + g4 * 4;
      int col = n0 + wn * 64 + j * 16 + r16;
      float bv = bias[col];
#pragma unroll
      for (int q = 0; q < 4; ++q)
        C[(size_t)(row + q) * 1024 + col] = acc[i][j][q] + bv;
    }
}

extern "C" void kernel_launch(void* const* d_in, const int* in_sizes, int n_in,
                              void* d_out, int out_size, void* d_ws, size_t ws_size,
                              hipStream_t stream) {
  const float* x      = (const float*)d_in[0];
  const float* W_attn = (const float*)d_in[1];
  const float* b_attn = (const float*)d_in[2];
  const float* W_proj = (const float*)d_in[3];
  const float* b_proj = (const float*)d_in[4];
  const float* E      = (const float*)d_in[5];
  const float* F      = (const float*)d_in[6];
  float* out = (float*)d_out;

  char* ws = (char*)d_ws;
  short* xb  = (short*)(ws + 0);          //  32 MB: x bf16            (16384x1024)
  short* WaT = (short*)(ws + 33554432);   //   6 MB: W_attn^T bf16     (3072x1024)
  short* WpT = (short*)(ws + 39845888);   //   2 MB: W_proj^T bf16     (1024x1024)
  short* Et  = (short*)(ws + 41943040);   //   8 MB: E^T bf16          (1024x4096)
  short* Ft  = (short*)(ws + 50331648);   //   8 MB: F^T bf16          (1024x4096)
  short* qb  = (short*)(ws + 58720256);   //  32 MB: q bf16            (16384x1024)
  short* xTb = (short*)(ws + 92274688);   //  32 MB: x^T bf16          (4x1024x4096)
  short* xEk = (short*)(ws + 125829120);  //   8 MB: E^T@x bf16        (4x1024x1024)
  short* xEv = (short*)(ws + 134217728);  //   8 MB: F^T@x bf16        (4x1024x1024)
  short* kp  = (short*)(ws + 142606336);  //   8 MB: k_proj bf16       (4x1024x1024)
  short* vpt = (short*)(ws + 150994944);  //   8 MB: v_proj^T bf16     (4x1024x1024)
  short* yb  = (short*)(ws + 159383552);  //  32 MB: attn out bf16     (16384x1024)
  float* sE  = (float*)(ws + 192937984);  //   4 KB: colsum(E)
  float* sF  = (float*)(ws + 192942080);  //   4 KB: colsum(F)
  float* part= (float*)(ws + 192946176);  // 512 KB: colsum partials (2x64x1024)

  k_cvt_tr<<<dim3(32, 128, 4), 256, 0, stream>>>(x, xb, xTb);
  k_transpose_cvt<<<dim3(96, 32), 256, 0, stream>>>(W_attn, WaT, 1024, 3072);
  k_transpose_cvt<<<dim3(32, 32), 256, 0, stream>>>(W_proj, WpT, 1024, 1024);
  k_transpose_cvt<<<dim3(32, 128), 256, 0, stream>>>(E, Et, 4096, 1024);
  k_transpose_cvt<<<dim3(32, 128), 256, 0, stream>>>(F, Ft, 4096, 1024);
  k_colsum1<<<dim3(4, 64, 2), 256, 0, stream>>>(E, F, part);
  k_colsum2<<<8, 256, 0, stream>>>(part, sE, sF);

  k_gemm_q<<<256, 512, 0, stream>>>(xb, WaT, b_attn, qb);
  k_proj<<<dim3(8, 8, 8), 256, 0, stream>>>(Et, Ft, xTb, xEk, xEv);
  k_kpvp<<<dim3(32, 8, 2), 256, 0, stream>>>(xEk, xEv, WaT, b_attn, sE, sF, kp, vpt);
  k_attn<<<dim3(32, 64), 256, 0, stream>>>(qb, kp, vpt, yb);
  k_gemm_out<<<256, 512, 0, stream>>>(yb, WpT, b_proj, out);
}

// Round 18
// 321.972 us; speedup vs baseline: 1.3032x; 1.0320x over previous
//
#include <hip/hip_runtime.h>
#include <stdint.h>

typedef short bf16x8 __attribute__((ext_vector_type(8)));
typedef short bf16x4 __attribute__((ext_vector_type(4)));
typedef float f32x4 __attribute__((ext_vector_type(4)));
typedef float f32x16 __attribute__((ext_vector_type(16)));
typedef int i32x4 __attribute__((ext_vector_type(4)));

__device__ __forceinline__ short f2bf(float f) {
  union { float f; uint32_t u; } v; v.f = f;
  uint32_t r = (v.u + 0x7FFFu + ((v.u >> 16) & 1u)) >> 16;
  return (short)(uint16_t)r;
}

__device__ __forceinline__ int cvtpk(float lo, float hi) {
  int r;
  asm("v_cvt_pk_bf16_f32 %0, %1, %2" : "=v"(r) : "v"(lo), "v"(hi));
  return r;
}

// async global->LDS, 16B per lane; LDS dest must be linear in lane order
__device__ __forceinline__ void gload16(const void* g, void* l) {
  __builtin_amdgcn_global_load_lds(
      (const __attribute__((address_space(1))) unsigned int*)g,
      (__attribute__((address_space(3))) unsigned int*)l, 16, 0, 0);
}

#define WAITV(n) asm volatile("s_waitcnt vmcnt(" #n ")" ::: "memory")
#define BARRIER()                          \
  do {                                     \
    __builtin_amdgcn_s_barrier();          \
    asm volatile("" ::: "memory");         \
  } while (0)

// ---------------- fused: xb = bf16(x), xT = bf16(x)^T (per batch) ----------------
__global__ __launch_bounds__(256) void k_cvt_tr(const float* __restrict__ in,
                                                short* __restrict__ xb,
                                                short* __restrict__ xT) {
  __shared__ short tile[32][34];
  const int b = blockIdx.z;
  const int t0 = blockIdx.y * 32, c0 = blockIdx.x * 32;
  const int tx = threadIdx.x & 31, ty = threadIdx.x >> 5;
  const float* src = in + ((size_t)b * 4096 + t0) * 1024 + c0;
  short* dstA = xb + ((size_t)b * 4096 + t0) * 1024 + c0;
#pragma unroll
  for (int j = 0; j < 4; ++j) {
    int r = ty + j * 8;
    short bv = f2bf(src[(size_t)r * 1024 + tx]);
    dstA[(size_t)r * 1024 + tx] = bv;
    tile[tx][r] = bv;
  }
  __syncthreads();
  short* dstT = xT + ((size_t)b * 1024 + c0) * 4096 + t0;
#pragma unroll
  for (int j = 0; j < 4; ++j) {
    int c = ty + j * 8;
    dstT[(size_t)c * 4096 + tx] = tile[c][tx];
  }
}

// ---------------- transpose + convert: out[C][R] = bf16(in[R][C]) ----------------
__global__ __launch_bounds__(256) void k_transpose_cvt(const float* __restrict__ in,
                                                       short* __restrict__ out,
                                                       int R, int C) {
  __shared__ float tile[32][33];
  int r0 = blockIdx.y * 32, c0 = blockIdx.x * 32;
  int tx = threadIdx.x & 31, ty = threadIdx.x >> 5;
#pragma unroll
  for (int j = 0; j < 4; ++j)
    tile[ty + j * 8][tx] = in[(size_t)(r0 + ty + j * 8) * C + c0 + tx];
  __syncthreads();
#pragma unroll
  for (int j = 0; j < 4; ++j)
    out[(size_t)(c0 + ty + j * 8) * R + r0 + tx] = f2bf(tile[tx][ty + j * 8]);
}

// ---------------- column sums, two-stage deterministic reduction ----------------
__global__ __launch_bounds__(256) void k_colsum1(const float* __restrict__ E,
                                                 const float* __restrict__ F,
                                                 float* __restrict__ partial) {
  const int c = blockIdx.x * 256 + threadIdx.x;
  const int tc = blockIdx.y, which = blockIdx.z;
  const float* src = (which ? F : E) + (size_t)(tc * 64) * 1024 + c;
  float s = 0.f;
#pragma unroll 8
  for (int t = 0; t < 64; ++t) s += src[(size_t)t * 1024];
  partial[((size_t)which * 64 + tc) * 1024 + c] = s;
}

__global__ __launch_bounds__(256) void k_colsum2(const float* __restrict__ partial,
                                                 float* __restrict__ sE,
                                                 float* __restrict__ sF) {
  const int bid = blockIdx.x;
  const int which = bid >> 2, c = (bid & 3) * 256 + threadIdx.x;
  const float* p = partial + (size_t)which * 64 * 1024 + c;
  float s = 0.f;
#pragma unroll 8
  for (int t = 0; t < 64; ++t) s += p[(size_t)t * 1024];
  (which ? sF : sE)[c] = s;
}

// ---------------- GEMM_q: qb = x @ Wq + bq  (256x256, BK=32, quad-buffered) ----------
__global__ __launch_bounds__(512, 2) void k_gemm_q(const short* __restrict__ A,
                                                   const short* __restrict__ BT,
                                                   const float* __restrict__ bias,
                                                   short* __restrict__ qb) {
  __shared__ __align__(16) char lds[4 * 32768];
  const int tid = threadIdx.x, l = tid & 63, wv = tid >> 6;
  const int wm = wv >> 2, wn = wv & 3;
  const int r16 = l & 15, g4 = l >> 4;
  const int orig = blockIdx.x;
  const int xcd = orig & 7, loc = orig >> 3;
  const int m0 = (xcd * 8 + (loc & 7)) * 256, n0 = (loc >> 3) * 256;
  const int sl = (tid & 3) ^ ((tid >> 3) & 3);
  const short* aS = A + (size_t)(m0 + (tid >> 2)) * 1024 + sl * 8;
  const short* bS = BT + (size_t)(n0 + (tid >> 2)) * 1024 + sl * 8;
  const int sw = (g4 ^ ((r16 >> 1) & 3)) * 16;

  f32x4 acc[8][4];
#pragma unroll
  for (int i = 0; i < 8; ++i)
#pragma unroll
    for (int j = 0; j < 4; ++j) acc[i][j] = f32x4{0.f, 0.f, 0.f, 0.f};

#define STAGEQ(kt, bf)                                                      \
  {                                                                         \
    const int k0_ = (kt) * 32;                                              \
    gload16(aS + k0_, lds + (bf) * 32768 + tid * 16);                       \
    gload16(aS + 131072 + k0_, lds + (bf) * 32768 + 8192 + tid * 16);       \
    gload16(bS + k0_, lds + (bf) * 32768 + 16384 + tid * 16);               \
    gload16(bS + 131072 + k0_, lds + (bf) * 32768 + 24576 + tid * 16);      \
  }

  STAGEQ(0, 0); STAGEQ(1, 1); STAGEQ(2, 2);

  for (int kt = 0; kt < 32; ++kt) {
    if (kt < 30) WAITV(8);
    else if (kt == 30) WAITV(4);
    else WAITV(0);
    BARRIER();
    if (kt + 3 < 32) STAGEQ(kt + 3, (kt + 3) & 3);
    const char* aT = lds + (kt & 3) * 32768;
    const char* bT = aT + 16384;
    bf16x8 af[8], bfr[4];
#pragma unroll
    for (int mi = 0; mi < 8; ++mi)
      af[mi] = *(const bf16x8*)(aT + (wm * 128 + mi * 16 + r16) * 64 + sw);
#pragma unroll
    for (int ni = 0; ni < 4; ++ni)
      bfr[ni] = *(const bf16x8*)(bT + (wn * 64 + ni * 16 + r16) * 64 + sw);
    __builtin_amdgcn_s_setprio(1);
#pragma unroll
    for (int mi = 0; mi < 8; ++mi)
#pragma unroll
      for (int ni = 0; ni < 4; ++ni)
        acc[mi][ni] = __builtin_amdgcn_mfma_f32_16x16x32_bf16(af[mi], bfr[ni], acc[mi][ni], 0, 0, 0);
    __builtin_amdgcn_s_setprio(0);
  }
#undef STAGEQ

#pragma unroll
  for (int i = 0; i < 8; ++i)
#pragma unroll
    for (int j = 0; j < 4; ++j) {
      int row = m0 + wm * 128 + i * 16 + g4 * 4;
      int col = n0 + wn * 64 + j * 16 + r16;
      float bv = bias[col];
#pragma unroll
      for (int q = 0; q < 4; ++q)
        qb[(size_t)(row + q) * 1024 + col] = f2bf(acc[i][j][q] + bv);
    }
}

// ---------------- xE GEMM (256x128, BK=32, 3-stage, K=4096) ----------------
// which=0: xEk[b][kk][c] = sum_t Et[kk][t]*xT[b][c][t]
// which=1: xEv[b][kk][c] = sum_t Ft[kk][t]*xT[b][c][t]
// grid (4, 8, 8): m0 = bx*256 (kk), n0 = by*128 (c), z = (b,which)
__global__ __launch_bounds__(512, 2) void k_proj(const short* __restrict__ Et,
                                                 const short* __restrict__ Ft,
                                                 const short* __restrict__ xT,
                                                 short* __restrict__ xEk,
                                                 short* __restrict__ xEv) {
  const int z = blockIdx.z, b = z >> 1, which = z & 1;
  const short* __restrict__ AT = which ? Ft : Et;
  const short* __restrict__ BTp = xT + ((size_t)b << 10) * 4096;
  short* __restrict__ outp = which ? xEv : xEk;
  __shared__ __align__(16) char lds[3 * 24576];   // buf: A(256x32)@0, B(128x32)@+16384
  const int tid = threadIdx.x, l = tid & 63, wv = tid >> 6;
  const int wm = wv >> 1, wn = wv & 1;            // 4(M) x 2(N) waves, per-wave 64x64
  const int r16 = l & 15, g4 = l >> 4;
  const int m0 = blockIdx.x * 256, n0 = blockIdx.y * 128;
  const int sl = (tid & 3) ^ ((tid >> 3) & 3);
  const short* aS = AT + (size_t)(m0 + (tid >> 2)) * 4096 + sl * 8;
  const short* bS = BTp + (size_t)(n0 + (tid >> 2)) * 4096 + sl * 8;
  const int sw = (g4 ^ ((r16 >> 1) & 3)) * 16;

  f32x4 acc[4][4];
#pragma unroll
  for (int i = 0; i < 4; ++i)
#pragma unroll
    for (int j = 0; j < 4; ++j) acc[i][j] = f32x4{0.f, 0.f, 0.f, 0.f};

#define STAGE2(kt, bf)                                                      \
  {                                                                         \
    const int k0_ = (kt) * 32;                                              \
    gload16(aS + k0_, lds + (bf) * 24576 + tid * 16);                       \
    gload16(aS + 524288 + k0_, lds + (bf) * 24576 + 8192 + tid * 16);       \
    gload16(bS + k0_, lds + (bf) * 24576 + 16384 + tid * 16);               \
  }

  STAGE2(0, 0); STAGE2(1, 1);

  for (int kt = 0; kt < 128; ++kt) {
    if (kt < 127) WAITV(3);
    else WAITV(0);
    BARRIER();
    if (kt + 2 < 128) STAGE2(kt + 2, (kt + 2) % 3);
    const char* aT = lds + (kt % 3) * 24576;
    const char* bT = aT + 16384;
    bf16x8 af[4], bfr[4];
#pragma unroll
    for (int mi = 0; mi < 4; ++mi)
      af[mi] = *(const bf16x8*)(aT + (wm * 64 + mi * 16 + r16) * 64 + sw);
#pragma unroll
    for (int ni = 0; ni < 4; ++ni)
      bfr[ni] = *(const bf16x8*)(bT + (wn * 64 + ni * 16 + r16) * 64 + sw);
    __builtin_amdgcn_s_setprio(1);
#pragma unroll
    for (int mi = 0; mi < 4; ++mi)
#pragma unroll
      for (int ni = 0; ni < 4; ++ni)
        acc[mi][ni] = __builtin_amdgcn_mfma_f32_16x16x32_bf16(af[mi], bfr[ni], acc[mi][ni], 0, 0, 0);
    __builtin_amdgcn_s_setprio(0);
  }
#undef STAGE2

#pragma unroll
  for (int i = 0; i < 4; ++i)
#pragma unroll
    for (int j = 0; j < 4; ++j) {
      int row = m0 + wm * 64 + i * 16 + g4 * 4;   // kk
      int col = n0 + wn * 64 + j * 16 + r16;      // c
#pragma unroll
      for (int q = 0; q < 4; ++q)
        outp[((size_t)(b * 1024) + row + q) * 1024 + col] = f2bf(acc[i][j][q]);
    }
}

// ---------------- kp/vp GEMM: kp = (0.125*log2e)*(xEk@Wk + sE*bk); vpt transposed ----
__global__ __launch_bounds__(256, 2) void k_kpvp(const short* __restrict__ xEk,
                                                 const short* __restrict__ xEv,
                                                 const short* __restrict__ WaT,
                                                 const float* __restrict__ b_attn,
                                                 const float* __restrict__ sE,
                                                 const float* __restrict__ sF,
                                                 short* __restrict__ kp,
                                                 short* __restrict__ vpt) {
  const int which = blockIdx.z;
  const short* __restrict__ A = which ? xEv : xEk;
  const short* __restrict__ BT = WaT + (size_t)(1024 + which * 1024) * 1024;
  const float* __restrict__ bias = b_attn + 1024 + which * 1024;
  const float* __restrict__ rs = which ? sF : sE;
  __shared__ __align__(16) char lds[4 * 16384];
  const int tid = threadIdx.x, l = tid & 63, wv = tid >> 6;
  const int wm = wv >> 1, wn = wv & 1;
  const int r16 = l & 15, g4 = l >> 4;
  const int m0 = blockIdx.x * 128, n0 = blockIdx.y * 128;
  const int sl = (tid & 3) ^ ((tid >> 3) & 3);
  const short* aS = A + (size_t)(m0 + (tid >> 2)) * 1024 + sl * 8;
  const short* bS = BT + (size_t)(n0 + (tid >> 2)) * 1024 + sl * 8;
  const int sw = (g4 ^ ((r16 >> 1) & 3)) * 16;

  f32x4 acc[4][4];
#pragma unroll
  for (int i = 0; i < 4; ++i)
#pragma unroll
    for (int j = 0; j < 4; ++j) acc[i][j] = f32x4{0.f, 0.f, 0.f, 0.f};

#define STAGEP(kt, bf)                                                      \
  {                                                                         \
    const int k0_ = (kt) * 32;                                              \
    gload16(aS + k0_, lds + (bf) * 16384 + tid * 16);                       \
    gload16(aS + 65536 + k0_, lds + (bf) * 16384 + 4096 + tid * 16);        \
    gload16(bS + k0_, lds + (bf) * 16384 + 8192 + tid * 16);                \
    gload16(bS + 65536 + k0_, lds + (bf) * 16384 + 12288 + tid * 16);       \
  }

  STAGEP(0, 0); STAGEP(1, 1); STAGEP(2, 2);

  for (int kt = 0; kt < 32; ++kt) {
    if (kt < 30) WAITV(8);
    else if (kt == 30) WAITV(4);
    else WAITV(0);
    BARRIER();
    if (kt + 3 < 32) STAGEP(kt + 3, (kt + 3) & 3);
    const char* aT = lds + (kt & 3) * 16384;
    const char* bT = aT + 8192;
    bf16x8 af[4], bfr[4];
#pragma unroll
    for (int mi = 0; mi < 4; ++mi)
      af[mi] = *(const bf16x8*)(aT + (wm * 64 + mi * 16 + r16) * 64 + sw);
#pragma unroll
    for (int ni = 0; ni < 4; ++ni)
      bfr[ni] = *(const bf16x8*)(bT + (wn * 64 + ni * 16 + r16) * 64 + sw);
    __builtin_amdgcn_s_setprio(1);
#pragma unroll
    for (int mi = 0; mi < 4; ++mi)
#pragma unroll
      for (int ni = 0; ni < 4; ++ni)
        acc[mi][ni] = __builtin_amdgcn_mfma_f32_16x16x32_bf16(af[mi], bfr[ni], acc[mi][ni], 0, 0, 0);
    __builtin_amdgcn_s_setprio(0);
  }
#undef STAGEP

  if (which) {
#pragma unroll
    for (int i = 0; i < 4; ++i)
#pragma unroll
      for (int j = 0; j < 4; ++j) {
        int row = m0 + wm * 64 + i * 16 + g4 * 4;   // global (b,kk) row
        int col = n0 + wn * 64 + j * 16 + r16;
        int bb = row >> 10;
        float bv = bias[col];
        bf16x4 ov;
#pragma unroll
        for (int q = 0; q < 4; ++q)
          ov[q] = f2bf(acc[i][j][q] + rs[(row + q) & 1023] * bv);
        *reinterpret_cast<bf16x4*>(
            &vpt[(((size_t)bb << 10) + col) * 1024 + (row & 1023)]) = ov;
      }
  } else {
    const float KSCALE = 0.125f * 1.4426950408889634f;
#pragma unroll
    for (int i = 0; i < 4; ++i)
#pragma unroll
      for (int j = 0; j < 4; ++j) {
        int row = m0 + wm * 64 + i * 16 + g4 * 4;
        int col = n0 + wn * 64 + j * 16 + r16;
        float bv = bias[col];
#pragma unroll
        for (int q = 0; q < 4; ++q)
          kp[(size_t)(row + q) * 1024 + col] =
              f2bf((acc[i][j][q] + rs[(row + q) & 1023] * bv) * KSCALE);
      }
  }
}

// ---------------- Flash attention: swapped 32x32x16, no-max exp2 softmax,
//                  T14 async stage split; 3 blocks/CU (proven config) ----------
__global__ __launch_bounds__(256, 3) void k_attn(const short* __restrict__ qb,
                                                 const short* __restrict__ kp,
                                                 const short* __restrict__ vpt,
                                                 short* __restrict__ y) {
  __shared__ __align__(16) char KsB[128 * 128];   // [kk][d] swizzled, 16 KB
  __shared__ __align__(16) char VtB[64 * 256];    // [d][kk] swizzled, 16 KB
  const int tid = threadIdx.x, lane = tid & 63, w = tid >> 6;
  const int r32 = lane & 31, hi = lane >> 5;
  const int iblk = 31 - blockIdx.x;     // heavy blocks first
  const int bh = blockIdx.y, b = bh >> 4, h = bh & 15;
  const int t0 = iblk * 128;
  const int tl = w * 32 + r32;          // local row
  const int T = t0 + tl;                // global row (within b)

  bf16x8 qf[4];
#pragma unroll
  for (int kd = 0; kd < 4; ++kd)
    qf[kd] = *reinterpret_cast<const bf16x8*>(
        &qb[(size_t)(b * 4096 + T) * 1024 + h * 64 + kd * 16 + hi * 8]);

  f32x16 o[2];
#pragma unroll
  for (int i = 0; i < 16; ++i) { o[0][i] = 0.f; o[1][i] = 0.f; }
  float lrun = 0.f;

  const short* kpb = kp + ((size_t)b << 20) + h * 64;             // [kk][c]
  const short* vtb = vpt + (((size_t)b << 10) + h * 64) * 1024;   // [c][kk]

  const int kkl_ = tid >> 3, c8 = tid & 7;
  const int dl_ = tid >> 4, c16 = tid & 15;
  bf16x8 kreg[4], vreg[4];

#define LOADT(jt)                                                              \
  {                                                                            \
    const int kk0_ = (jt) * 128;                                               \
    _Pragma("unroll") for (int it = 0; it < 4; ++it) {                         \
      kreg[it] = *reinterpret_cast<const bf16x8*>(                             \
          &kpb[(size_t)(kk0_ + it * 32 + kkl_) * 1024 + c8 * 8]);              \
      vreg[it] = *reinterpret_cast<const bf16x8*>(                             \
          &vtb[(size_t)(it * 16 + dl_) * 1024 + kk0_ + c16 * 8]);              \
    }                                                                          \
  }

  LOADT(0);

  const int ntiles = (iblk + 1 < 8) ? (iblk + 1) : 8;
  for (int jt = 0; jt < ntiles; ++jt) {
    WAITV(0);        // prefetched regs valid
    BARRIER();       // all waves done reading previous tile's LDS
#pragma unroll
    for (int it = 0; it < 4; ++it) {
      int kk = it * 32 + kkl_;
      *reinterpret_cast<bf16x8*>(&KsB[kk * 128 + ((c8 * 16) ^ ((kk & 7) << 4))]) = kreg[it];
      int d = it * 16 + dl_;
      *reinterpret_cast<bf16x8*>(&VtB[d * 256 + ((c16 * 16) ^ ((d & 7) << 4))]) = vreg[it];
    }
    __syncthreads();                    // writes visible
    if (jt + 1 < ntiles) LOADT(jt + 1); // async: latency hides under compute below

#pragma unroll
    for (int st = 0; st < 2; ++st) {          // 64-kk sub-tiles
      f32x16 s[2];
#pragma unroll
      for (int i = 0; i < 16; ++i) { s[0][i] = 0.f; s[1][i] = 0.f; }
#pragma unroll
      for (int ni = 0; ni < 2; ++ni) {
        int row = (st * 2 + ni) * 32 + r32;
#pragma unroll
        for (int kd = 0; kd < 4; ++kd) {
          bf16x8 kf = *reinterpret_cast<const bf16x8*>(
              &KsB[row * 128 + ((kd * 32 + hi * 16) ^ ((row & 7) << 4))]);
          s[ni] = __builtin_amdgcn_mfma_f32_32x32x16_bf16(kf, qf[kd], s[ni], 0, 0, 0);
        }
      }

      if (jt == iblk) {  // causal mask on diagonal tile
#pragma unroll
        for (int ni = 0; ni < 2; ++ni)
#pragma unroll
          for (int j = 0; j < 16; ++j) {
            int kkl = (st * 2 + ni) * 32 + (j & 3) + 8 * (j >> 2) + 4 * hi;
            if (kkl > tl) s[ni][j] = -1e30f;
          }
      }

      // --- no-max softmax, exp2 domain (log2e folded into kp): P = exp2(S)
      float r0 = 0.f, r1 = 0.f, r2 = 0.f, r3 = 0.f;
#pragma unroll
      for (int j = 0; j < 16; j += 2) {
        float e0 = __builtin_amdgcn_exp2f(s[0][j]);
        float e1 = __builtin_amdgcn_exp2f(s[0][j + 1]);
        float e2 = __builtin_amdgcn_exp2f(s[1][j]);
        float e3 = __builtin_amdgcn_exp2f(s[1][j + 1]);
        s[0][j] = e0; s[0][j + 1] = e1; s[1][j] = e2; s[1][j + 1] = e3;
        r0 += e0; r1 += e1; r2 += e2; r3 += e3;
      }
      float rsum = (r0 + r1) + (r2 + r3);
      rsum += __shfl_xor(rsum, 32, 64);
      lrun += rsum;

      // --- pack P -> bf16 B-frags (cvtpk + permlane32_swap) and PV MFMA
#pragma unroll
      for (int kbl = 0; kbl < 4; ++kbl) {
        const int ni = kbl >> 1, jb = (kbl & 1) * 8;
        int lo0 = cvtpk(s[ni][jb + 0], s[ni][jb + 1]);
        int lo1 = cvtpk(s[ni][jb + 2], s[ni][jb + 3]);
        int hi0 = cvtpk(s[ni][jb + 4], s[ni][jb + 5]);
        int hi1 = cvtpk(s[ni][jb + 6], s[ni][jb + 7]);
        asm("v_permlane32_swap_b32 %0, %1" : "+v"(lo0), "+v"(hi0));
        asm("v_permlane32_swap_b32 %0, %1" : "+v"(lo1), "+v"(hi1));
        i32x4 pw; pw[0] = lo0; pw[1] = lo1; pw[2] = hi0; pw[3] = hi1;
        bf16x8 pf = __builtin_bit_cast(bf16x8, pw);
        const int kb = st * 4 + kbl;
#pragma unroll
        for (int mo = 0; mo < 2; ++mo) {
          int row = mo * 32 + r32;
          bf16x8 vf = *reinterpret_cast<const bf16x8*>(
              &VtB[row * 256 + ((kb * 32 + hi * 16) ^ ((row & 7) << 4))]);
          o[mo] = __builtin_amdgcn_mfma_f32_32x32x16_bf16(vf, pf, o[mo], 0, 0, 0);
        }
      }
    }
  }

  float inv = 1.0f / lrun;
#pragma unroll
  for (int mo = 0; mo < 2; ++mo)
#pragma unroll
    for (int rq = 0; rq < 4; ++rq) {
      bf16x4 ov;
#pragma unroll
      for (int c = 0; c < 4; ++c) ov[c] = f2bf(o[mo][rq * 4 + c] * inv);
      *reinterpret_cast<bf16x4*>(
          &y[(size_t)(b * 4096 + T) * 1024 + h * 64 + mo * 32 + rq * 8 + hi * 4]) = ov;
    }
#undef LOADT
}

// ---------------- GEMM2: out = y @ W_proj + b (256x256, BK=32, quad-buffered) --------
__global__ __launch_bounds__(512, 2) void k_gemm_out(const short* __restrict__ A,
                                                     const short* __restrict__ BT,
                                                     const float* __restrict__ bias,
                                                     float* __restrict__ C) {
  __shared__ __align__(16) char lds[4 * 32768];
  const int tid = threadIdx.x, l = tid & 63, wv = tid >> 6;
  const int wm = wv >> 2, wn = wv & 3;
  const int r16 = l & 15, g4 = l >> 4;
  const int orig = blockIdx.x;
  const int xcd = orig & 7, loc = orig >> 3;
  const int m0 = (xcd * 8 + (loc & 7)) * 256, n0 = (loc >> 3) * 256;
  const int sl = (tid & 3) ^ ((tid >> 3) & 3);
  const short* aS = A + (size_t)(m0 + (tid >> 2)) * 1024 + sl * 8;
  const short* bS = BT + (size_t)(n0 + (tid >> 2)) * 1024 + sl * 8;
  const int sw = (g4 ^ ((r16 >> 1) & 3)) * 16;

  f32x4 acc[8][4];
#pragma unroll
  for (int i = 0; i < 8; ++i)
#pragma unroll
    for (int j = 0; j < 4; ++j) acc[i][j] = f32x4{0.f, 0.f, 0.f, 0.f};

#define STAGE3(kt, bf)                                                      \
  {                                                                         \
    const int k0_ = (kt) * 32;                                              \
    gload16(aS + k0_, lds + (bf) * 32768 + tid * 16);                       \
    gload16(aS + 131072 + k0_, lds + (bf) * 32768 + 8192 + tid * 16);       \
    gload16(bS + k0_, lds + (bf) * 32768 + 16384 + tid * 16);               \
    gload16(bS + 131072 + k0_, lds + (bf) * 32768 + 24576 + tid * 16);      \
  }

  STAGE3(0, 0); STAGE3(1, 1); STAGE3(2, 2);

  for (int kt = 0; kt < 32; ++kt) {
    if (kt < 30) WAITV(8);
    else if (kt == 30) WAITV(4);
    else WAITV(0);
    BARRIER();
    if (kt + 3 < 32) STAGE3(kt + 3, (kt + 3) & 3);
    const char* aT = lds + (kt & 3) * 32768;
    const char* bT = aT + 16384;
    bf16x8 af[8], bfr[4];
#pragma unroll
    for (int mi = 0; mi < 8; ++mi)
      af[mi] = *(const bf16x8*)(aT + (wm * 128 + mi * 16 + r16) * 64 + sw);
#pragma unroll
    for (int ni = 0; ni < 4; ++ni)
      bfr[ni] = *(const bf16x8*)(bT + (wn * 64 + ni * 16 + r16) * 64 + sw);
    __builtin_amdgcn_s_setprio(1);
#pragma unroll
    for (int mi = 0; mi < 8; ++mi)
#pragma unroll
      for (int ni = 0; ni < 4; ++ni)
        acc[mi][ni] = __builtin_amdgcn_mfma_f32_16x16x32_bf16(af[mi], bfr[ni], acc[mi][ni], 0, 0, 0);
    __builtin_amdgcn_s_setprio(0);
  }
#undef STAGE3

#pragma unroll
  for (int i = 0; i < 8; ++i)
#pragma unroll
    for (int j = 0; j < 4; ++j) {
      int row = m0 + wm * 128 + i * 16 + g4 * 4;
      int col = n0 + wn * 64 + j * 16 + r16;
      float bv = bias[col];
#pragma unroll
      for (int q = 0; q < 4; ++q)
        C[(size_t)(row + q) * 1024 + col] = acc[i][j][q] + bv;
    }
}

extern "C" void kernel_launch(void* const* d_in, const int* in_sizes, int n_in,
                              void* d_out, int out_size, void* d_ws, size_t ws_size,
                              hipStream_t stream) {
  const float* x      = (const float*)d_in[0];
  const float* W_attn = (const float*)d_in[1];
  const float* b_attn = (const float*)d_in[2];
  const float* W_proj = (const float*)d_in[3];
  const float* b_proj = (const float*)d_in[4];
  const float* E      = (const float*)d_in[5];
  const float* F      = (const float*)d_in[6];
  float* out = (float*)d_out;

  char* ws = (char*)d_ws;
  short* xb  = (short*)(ws + 0);          //  32 MB: x bf16            (16384x1024)
  short* WaT = (short*)(ws + 33554432);   //   6 MB: W_attn^T bf16     (3072x1024)
  short* WpT = (short*)(ws + 39845888);   //   2 MB: W_proj^T bf16     (1024x1024)
  short* Et  = (short*)(ws + 41943040);   //   8 MB: E^T bf16          (1024x4096)
  short* Ft  = (short*)(ws + 50331648);   //   8 MB: F^T bf16          (1024x4096)
  short* qb  = (short*)(ws + 58720256);   //  32 MB: q bf16            (16384x1024)
  short* xTb = (short*)(ws + 92274688);   //  32 MB: x^T bf16          (4x1024x4096)
  short* xEk = (short*)(ws + 125829120);  //   8 MB: E^T@x bf16        (4x1024x1024)
  short* xEv = (short*)(ws + 134217728);  //   8 MB: F^T@x bf16        (4x1024x1024)
  short* kp  = (short*)(ws + 142606336);  //   8 MB: k_proj bf16       (4x1024x1024)
  short* vpt = (short*)(ws + 150994944);  //   8 MB: v_proj^T bf16     (4x1024x1024)
  short* yb  = (short*)(ws + 159383552);  //  32 MB: attn out bf16     (16384x1024)
  float* sE  = (float*)(ws + 192937984);  //   4 KB: colsum(E)
  float* sF  = (float*)(ws + 192942080);  //   4 KB: colsum(F)
  float* part= (float*)(ws + 192946176);  // 512 KB: colsum partials (2x64x1024)

  k_cvt_tr<<<dim3(32, 128, 4), 256, 0, stream>>>(x, xb, xTb);
  k_transpose_cvt<<<dim3(96, 32), 256, 0, stream>>>(W_attn, WaT, 1024, 3072);
  k_transpose_cvt<<<dim3(32, 32), 256, 0, stream>>>(W_proj, WpT, 1024, 1024);
  k_transpose_cvt<<<dim3(32, 128), 256, 0, stream>>>(E, Et, 4096, 1024);
  k_transpose_cvt<<<dim3(32, 128), 256, 0, stream>>>(F, Ft, 4096, 1024);
  k_colsum1<<<dim3(4, 64, 2), 256, 0, stream>>>(E, F, part);
  k_colsum2<<<8, 256, 0, stream>>>(part, sE, sF);

  k_gemm_q<<<256, 512, 0, stream>>>(xb, WaT, b_attn, qb);
  k_proj<<<dim3(4, 8, 8), 512, 0, stream>>>(Et, Ft, xTb, xEk, xEv);
  k_kpvp<<<dim3(32, 8, 2), 256, 0, stream>>>(xEk, xEv, WaT, b_attn, sE, sF, kp, vpt);
  k_attn<<<dim3(32, 64), 256, 0, stream>>>(qb, kp, vpt, yb);
  k_gemm_out<<<256, 512, 0, stream>>>(yb, WpT, b_proj, out);
}

// Round 19
// 321.554 us; speedup vs baseline: 1.3049x; 1.0013x over previous
//
#include <hip/hip_runtime.h>
#include <stdint.h>

typedef short bf16x8 __attribute__((ext_vector_type(8)));
typedef short bf16x4 __attribute__((ext_vector_type(4)));
typedef float f32x4 __attribute__((ext_vector_type(4)));
typedef float f32x16 __attribute__((ext_vector_type(16)));
typedef int i32x4 __attribute__((ext_vector_type(4)));

__device__ __forceinline__ short f2bf(float f) {
  union { float f; uint32_t u; } v; v.f = f;
  uint32_t r = (v.u + 0x7FFFu + ((v.u >> 16) & 1u)) >> 16;
  return (short)(uint16_t)r;
}

__device__ __forceinline__ int cvtpk(float lo, float hi) {
  int r;
  asm("v_cvt_pk_bf16_f32 %0, %1, %2" : "=v"(r) : "v"(lo), "v"(hi));
  return r;
}

// async global->LDS, 16B per lane; LDS dest must be linear in lane order
__device__ __forceinline__ void gload16(const void* g, void* l) {
  __builtin_amdgcn_global_load_lds(
      (const __attribute__((address_space(1))) unsigned int*)g,
      (__attribute__((address_space(3))) unsigned int*)l, 16, 0, 0);
}

#define WAITV(n) asm volatile("s_waitcnt vmcnt(" #n ")" ::: "memory")
#define BARRIER()                          \
  do {                                     \
    __builtin_amdgcn_s_barrier();          \
    asm volatile("" ::: "memory");         \
  } while (0)

// ---------------- fused: xb = bf16(x), xT = bf16(x)^T (per batch) ----------------
__global__ __launch_bounds__(256) void k_cvt_tr(const float* __restrict__ in,
                                                short* __restrict__ xb,
                                                short* __restrict__ xT) {
  __shared__ short tile[32][34];
  const int b = blockIdx.z;
  const int t0 = blockIdx.y * 32, c0 = blockIdx.x * 32;
  const int tx = threadIdx.x & 31, ty = threadIdx.x >> 5;
  const float* src = in + ((size_t)b * 4096 + t0) * 1024 + c0;
  short* dstA = xb + ((size_t)b * 4096 + t0) * 1024 + c0;
#pragma unroll
  for (int j = 0; j < 4; ++j) {
    int r = ty + j * 8;
    short bv = f2bf(src[(size_t)r * 1024 + tx]);
    dstA[(size_t)r * 1024 + tx] = bv;
    tile[tx][r] = bv;
  }
  __syncthreads();
  short* dstT = xT + ((size_t)b * 1024 + c0) * 4096 + t0;
#pragma unroll
  for (int j = 0; j < 4; ++j) {
    int c = ty + j * 8;
    dstT[(size_t)c * 4096 + tx] = tile[c][tx];
  }
}

// ---------------- transpose + convert: out[C][R] = bf16(in[R][C]) ----------------
__global__ __launch_bounds__(256) void k_transpose_cvt(const float* __restrict__ in,
                                                       short* __restrict__ out,
                                                       int R, int C) {
  __shared__ float tile[32][33];
  int r0 = blockIdx.y * 32, c0 = blockIdx.x * 32;
  int tx = threadIdx.x & 31, ty = threadIdx.x >> 5;
#pragma unroll
  for (int j = 0; j < 4; ++j)
    tile[ty + j * 8][tx] = in[(size_t)(r0 + ty + j * 8) * C + c0 + tx];
  __syncthreads();
#pragma unroll
  for (int j = 0; j < 4; ++j)
    out[(size_t)(c0 + ty + j * 8) * R + r0 + tx] = f2bf(tile[tx][ty + j * 8]);
}

// ---------------- column sums, two-stage deterministic reduction ----------------
__global__ __launch_bounds__(256) void k_colsum1(const float* __restrict__ E,
                                                 const float* __restrict__ F,
                                                 float* __restrict__ partial) {
  const int c = blockIdx.x * 256 + threadIdx.x;
  const int tc = blockIdx.y, which = blockIdx.z;
  const float* src = (which ? F : E) + (size_t)(tc * 64) * 1024 + c;
  float s = 0.f;
#pragma unroll 8
  for (int t = 0; t < 64; ++t) s += src[(size_t)t * 1024];
  partial[((size_t)which * 64 + tc) * 1024 + c] = s;
}

__global__ __launch_bounds__(256) void k_colsum2(const float* __restrict__ partial,
                                                 float* __restrict__ sE,
                                                 float* __restrict__ sF) {
  const int bid = blockIdx.x;
  const int which = bid >> 2, c = (bid & 3) * 256 + threadIdx.x;
  const float* p = partial + (size_t)which * 64 * 1024 + c;
  float s = 0.f;
#pragma unroll 8
  for (int t = 0; t < 64; ++t) s += p[(size_t)t * 1024];
  (which ? sF : sE)[c] = s;
}

// ---------------- GEMM_q: qb = x @ Wq + bq  (256x256, BK=32, quad-buffered) ----------
__global__ __launch_bounds__(512, 2) void k_gemm_q(const short* __restrict__ A,
                                                   const short* __restrict__ BT,
                                                   const float* __restrict__ bias,
                                                   short* __restrict__ qb) {
  __shared__ __align__(16) char lds[4 * 32768];
  const int tid = threadIdx.x, l = tid & 63, wv = tid >> 6;
  const int wm = wv >> 2, wn = wv & 3;
  const int r16 = l & 15, g4 = l >> 4;
  const int orig = blockIdx.x;
  const int xcd = orig & 7, loc = orig >> 3;
  const int m0 = (xcd * 8 + (loc & 7)) * 256, n0 = (loc >> 3) * 256;
  const int sl = (tid & 3) ^ ((tid >> 3) & 3);
  const short* aS = A + (size_t)(m0 + (tid >> 2)) * 1024 + sl * 8;
  const short* bS = BT + (size_t)(n0 + (tid >> 2)) * 1024 + sl * 8;
  const int sw = (g4 ^ ((r16 >> 1) & 3)) * 16;

  f32x4 acc[8][4];
#pragma unroll
  for (int i = 0; i < 8; ++i)
#pragma unroll
    for (int j = 0; j < 4; ++j) acc[i][j] = f32x4{0.f, 0.f, 0.f, 0.f};

#define STAGEQ(kt, bf)                                                      \
  {                                                                         \
    const int k0_ = (kt) * 32;                                              \
    gload16(aS + k0_, lds + (bf) * 32768 + tid * 16);                       \
    gload16(aS + 131072 + k0_, lds + (bf) * 32768 + 8192 + tid * 16);       \
    gload16(bS + k0_, lds + (bf) * 32768 + 16384 + tid * 16);               \
    gload16(bS + 131072 + k0_, lds + (bf) * 32768 + 24576 + tid * 16);      \
  }

  STAGEQ(0, 0); STAGEQ(1, 1); STAGEQ(2, 2);

  for (int kt = 0; kt < 32; ++kt) {
    if (kt < 30) WAITV(8);
    else if (kt == 30) WAITV(4);
    else WAITV(0);
    BARRIER();
    if (kt + 3 < 32) STAGEQ(kt + 3, (kt + 3) & 3);
    const char* aT = lds + (kt & 3) * 32768;
    const char* bT = aT + 16384;
    bf16x8 af[8], bfr[4];
#pragma unroll
    for (int mi = 0; mi < 8; ++mi)
      af[mi] = *(const bf16x8*)(aT + (wm * 128 + mi * 16 + r16) * 64 + sw);
#pragma unroll
    for (int ni = 0; ni < 4; ++ni)
      bfr[ni] = *(const bf16x8*)(bT + (wn * 64 + ni * 16 + r16) * 64 + sw);
    __builtin_amdgcn_s_setprio(1);
#pragma unroll
    for (int mi = 0; mi < 8; ++mi)
#pragma unroll
      for (int ni = 0; ni < 4; ++ni)
        acc[mi][ni] = __builtin_amdgcn_mfma_f32_16x16x32_bf16(af[mi], bfr[ni], acc[mi][ni], 0, 0, 0);
    __builtin_amdgcn_s_setprio(0);
  }
#undef STAGEQ

#pragma unroll
  for (int i = 0; i < 8; ++i)
#pragma unroll
    for (int j = 0; j < 4; ++j) {
      int row = m0 + wm * 128 + i * 16 + g4 * 4;
      int col = n0 + wn * 64 + j * 16 + r16;
      float bv = bias[col];
#pragma unroll
      for (int q = 0; q < 4; ++q)
        qb[(size_t)(row + q) * 1024 + col] = f2bf(acc[i][j][q] + bv);
    }
}

// ---------------- xE GEMM (256x128, BK=32, 3-stage, K=4096) ----------------
__global__ __launch_bounds__(512, 2) void k_proj(const short* __restrict__ Et,
                                                 const short* __restrict__ Ft,
                                                 const short* __restrict__ xT,
                                                 short* __restrict__ xEk,
                                                 short* __restrict__ xEv) {
  const int z = blockIdx.z, b = z >> 1, which = z & 1;
  const short* __restrict__ AT = which ? Ft : Et;
  const short* __restrict__ BTp = xT + ((size_t)b << 10) * 4096;
  short* __restrict__ outp = which ? xEv : xEk;
  __shared__ __align__(16) char lds[3 * 24576];
  const int tid = threadIdx.x, l = tid & 63, wv = tid >> 6;
  const int wm = wv >> 1, wn = wv & 1;
  const int r16 = l & 15, g4 = l >> 4;
  const int m0 = blockIdx.x * 256, n0 = blockIdx.y * 128;
  const int sl = (tid & 3) ^ ((tid >> 3) & 3);
  const short* aS = AT + (size_t)(m0 + (tid >> 2)) * 4096 + sl * 8;
  const short* bS = BTp + (size_t)(n0 + (tid >> 2)) * 4096 + sl * 8;
  const int sw = (g4 ^ ((r16 >> 1) & 3)) * 16;

  f32x4 acc[4][4];
#pragma unroll
  for (int i = 0; i < 4; ++i)
#pragma unroll
    for (int j = 0; j < 4; ++j) acc[i][j] = f32x4{0.f, 0.f, 0.f, 0.f};

#define STAGE2(kt, bf)                                                      \
  {                                                                         \
    const int k0_ = (kt) * 32;                                              \
    gload16(aS + k0_, lds + (bf) * 24576 + tid * 16);                       \
    gload16(aS + 524288 + k0_, lds + (bf) * 24576 + 8192 + tid * 16);       \
    gload16(bS + k0_, lds + (bf) * 24576 + 16384 + tid * 16);               \
  }

  STAGE2(0, 0); STAGE2(1, 1);

  for (int kt = 0; kt < 128; ++kt) {
    if (kt < 127) WAITV(3);
    else WAITV(0);
    BARRIER();
    if (kt + 2 < 128) STAGE2(kt + 2, (kt + 2) % 3);
    const char* aT = lds + (kt % 3) * 24576;
    const char* bT = aT + 16384;
    bf16x8 af[4], bfr[4];
#pragma unroll
    for (int mi = 0; mi < 4; ++mi)
      af[mi] = *(const bf16x8*)(aT + (wm * 64 + mi * 16 + r16) * 64 + sw);
#pragma unroll
    for (int ni = 0; ni < 4; ++ni)
      bfr[ni] = *(const bf16x8*)(bT + (wn * 64 + ni * 16 + r16) * 64 + sw);
    __builtin_amdgcn_s_setprio(1);
#pragma unroll
    for (int mi = 0; mi < 4; ++mi)
#pragma unroll
      for (int ni = 0; ni < 4; ++ni)
        acc[mi][ni] = __builtin_amdgcn_mfma_f32_16x16x32_bf16(af[mi], bfr[ni], acc[mi][ni], 0, 0, 0);
    __builtin_amdgcn_s_setprio(0);
  }
#undef STAGE2

#pragma unroll
  for (int i = 0; i < 4; ++i)
#pragma unroll
    for (int j = 0; j < 4; ++j) {
      int row = m0 + wm * 64 + i * 16 + g4 * 4;   // kk
      int col = n0 + wn * 64 + j * 16 + r16;      // c
#pragma unroll
      for (int q = 0; q < 4; ++q)
        outp[((size_t)(b * 1024) + row + q) * 1024 + col] = f2bf(acc[i][j][q]);
    }
}

// ---------------- kp/vp GEMM: kp = (0.125*log2e)*(xEk@Wk + sE*bk); vpt transposed ----
__global__ __launch_bounds__(256, 2) void k_kpvp(const short* __restrict__ xEk,
                                                 const short* __restrict__ xEv,
                                                 const short* __restrict__ WaT,
                                                 const float* __restrict__ b_attn,
                                                 const float* __restrict__ sE,
                                                 const float* __restrict__ sF,
                                                 short* __restrict__ kp,
                                                 short* __restrict__ vpt) {
  const int which = blockIdx.z;
  const short* __restrict__ A = which ? xEv : xEk;
  const short* __restrict__ BT = WaT + (size_t)(1024 + which * 1024) * 1024;
  const float* __restrict__ bias = b_attn + 1024 + which * 1024;
  const float* __restrict__ rs = which ? sF : sE;
  __shared__ __align__(16) char lds[4 * 16384];
  const int tid = threadIdx.x, l = tid & 63, wv = tid >> 6;
  const int wm = wv >> 1, wn = wv & 1;
  const int r16 = l & 15, g4 = l >> 4;
  const int m0 = blockIdx.x * 128, n0 = blockIdx.y * 128;
  const int sl = (tid & 3) ^ ((tid >> 3) & 3);
  const short* aS = A + (size_t)(m0 + (tid >> 2)) * 1024 + sl * 8;
  const short* bS = BT + (size_t)(n0 + (tid >> 2)) * 1024 + sl * 8;
  const int sw = (g4 ^ ((r16 >> 1) & 3)) * 16;

  f32x4 acc[4][4];
#pragma unroll
  for (int i = 0; i < 4; ++i)
#pragma unroll
    for (int j = 0; j < 4; ++j) acc[i][j] = f32x4{0.f, 0.f, 0.f, 0.f};

#define STAGEP(kt, bf)                                                      \
  {                                                                         \
    const int k0_ = (kt) * 32;                                              \
    gload16(aS + k0_, lds + (bf) * 16384 + tid * 16);                       \
    gload16(aS + 65536 + k0_, lds + (bf) * 16384 + 4096 + tid * 16);        \
    gload16(bS + k0_, lds + (bf) * 16384 + 8192 + tid * 16);                \
    gload16(bS + 65536 + k0_, lds + (bf) * 16384 + 12288 + tid * 16);       \
  }

  STAGEP(0, 0); STAGEP(1, 1); STAGEP(2, 2);

  for (int kt = 0; kt < 32; ++kt) {
    if (kt < 30) WAITV(8);
    else if (kt == 30) WAITV(4);
    else WAITV(0);
    BARRIER();
    if (kt + 3 < 32) STAGEP(kt + 3, (kt + 3) & 3);
    const char* aT = lds + (kt & 3) * 16384;
    const char* bT = aT + 8192;
    bf16x8 af[4], bfr[4];
#pragma unroll
    for (int mi = 0; mi < 4; ++mi)
      af[mi] = *(const bf16x8*)(aT + (wm * 64 + mi * 16 + r16) * 64 + sw);
#pragma unroll
    for (int ni = 0; ni < 4; ++ni)
      bfr[ni] = *(const bf16x8*)(bT + (wn * 64 + ni * 16 + r16) * 64 + sw);
    __builtin_amdgcn_s_setprio(1);
#pragma unroll
    for (int mi = 0; mi < 4; ++mi)
#pragma unroll
      for (int ni = 0; ni < 4; ++ni)
        acc[mi][ni] = __builtin_amdgcn_mfma_f32_16x16x32_bf16(af[mi], bfr[ni], acc[mi][ni], 0, 0, 0);
    __builtin_amdgcn_s_setprio(0);
  }
#undef STAGEP

  if (which) {
#pragma unroll
    for (int i = 0; i < 4; ++i)
#pragma unroll
      for (int j = 0; j < 4; ++j) {
        int row = m0 + wm * 64 + i * 16 + g4 * 4;   // global (b,kk) row
        int col = n0 + wn * 64 + j * 16 + r16;
        int bb = row >> 10;
        float bv = bias[col];
        bf16x4 ov;
#pragma unroll
        for (int q = 0; q < 4; ++q)
          ov[q] = f2bf(acc[i][j][q] + rs[(row + q) & 1023] * bv);
        *reinterpret_cast<bf16x4*>(
            &vpt[(((size_t)bb << 10) + col) * 1024 + (row & 1023)]) = ov;
      }
  } else {
    const float KSCALE = 0.125f * 1.4426950408889634f;
#pragma unroll
    for (int i = 0; i < 4; ++i)
#pragma unroll
      for (int j = 0; j < 4; ++j) {
        int row = m0 + wm * 64 + i * 16 + g4 * 4;
        int col = n0 + wn * 64 + j * 16 + r16;
        float bv = bias[col];
#pragma unroll
        for (int q = 0; q < 4; ++q)
          kp[(size_t)(row + q) * 1024 + col] =
              f2bf((acc[i][j][q] + rs[(row + q) & 1023] * bv) * KSCALE);
      }
  }
}

// ---------------- Flash attention: 256 Q-rows/block (2 row-groups share K/V tiles),
//                  swapped 32x32x16, no-max exp2 softmax, T14 async stage ----------
__global__ __launch_bounds__(256, 2) void k_attn(const short* __restrict__ qb,
                                                 const short* __restrict__ kp,
                                                 const short* __restrict__ vpt,
                                                 short* __restrict__ y) {
  __shared__ __align__(16) char KsB[128 * 128];   // [kk][d] swizzled, 16 KB
  __shared__ __align__(16) char VtB[64 * 256];    // [d][kk] swizzled, 16 KB
  const int tid = threadIdx.x, lane = tid & 63, w = tid >> 6;
  const int r32 = lane & 31, hi = lane >> 5;
  const int iblk = 15 - blockIdx.x;     // heavy blocks first
  const int bh = blockIdx.y, b = bh >> 4, h = bh & 15;
  const int t0 = iblk * 256;
  const int tl = w * 32 + r32;          // row within a 128-row group

  bf16x8 qf[2][4];
#pragma unroll
  for (int rg = 0; rg < 2; ++rg)
#pragma unroll
    for (int kd = 0; kd < 4; ++kd)
      qf[rg][kd] = *reinterpret_cast<const bf16x8*>(
          &qb[(size_t)(b * 4096 + t0 + rg * 128 + tl) * 1024 + h * 64 + kd * 16 + hi * 8]);

  f32x16 o[2][2];
#pragma unroll
  for (int rg = 0; rg < 2; ++rg)
#pragma unroll
    for (int i = 0; i < 16; ++i) { o[rg][0][i] = 0.f; o[rg][1][i] = 0.f; }
  float lr0 = 0.f, lr1 = 0.f;

  const short* kpb = kp + ((size_t)b << 20) + h * 64;             // [kk][c]
  const short* vtb = vpt + (((size_t)b << 10) + h * 64) * 1024;   // [c][kk]

  const int kkl_ = tid >> 3, c8 = tid & 7;
  const int dl_ = tid >> 4, c16 = tid & 15;
  bf16x8 kreg[4], vreg[4];

#define LOADT(jt)                                                              \
  {                                                                            \
    const int kk0_ = (jt) * 128;                                               \
    _Pragma("unroll") for (int it = 0; it < 4; ++it) {                         \
      kreg[it] = *reinterpret_cast<const bf16x8*>(                             \
          &kpb[(size_t)(kk0_ + it * 32 + kkl_) * 1024 + c8 * 8]);              \
      vreg[it] = *reinterpret_cast<const bf16x8*>(                             \
          &vtb[(size_t)(it * 16 + dl_) * 1024 + kk0_ + c16 * 8]);              \
    }                                                                          \
  }

// one 128-row group's compute for tile jt
#define ATT_RG(RG, LRUN)                                                       \
  {                                                                            \
    f32x16 s[2];                                                               \
    _Pragma("unroll") for (int st = 0; st < 2; ++st) {                         \
      _Pragma("unroll") for (int i = 0; i < 16; ++i) { s[0][i] = 0.f; s[1][i] = 0.f; } \
      _Pragma("unroll") for (int ni = 0; ni < 2; ++ni) {                       \
        int row = (st * 2 + ni) * 32 + r32;                                    \
        _Pragma("unroll") for (int kd = 0; kd < 4; ++kd) {                     \
          bf16x8 kf = *reinterpret_cast<const bf16x8*>(                        \
              &KsB[row * 128 + ((kd * 32 + hi * 16) ^ ((row & 7) << 4))]);     \
          s[ni] = __builtin_amdgcn_mfma_f32_32x32x16_bf16(kf, qf[RG][kd], s[ni], 0, 0, 0); \
        }                                                                      \
      }                                                                        \
      if (jt == 2 * iblk + RG) {                                               \
        _Pragma("unroll") for (int ni = 0; ni < 2; ++ni)                       \
          _Pragma("unroll") for (int j = 0; j < 16; ++j) {                     \
            int kkl = (st * 2 + ni) * 32 + (j & 3) + 8 * (j >> 2) + 4 * hi;    \
            if (kkl > tl) s[ni][j] = -1e30f;                                   \
          }                                                                    \
      }                                                                        \
      float r0 = 0.f, r1 = 0.f, r2 = 0.f, r3 = 0.f;                            \
      _Pragma("unroll") for (int j = 0; j < 16; j += 2) {                      \
        float e0 = __builtin_amdgcn_exp2f(s[0][j]);                            \
        float e1 = __builtin_amdgcn_exp2f(s[0][j + 1]);                        \
        float e2 = __builtin_amdgcn_exp2f(s[1][j]);                            \
        float e3 = __builtin_amdgcn_exp2f(s[1][j + 1]);                        \
        s[0][j] = e0; s[0][j + 1] = e1; s[1][j] = e2; s[1][j + 1] = e3;        \
        r0 += e0; r1 += e1; r2 += e2; r3 += e3;                                \
      }                                                                        \
      float rsum = (r0 + r1) + (r2 + r3);                                      \
      rsum += __shfl_xor(rsum, 32, 64);                                        \
      LRUN += rsum;                                                            \
      _Pragma("unroll") for (int kbl = 0; kbl < 4; ++kbl) {                    \
        const int ni = kbl >> 1, jb = (kbl & 1) * 8;                           \
        int lo0 = cvtpk(s[ni][jb + 0], s[ni][jb + 1]);                         \
        int lo1 = cvtpk(s[ni][jb + 2], s[ni][jb + 3]);                         \
        int hi0 = cvtpk(s[ni][jb + 4], s[ni][jb + 5]);                         \
        int hi1 = cvtpk(s[ni][jb + 6], s[ni][jb + 7]);                         \
        asm("v_permlane32_swap_b32 %0, %1" : "+v"(lo0), "+v"(hi0));            \
        asm("v_permlane32_swap_b32 %0, %1" : "+v"(lo1), "+v"(hi1));            \
        i32x4 pw; pw[0] = lo0; pw[1] = lo1; pw[2] = hi0; pw[3] = hi1;          \
        bf16x8 pf = __builtin_bit_cast(bf16x8, pw);                            \
        const int kb = st * 4 + kbl;                                           \
        _Pragma("unroll") for (int mo = 0; mo < 2; ++mo) {                     \
          int row = mo * 32 + r32;                                             \
          bf16x8 vf = *reinterpret_cast<const bf16x8*>(                        \
              &VtB[row * 256 + ((kb * 32 + hi * 16) ^ ((row & 7) << 4))]);     \
          o[RG][mo] = __builtin_amdgcn_mfma_f32_32x32x16_bf16(vf, pf, o[RG][mo], 0, 0, 0); \
        }                                                                      \
      }                                                                        \
    }                                                                          \
  }

  LOADT(0);

  const int ntiles = (2 * iblk + 2 < 8) ? (2 * iblk + 2) : 8;
  for (int jt = 0; jt < ntiles; ++jt) {
    WAITV(0);        // prefetched regs valid
    BARRIER();       // all waves done reading previous tile's LDS
#pragma unroll
    for (int it = 0; it < 4; ++it) {
      int kk = it * 32 + kkl_;
      *reinterpret_cast<bf16x8*>(&KsB[kk * 128 + ((c8 * 16) ^ ((kk & 7) << 4))]) = kreg[it];
      int d = it * 16 + dl_;
      *reinterpret_cast<bf16x8*>(&VtB[d * 256 + ((c16 * 16) ^ ((d & 7) << 4))]) = vreg[it];
    }
    __syncthreads();                    // writes visible

    if (jt <= 2 * iblk) ATT_RG(0, lr0);           // rg0 causal window
    if (jt + 1 < ntiles) LOADT(jt + 1);           // hide HBM/L2 latency under rg1
    ATT_RG(1, lr1);                               // rg1 always in window (jt < ntiles)
  }

  // epilogue both row-groups
#pragma unroll
  for (int rg = 0; rg < 2; ++rg) {
    float lr = rg ? lr1 : lr0;
    float inv = 1.0f / lr;
    const int T = t0 + rg * 128 + tl;
#pragma unroll
    for (int mo = 0; mo < 2; ++mo)
#pragma unroll
      for (int rq = 0; rq < 4; ++rq) {
        bf16x4 ov;
#pragma unroll
        for (int c = 0; c < 4; ++c) ov[c] = f2bf(o[rg][mo][rq * 4 + c] * inv);
        *reinterpret_cast<bf16x4*>(
            &y[(size_t)(b * 4096 + T) * 1024 + h * 64 + mo * 32 + rq * 8 + hi * 4]) = ov;
      }
  }
#undef ATT_RG
#undef LOADT
}

// ---------------- GEMM2: out = y @ W_proj + b (256x256, BK=32, quad-buffered) --------
__global__ __launch_bounds__(512, 2) void k_gemm_out(const short* __restrict__ A,
                                                     const short* __restrict__ BT,
                                                     const float* __restrict__ bias,
                                                     float* __restrict__ C) {
  __shared__ __align__(16) char lds[4 * 32768];
  const int tid = threadIdx.x, l = tid & 63, wv = tid >> 6;
  const int wm = wv >> 2, wn = wv & 3;
  const int r16 = l & 15, g4 = l >> 4;
  const int orig = blockIdx.x;
  const int xcd = orig & 7, loc = orig >> 3;
  const int m0 = (xcd * 8 + (loc & 7)) * 256, n0 = (loc >> 3) * 256;
  const int sl = (tid & 3) ^ ((tid >> 3) & 3);
  const short* aS = A + (size_t)(m0 + (tid >> 2)) * 1024 + sl * 8;
  const short* bS = BT + (size_t)(n0 + (tid >> 2)) * 1024 + sl * 8;
  const int sw = (g4 ^ ((r16 >> 1) & 3)) * 16;

  f32x4 acc[8][4];
#pragma unroll
  for (int i = 0; i < 8; ++i)
#pragma unroll
    for (int j = 0; j < 4; ++j) acc[i][j] = f32x4{0.f, 0.f, 0.f, 0.f};

#define STAGE3(kt, bf)                                                      \
  {                                                                         \
    const int k0_ = (kt) * 32;                                              \
    gload16(aS + k0_, lds + (bf) * 32768 + tid * 16);                       \
    gload16(aS + 131072 + k0_, lds + (bf) * 32768 + 8192 + tid * 16);       \
    gload16(bS + k0_, lds + (bf) * 32768 + 16384 + tid * 16);               \
    gload16(bS + 131072 + k0_, lds + (bf) * 32768 + 24576 + tid * 16);      \
  }

  STAGE3(0, 0); STAGE3(1, 1); STAGE3(2, 2);

  for (int kt = 0; kt < 32; ++kt) {
    if (kt < 30) WAITV(8);
    else if (kt == 30) WAITV(4);
    else WAITV(0);
    BARRIER();
    if (kt + 3 < 32) STAGE3(kt + 3, (kt + 3) & 3);
    const char* aT = lds + (kt & 3) * 32768;
    const char* bT = aT + 16384;
    bf16x8 af[8], bfr[4];
#pragma unroll
    for (int mi = 0; mi < 8; ++mi)
      af[mi] = *(const bf16x8*)(aT + (wm * 128 + mi * 16 + r16) * 64 + sw);
#pragma unroll
    for (int ni = 0; ni < 4; ++ni)
      bfr[ni] = *(const bf16x8*)(bT + (wn * 64 + ni * 16 + r16) * 64 + sw);
    __builtin_amdgcn_s_setprio(1);
#pragma unroll
    for (int mi = 0; mi < 8; ++mi)
#pragma unroll
      for (int ni = 0; ni < 4; ++ni)
        acc[mi][ni] = __builtin_amdgcn_mfma_f32_16x16x32_bf16(af[mi], bfr[ni], acc[mi][ni], 0, 0, 0);
    __builtin_amdgcn_s_setprio(0);
  }
#undef STAGE3

#pragma unroll
  for (int i = 0; i < 8; ++i)
#pragma unroll
    for (int j = 0; j < 4; ++j) {
      int row = m0 + wm * 128 + i * 16 + g4 * 4;
      int col = n0 + wn * 64 + j * 16 + r16;
      float bv = bias[col];
#pragma unroll
      for (int q = 0; q < 4; ++q)
        C[(size_t)(row + q) * 1024 + col] = acc[i][j][q] + bv;
    }
}

extern "C" void kernel_launch(void* const* d_in, const int* in_sizes, int n_in,
                              void* d_out, int out_size, void* d_ws, size_t ws_size,
                              hipStream_t stream) {
  const float* x      = (const float*)d_in[0];
  const float* W_attn = (const float*)d_in[1];
  const float* b_attn = (const float*)d_in[2];
  const float* W_proj = (const float*)d_in[3];
  const float* b_proj = (const float*)d_in[4];
  const float* E      = (const float*)d_in[5];
  const float* F      = (const float*)d_in[6];
  float* out = (float*)d_out;

  char* ws = (char*)d_ws;
  short* xb  = (short*)(ws + 0);          //  32 MB: x bf16            (16384x1024)
  short* WaT = (short*)(ws + 33554432);   //   6 MB: W_attn^T bf16     (3072x1024)
  short* WpT = (short*)(ws + 39845888);   //   2 MB: W_proj^T bf16     (1024x1024)
  short* Et  = (short*)(ws + 41943040);   //   8 MB: E^T bf16          (1024x4096)
  short* Ft  = (short*)(ws + 50331648);   //   8 MB: F^T bf16          (1024x4096)
  short* qb  = (short*)(ws + 58720256);   //  32 MB: q bf16            (16384x1024)
  short* xTb = (short*)(ws + 92274688);   //  32 MB: x^T bf16          (4x1024x4096)
  short* xEk = (short*)(ws + 125829120);  //   8 MB: E^T@x bf16        (4x1024x1024)
  short* xEv = (short*)(ws + 134217728);  //   8 MB: F^T@x bf16        (4x1024x1024)
  short* kp  = (short*)(ws + 142606336);  //   8 MB: k_proj bf16       (4x1024x1024)
  short* vpt = (short*)(ws + 150994944);  //   8 MB: v_proj^T bf16     (4x1024x1024)
  short* yb  = (short*)(ws + 159383552);  //  32 MB: attn out bf16     (16384x1024)
  float* sE  = (float*)(ws + 192937984);  //   4 KB: colsum(E)
  float* sF  = (float*)(ws + 192942080);  //   4 KB: colsum(F)
  float* part= (float*)(ws + 192946176);  // 512 KB: colsum partials (2x64x1024)

  k_cvt_tr<<<dim3(32, 128, 4), 256, 0, stream>>>(x, xb, xTb);
  k_transpose_cvt<<<dim3(96, 32), 256, 0, stream>>>(W_attn, WaT, 1024, 3072);
  k_transpose_cvt<<<dim3(32, 32), 256, 0, stream>>>(W_proj, WpT, 1024, 1024);
  k_transpose_cvt<<<dim3(32, 128), 256, 0, stream>>>(E, Et, 4096, 1024);
  k_transpose_cvt<<<dim3(32, 128), 256, 0, stream>>>(F, Ft, 4096, 1024);
  k_colsum1<<<dim3(4, 64, 2), 256, 0, stream>>>(E, F, part);
  k_colsum2<<<8, 256, 0, stream>>>(part, sE, sF);

  k_gemm_q<<<256, 512, 0, stream>>>(xb, WaT, b_attn, qb);
  k_proj<<<dim3(4, 8, 8), 512, 0, stream>>>(Et, Ft, xTb, xEk, xEv);
  k_kpvp<<<dim3(32, 8, 2), 256, 0, stream>>>(xEk, xEv, WaT, b_attn, sE, sF, kp, vpt);
  k_attn<<<dim3(16, 64), 256, 0, stream>>>(qb, kp, vpt, yb);
  k_gemm_out<<<256, 512, 0, stream>>>(yb, WpT, b_proj, out);
}

// Round 20
// 320.991 us; speedup vs baseline: 1.3072x; 1.0018x over previous
//
#include <hip/hip_runtime.h>
#include <stdint.h>

typedef short bf16x8 __attribute__((ext_vector_type(8)));
typedef short bf16x4 __attribute__((ext_vector_type(4)));
typedef float f32x4 __attribute__((ext_vector_type(4)));
typedef float f32x16 __attribute__((ext_vector_type(16)));
typedef int i32x4 __attribute__((ext_vector_type(4)));

__device__ __forceinline__ short f2bf(float f) {
  union { float f; uint32_t u; } v; v.f = f;
  uint32_t r = (v.u + 0x7FFFu + ((v.u >> 16) & 1u)) >> 16;
  return (short)(uint16_t)r;
}

__device__ __forceinline__ int cvtpk(float lo, float hi) {
  int r;
  asm("v_cvt_pk_bf16_f32 %0, %1, %2" : "=v"(r) : "v"(lo), "v"(hi));
  return r;
}

// async global->LDS, 16B per lane; LDS dest must be linear in lane order
__device__ __forceinline__ void gload16(const void* g, void* l) {
  __builtin_amdgcn_global_load_lds(
      (const __attribute__((address_space(1))) unsigned int*)g,
      (__attribute__((address_space(3))) unsigned int*)l, 16, 0, 0);
}

#define WAITV(n) asm volatile("s_waitcnt vmcnt(" #n ")" ::: "memory")
#define BARRIER()                          \
  do {                                     \
    __builtin_amdgcn_s_barrier();          \
    asm volatile("" ::: "memory");         \
  } while (0)

// ---------------- fused: xb = bf16(x), xT = bf16(x)^T (per batch) ----------------
__global__ __launch_bounds__(256) void k_cvt_tr(const float* __restrict__ in,
                                                short* __restrict__ xb,
                                                short* __restrict__ xT) {
  __shared__ short tile[32][34];
  const int b = blockIdx.z;
  const int t0 = blockIdx.y * 32, c0 = blockIdx.x * 32;
  const int tx = threadIdx.x & 31, ty = threadIdx.x >> 5;
  const float* src = in + ((size_t)b * 4096 + t0) * 1024 + c0;
  short* dstA = xb + ((size_t)b * 4096 + t0) * 1024 + c0;
#pragma unroll
  for (int j = 0; j < 4; ++j) {
    int r = ty + j * 8;
    short bv = f2bf(src[(size_t)r * 1024 + tx]);
    dstA[(size_t)r * 1024 + tx] = bv;
    tile[tx][r] = bv;
  }
  __syncthreads();
  short* dstT = xT + ((size_t)b * 1024 + c0) * 4096 + t0;
#pragma unroll
  for (int j = 0; j < 4; ++j) {
    int c = ty + j * 8;
    dstT[(size_t)c * 4096 + tx] = tile[c][tx];
  }
}

// ---------------- transpose + convert: out[C][R] = bf16(in[R][C]) ----------------
__global__ __launch_bounds__(256) void k_transpose_cvt(const float* __restrict__ in,
                                                       short* __restrict__ out,
                                                       int R, int C) {
  __shared__ float tile[32][33];
  int r0 = blockIdx.y * 32, c0 = blockIdx.x * 32;
  int tx = threadIdx.x & 31, ty = threadIdx.x >> 5;
#pragma unroll
  for (int j = 0; j < 4; ++j)
    tile[ty + j * 8][tx] = in[(size_t)(r0 + ty + j * 8) * C + c0 + tx];
  __syncthreads();
#pragma unroll
  for (int j = 0; j < 4; ++j)
    out[(size_t)(c0 + ty + j * 8) * R + r0 + tx] = f2bf(tile[tx][ty + j * 8]);
}

// ---------------- column sums, two-stage deterministic reduction ----------------
__global__ __launch_bounds__(256) void k_colsum1(const float* __restrict__ E,
                                                 const float* __restrict__ F,
                                                 float* __restrict__ partial) {
  const int c = blockIdx.x * 256 + threadIdx.x;
  const int tc = blockIdx.y, which = blockIdx.z;
  const float* src = (which ? F : E) + (size_t)(tc * 64) * 1024 + c;
  float s = 0.f;
#pragma unroll 8
  for (int t = 0; t < 64; ++t) s += src[(size_t)t * 1024];
  partial[((size_t)which * 64 + tc) * 1024 + c] = s;
}

__global__ __launch_bounds__(256) void k_colsum2(const float* __restrict__ partial,
                                                 float* __restrict__ sE,
                                                 float* __restrict__ sF) {
  const int bid = blockIdx.x;
  const int which = bid >> 2, c = (bid & 3) * 256 + threadIdx.x;
  const float* p = partial + (size_t)which * 64 * 1024 + c;
  float s = 0.f;
#pragma unroll 8
  for (int t = 0; t < 64; ++t) s += p[(size_t)t * 1024];
  (which ? sF : sE)[c] = s;
}

// ---------------- GEMM_q: qb = x @ Wq + bq  (256x256, BK=32, quad-buffered) ----------
__global__ __launch_bounds__(512, 2) void k_gemm_q(const short* __restrict__ A,
                                                   const short* __restrict__ BT,
                                                   const float* __restrict__ bias,
                                                   short* __restrict__ qb) {
  __shared__ __align__(16) char lds[4 * 32768];
  const int tid = threadIdx.x, l = tid & 63, wv = tid >> 6;
  const int wm = wv >> 2, wn = wv & 3;
  const int r16 = l & 15, g4 = l >> 4;
  const int orig = blockIdx.x;
  const int xcd = orig & 7, loc = orig >> 3;
  const int m0 = (xcd * 8 + (loc & 7)) * 256, n0 = (loc >> 3) * 256;
  const int sl = (tid & 3) ^ ((tid >> 3) & 3);
  const short* aS = A + (size_t)(m0 + (tid >> 2)) * 1024 + sl * 8;
  const short* bS = BT + (size_t)(n0 + (tid >> 2)) * 1024 + sl * 8;
  const int sw = (g4 ^ ((r16 >> 1) & 3)) * 16;

  f32x4 acc[8][4];
#pragma unroll
  for (int i = 0; i < 8; ++i)
#pragma unroll
    for (int j = 0; j < 4; ++j) acc[i][j] = f32x4{0.f, 0.f, 0.f, 0.f};

#define STAGEQ(kt, bf)                                                      \
  {                                                                         \
    const int k0_ = (kt) * 32;                                              \
    gload16(aS + k0_, lds + (bf) * 32768 + tid * 16);                       \
    gload16(aS + 131072 + k0_, lds + (bf) * 32768 + 8192 + tid * 16);       \
    gload16(bS + k0_, lds + (bf) * 32768 + 16384 + tid * 16);               \
    gload16(bS + 131072 + k0_, lds + (bf) * 32768 + 24576 + tid * 16);      \
  }

  STAGEQ(0, 0); STAGEQ(1, 1); STAGEQ(2, 2);

  for (int kt = 0; kt < 32; ++kt) {
    if (kt < 30) WAITV(8);
    else if (kt == 30) WAITV(4);
    else WAITV(0);
    BARRIER();
    if (kt + 3 < 32) STAGEQ(kt + 3, (kt + 3) & 3);
    const char* aT = lds + (kt & 3) * 32768;
    const char* bT = aT + 16384;
    bf16x8 af[8], bfr[4];
#pragma unroll
    for (int mi = 0; mi < 8; ++mi)
      af[mi] = *(const bf16x8*)(aT + (wm * 128 + mi * 16 + r16) * 64 + sw);
#pragma unroll
    for (int ni = 0; ni < 4; ++ni)
      bfr[ni] = *(const bf16x8*)(bT + (wn * 64 + ni * 16 + r16) * 64 + sw);
    __builtin_amdgcn_s_setprio(1);
#pragma unroll
    for (int mi = 0; mi < 8; ++mi)
#pragma unroll
      for (int ni = 0; ni < 4; ++ni)
        acc[mi][ni] = __builtin_amdgcn_mfma_f32_16x16x32_bf16(af[mi], bfr[ni], acc[mi][ni], 0, 0, 0);
    __builtin_amdgcn_s_setprio(0);
  }
#undef STAGEQ

#pragma unroll
  for (int i = 0; i < 8; ++i)
#pragma unroll
    for (int j = 0; j < 4; ++j) {
      int row = m0 + wm * 128 + i * 16 + g4 * 4;
      int col = n0 + wn * 64 + j * 16 + r16;
      float bv = bias[col];
#pragma unroll
      for (int q = 0; q < 4; ++q)
        qb[(size_t)(row + q) * 1024 + col] = f2bf(acc[i][j][q] + bv);
    }
}

// ---------------- xE GEMM (256x128, BK=32, 3-stage, K=4096) ----------------
__global__ __launch_bounds__(512, 2) void k_proj(const short* __restrict__ Et,
                                                 const short* __restrict__ Ft,
                                                 const short* __restrict__ xT,
                                                 short* __restrict__ xEk,
                                                 short* __restrict__ xEv) {
  const int z = blockIdx.z, b = z >> 1, which = z & 1;
  const short* __restrict__ AT = which ? Ft : Et;
  const short* __restrict__ BTp = xT + ((size_t)b << 10) * 4096;
  short* __restrict__ outp = which ? xEv : xEk;
  __shared__ __align__(16) char lds[3 * 24576];
  const int tid = threadIdx.x, l = tid & 63, wv = tid >> 6;
  const int wm = wv >> 1, wn = wv & 1;
  const int r16 = l & 15, g4 = l >> 4;
  const int m0 = blockIdx.x * 256, n0 = blockIdx.y * 128;
  const int sl = (tid & 3) ^ ((tid >> 3) & 3);
  const short* aS = AT + (size_t)(m0 + (tid >> 2)) * 4096 + sl * 8;
  const short* bS = BTp + (size_t)(n0 + (tid >> 2)) * 4096 + sl * 8;
  const int sw = (g4 ^ ((r16 >> 1) & 3)) * 16;

  f32x4 acc[4][4];
#pragma unroll
  for (int i = 0; i < 4; ++i)
#pragma unroll
    for (int j = 0; j < 4; ++j) acc[i][j] = f32x4{0.f, 0.f, 0.f, 0.f};

#define STAGE2(kt, bf)                                                      \
  {                                                                         \
    const int k0_ = (kt) * 32;                                              \
    gload16(aS + k0_, lds + (bf) * 24576 + tid * 16);                       \
    gload16(aS + 524288 + k0_, lds + (bf) * 24576 + 8192 + tid * 16);       \
    gload16(bS + k0_, lds + (bf) * 24576 + 16384 + tid * 16);               \
  }

  STAGE2(0, 0); STAGE2(1, 1);

  for (int kt = 0; kt < 128; ++kt) {
    if (kt < 127) WAITV(3);
    else WAITV(0);
    BARRIER();
    if (kt + 2 < 128) STAGE2(kt + 2, (kt + 2) % 3);
    const char* aT = lds + (kt % 3) * 24576;
    const char* bT = aT + 16384;
    bf16x8 af[4], bfr[4];
#pragma unroll
    for (int mi = 0; mi < 4; ++mi)
      af[mi] = *(const bf16x8*)(aT + (wm * 64 + mi * 16 + r16) * 64 + sw);
#pragma unroll
    for (int ni = 0; ni < 4; ++ni)
      bfr[ni] = *(const bf16x8*)(bT + (wn * 64 + ni * 16 + r16) * 64 + sw);
    __builtin_amdgcn_s_setprio(1);
#pragma unroll
    for (int mi = 0; mi < 4; ++mi)
#pragma unroll
      for (int ni = 0; ni < 4; ++ni)
        acc[mi][ni] = __builtin_amdgcn_mfma_f32_16x16x32_bf16(af[mi], bfr[ni], acc[mi][ni], 0, 0, 0);
    __builtin_amdgcn_s_setprio(0);
  }
#undef STAGE2

#pragma unroll
  for (int i = 0; i < 4; ++i)
#pragma unroll
    for (int j = 0; j < 4; ++j) {
      int row = m0 + wm * 64 + i * 16 + g4 * 4;   // kk
      int col = n0 + wn * 64 + j * 16 + r16;      // c
#pragma unroll
      for (int q = 0; q < 4; ++q)
        outp[((size_t)(b * 1024) + row + q) * 1024 + col] = f2bf(acc[i][j][q]);
    }
}

// ---------------- kp/vp GEMM: kp = (0.125*log2e)*(xEk@Wk + sE*bk); vpt transposed ----
__global__ __launch_bounds__(256, 2) void k_kpvp(const short* __restrict__ xEk,
                                                 const short* __restrict__ xEv,
                                                 const short* __restrict__ WaT,
                                                 const float* __restrict__ b_attn,
                                                 const float* __restrict__ sE,
                                                 const float* __restrict__ sF,
                                                 short* __restrict__ kp,
                                                 short* __restrict__ vpt) {
  const int which = blockIdx.z;
  const short* __restrict__ A = which ? xEv : xEk;
  const short* __restrict__ BT = WaT + (size_t)(1024 + which * 1024) * 1024;
  const float* __restrict__ bias = b_attn + 1024 + which * 1024;
  const float* __restrict__ rs = which ? sF : sE;
  __shared__ __align__(16) char lds[4 * 16384];
  const int tid = threadIdx.x, l = tid & 63, wv = tid >> 6;
  const int wm = wv >> 1, wn = wv & 1;
  const int r16 = l & 15, g4 = l >> 4;
  const int m0 = blockIdx.x * 128, n0 = blockIdx.y * 128;
  const int sl = (tid & 3) ^ ((tid >> 3) & 3);
  const short* aS = A + (size_t)(m0 + (tid >> 2)) * 1024 + sl * 8;
  const short* bS = BT + (size_t)(n0 + (tid >> 2)) * 1024 + sl * 8;
  const int sw = (g4 ^ ((r16 >> 1) & 3)) * 16;

  f32x4 acc[4][4];
#pragma unroll
  for (int i = 0; i < 4; ++i)
#pragma unroll
    for (int j = 0; j < 4; ++j) acc[i][j] = f32x4{0.f, 0.f, 0.f, 0.f};

#define STAGEP(kt, bf)                                                      \
  {                                                                         \
    const int k0_ = (kt) * 32;                                              \
    gload16(aS + k0_, lds + (bf) * 16384 + tid * 16);                       \
    gload16(aS + 65536 + k0_, lds + (bf) * 16384 + 4096 + tid * 16);        \
    gload16(bS + k0_, lds + (bf) * 16384 + 8192 + tid * 16);                \
    gload16(bS + 65536 + k0_, lds + (bf) * 16384 + 12288 + tid * 16);       \
  }

  STAGEP(0, 0); STAGEP(1, 1); STAGEP(2, 2);

  for (int kt = 0; kt < 32; ++kt) {
    if (kt < 30) WAITV(8);
    else if (kt == 30) WAITV(4);
    else WAITV(0);
    BARRIER();
    if (kt + 3 < 32) STAGEP(kt + 3, (kt + 3) & 3);
    const char* aT = lds + (kt & 3) * 16384;
    const char* bT = aT + 8192;
    bf16x8 af[4], bfr[4];
#pragma unroll
    for (int mi = 0; mi < 4; ++mi)
      af[mi] = *(const bf16x8*)(aT + (wm * 64 + mi * 16 + r16) * 64 + sw);
#pragma unroll
    for (int ni = 0; ni < 4; ++ni)
      bfr[ni] = *(const bf16x8*)(bT + (wn * 64 + ni * 16 + r16) * 64 + sw);
    __builtin_amdgcn_s_setprio(1);
#pragma unroll
    for (int mi = 0; mi < 4; ++mi)
#pragma unroll
      for (int ni = 0; ni < 4; ++ni)
        acc[mi][ni] = __builtin_amdgcn_mfma_f32_16x16x32_bf16(af[mi], bfr[ni], acc[mi][ni], 0, 0, 0);
    __builtin_amdgcn_s_setprio(0);
  }
#undef STAGEP

  if (which) {
#pragma unroll
    for (int i = 0; i < 4; ++i)
#pragma unroll
      for (int j = 0; j < 4; ++j) {
        int row = m0 + wm * 64 + i * 16 + g4 * 4;   // global (b,kk) row
        int col = n0 + wn * 64 + j * 16 + r16;
        int bb = row >> 10;
        float bv = bias[col];
        bf16x4 ov;
#pragma unroll
        for (int q = 0; q < 4; ++q)
          ov[q] = f2bf(acc[i][j][q] + rs[(row + q) & 1023] * bv);
        *reinterpret_cast<bf16x4*>(
            &vpt[(((size_t)bb << 10) + col) * 1024 + (row & 1023)]) = ov;
      }
  } else {
    const float KSCALE = 0.125f * 1.4426950408889634f;
#pragma unroll
    for (int i = 0; i < 4; ++i)
#pragma unroll
      for (int j = 0; j < 4; ++j) {
        int row = m0 + wm * 64 + i * 16 + g4 * 4;
        int col = n0 + wn * 64 + j * 16 + r16;
        float bv = bias[col];
#pragma unroll
        for (int q = 0; q < 4; ++q)
          kp[(size_t)(row + q) * 1024 + col] =
              f2bf((acc[i][j][q] + rs[(row + q) & 1023] * bv) * KSCALE);
      }
  }
}

// ---------------- Flash attention: swapped 32x32x16, no-max exp2 softmax,
//                  T14 async stage split; 3 blocks/CU (proven R17 config) ----------
__global__ __launch_bounds__(256, 3) void k_attn(const short* __restrict__ qb,
                                                 const short* __restrict__ kp,
                                                 const short* __restrict__ vpt,
                                                 short* __restrict__ y) {
  __shared__ __align__(16) char KsB[128 * 128];   // [kk][d] swizzled, 16 KB
  __shared__ __align__(16) char VtB[64 * 256];    // [d][kk] swizzled, 16 KB
  const int tid = threadIdx.x, lane = tid & 63, w = tid >> 6;
  const int r32 = lane & 31, hi = lane >> 5;
  const int iblk = 31 - blockIdx.x;     // heavy blocks first
  const int bh = blockIdx.y, b = bh >> 4, h = bh & 15;
  const int t0 = iblk * 128;
  const int tl = w * 32 + r32;          // local row
  const int T = t0 + tl;                // global row (within b)

  bf16x8 qf[4];
#pragma unroll
  for (int kd = 0; kd < 4; ++kd)
    qf[kd] = *reinterpret_cast<const bf16x8*>(
        &qb[(size_t)(b * 4096 + T) * 1024 + h * 64 + kd * 16 + hi * 8]);

  f32x16 o[2];
#pragma unroll
  for (int i = 0; i < 16; ++i) { o[0][i] = 0.f; o[1][i] = 0.f; }
  float lrun = 0.f;

  const short* kpb = kp + ((size_t)b << 20) + h * 64;             // [kk][c]
  const short* vtb = vpt + (((size_t)b << 10) + h * 64) * 1024;   // [c][kk]

  const int kkl_ = tid >> 3, c8 = tid & 7;
  const int dl_ = tid >> 4, c16 = tid & 15;
  bf16x8 kreg[4], vreg[4];

#define LOADT(jt)                                                              \
  {                                                                            \
    const int kk0_ = (jt) * 128;                                               \
    _Pragma("unroll") for (int it = 0; it < 4; ++it) {                         \
      kreg[it] = *reinterpret_cast<const bf16x8*>(                             \
          &kpb[(size_t)(kk0_ + it * 32 + kkl_) * 1024 + c8 * 8]);              \
      vreg[it] = *reinterpret_cast<const bf16x8*>(                             \
          &vtb[(size_t)(it * 16 + dl_) * 1024 + kk0_ + c16 * 8]);              \
    }                                                                          \
  }

  LOADT(0);

  const int ntiles = (iblk + 1 < 8) ? (iblk + 1) : 8;
  for (int jt = 0; jt < ntiles; ++jt) {
    WAITV(0);        // prefetched regs valid
    BARRIER();       // all waves done reading previous tile's LDS
#pragma unroll
    for (int it = 0; it < 4; ++it) {
      int kk = it * 32 + kkl_;
      *reinterpret_cast<bf16x8*>(&KsB[kk * 128 + ((c8 * 16) ^ ((kk & 7) << 4))]) = kreg[it];
      int d = it * 16 + dl_;
      *reinterpret_cast<bf16x8*>(&VtB[d * 256 + ((c16 * 16) ^ ((d & 7) << 4))]) = vreg[it];
    }
    __syncthreads();                    // writes visible
    if (jt + 1 < ntiles) LOADT(jt + 1); // async: latency hides under compute below

#pragma unroll
    for (int st = 0; st < 2; ++st) {          // 64-kk sub-tiles
      f32x16 s[2];
#pragma unroll
      for (int i = 0; i < 16; ++i) { s[0][i] = 0.f; s[1][i] = 0.f; }
#pragma unroll
      for (int ni = 0; ni < 2; ++ni) {
        int row = (st * 2 + ni) * 32 + r32;
#pragma unroll
        for (int kd = 0; kd < 4; ++kd) {
          bf16x8 kf = *reinterpret_cast<const bf16x8*>(
              &KsB[row * 128 + ((kd * 32 + hi * 16) ^ ((row & 7) << 4))]);
          s[ni] = __builtin_amdgcn_mfma_f32_32x32x16_bf16(kf, qf[kd], s[ni], 0, 0, 0);
        }
      }

      if (jt == iblk) {  // causal mask on diagonal tile
#pragma unroll
        for (int ni = 0; ni < 2; ++ni)
#pragma unroll
          for (int j = 0; j < 16; ++j) {
            int kkl = (st * 2 + ni) * 32 + (j & 3) + 8 * (j >> 2) + 4 * hi;
            if (kkl > tl) s[ni][j] = -1e30f;
          }
      }

      // --- no-max softmax, exp2 domain (log2e folded into kp): P = exp2(S)
      float r0 = 0.f, r1 = 0.f, r2 = 0.f, r3 = 0.f;
#pragma unroll
      for (int j = 0; j < 16; j += 2) {
        float e0 = __builtin_amdgcn_exp2f(s[0][j]);
        float e1 = __builtin_amdgcn_exp2f(s[0][j + 1]);
        float e2 = __builtin_amdgcn_exp2f(s[1][j]);
        float e3 = __builtin_amdgcn_exp2f(s[1][j + 1]);
        s[0][j] = e0; s[0][j + 1] = e1; s[1][j] = e2; s[1][j + 1] = e3;
        r0 += e0; r1 += e1; r2 += e2; r3 += e3;
      }
      float rsum = (r0 + r1) + (r2 + r3);
      rsum += __shfl_xor(rsum, 32, 64);
      lrun += rsum;

      // --- pack P -> bf16 B-frags (cvtpk + permlane32_swap) and PV MFMA
#pragma unroll
      for (int kbl = 0; kbl < 4; ++kbl) {
        const int ni = kbl >> 1, jb = (kbl & 1) * 8;
        int lo0 = cvtpk(s[ni][jb + 0], s[ni][jb + 1]);
        int lo1 = cvtpk(s[ni][jb + 2], s[ni][jb + 3]);
        int hi0 = cvtpk(s[ni][jb + 4], s[ni][jb + 5]);
        int hi1 = cvtpk(s[ni][jb + 6], s[ni][jb + 7]);
        asm("v_permlane32_swap_b32 %0, %1" : "+v"(lo0), "+v"(hi0));
        asm("v_permlane32_swap_b32 %0, %1" : "+v"(lo1), "+v"(hi1));
        i32x4 pw; pw[0] = lo0; pw[1] = lo1; pw[2] = hi0; pw[3] = hi1;
        bf16x8 pf = __builtin_bit_cast(bf16x8, pw);
        const int kb = st * 4 + kbl;
#pragma unroll
        for (int mo = 0; mo < 2; ++mo) {
          int row = mo * 32 + r32;
          bf16x8 vf = *reinterpret_cast<const bf16x8*>(
              &VtB[row * 256 + ((kb * 32 + hi * 16) ^ ((row & 7) << 4))]);
          o[mo] = __builtin_amdgcn_mfma_f32_32x32x16_bf16(vf, pf, o[mo], 0, 0, 0);
        }
      }
    }
  }

  float inv = 1.0f / lrun;
#pragma unroll
  for (int mo = 0; mo < 2; ++mo)
#pragma unroll
    for (int rq = 0; rq < 4; ++rq) {
      bf16x4 ov;
#pragma unroll
      for (int c = 0; c < 4; ++c) ov[c] = f2bf(o[mo][rq * 4 + c] * inv);
      *reinterpret_cast<bf16x4*>(
          &y[(size_t)(b * 4096 + T) * 1024 + h * 64 + mo * 32 + rq * 8 + hi * 4]) = ov;
    }
#undef LOADT
}

// ---------------- GEMM2: out = y @ W_proj + b (256x256, BK=32, quad-buffered) --------
__global__ __launch_bounds__(512, 2) void k_gemm_out(const short* __restrict__ A,
                                                     const short* __restrict__ BT,
                                                     const float* __restrict__ bias,
                                                     float* __restrict__ C) {
  __shared__ __align__(16) char lds[4 * 32768];
  const int tid = threadIdx.x, l = tid & 63, wv = tid >> 6;
  const int wm = wv >> 2, wn = wv & 3;
  const int r16 = l & 15, g4 = l >> 4;
  const int orig = blockIdx.x;
  const int xcd = orig & 7, loc = orig >> 3;
  const int m0 = (xcd * 8 + (loc & 7)) * 256, n0 = (loc >> 3) * 256;
  const int sl = (tid & 3) ^ ((tid >> 3) & 3);
  const short* aS = A + (size_t)(m0 + (tid >> 2)) * 1024 + sl * 8;
  const short* bS = BT + (size_t)(n0 + (tid >> 2)) * 1024 + sl * 8;
  const int sw = (g4 ^ ((r16 >> 1) & 3)) * 16;

  f32x4 acc[8][4];
#pragma unroll
  for (int i = 0; i < 8; ++i)
#pragma unroll
    for (int j = 0; j < 4; ++j) acc[i][j] = f32x4{0.f, 0.f, 0.f, 0.f};

#define STAGE3(kt, bf)                                                      \
  {                                                                         \
    const int k0_ = (kt) * 32;                                              \
    gload16(aS + k0_, lds + (bf) * 32768 + tid * 16);                       \
    gload16(aS + 131072 + k0_, lds + (bf) * 32768 + 8192 + tid * 16);       \
    gload16(bS + k0_, lds + (bf) * 32768 + 16384 + tid * 16);               \
    gload16(bS + 131072 + k0_, lds + (bf) * 32768 + 24576 + tid * 16);      \
  }

  STAGE3(0, 0); STAGE3(1, 1); STAGE3(2, 2);

  for (int kt = 0; kt < 32; ++kt) {
    if (kt < 30) WAITV(8);
    else if (kt == 30) WAITV(4);
    else WAITV(0);
    BARRIER();
    if (kt + 3 < 32) STAGE3(kt + 3, (kt + 3) & 3);
    const char* aT = lds + (kt & 3) * 32768;
    const char* bT = aT + 16384;
    bf16x8 af[8], bfr[4];
#pragma unroll
    for (int mi = 0; mi < 8; ++mi)
      af[mi] = *(const bf16x8*)(aT + (wm * 128 + mi * 16 + r16) * 64 + sw);
#pragma unroll
    for (int ni = 0; ni < 4; ++ni)
      bfr[ni] = *(const bf16x8*)(bT + (wn * 64 + ni * 16 + r16) * 64 + sw);
    __builtin_amdgcn_s_setprio(1);
#pragma unroll
    for (int mi = 0; mi < 8; ++mi)
#pragma unroll
      for (int ni = 0; ni < 4; ++ni)
        acc[mi][ni] = __builtin_amdgcn_mfma_f32_16x16x32_bf16(af[mi], bfr[ni], acc[mi][ni], 0, 0, 0);
    __builtin_amdgcn_s_setprio(0);
  }
#undef STAGE3

#pragma unroll
  for (int i = 0; i < 8; ++i)
#pragma unroll
    for (int j = 0; j < 4; ++j) {
      int row = m0 + wm * 128 + i * 16 + g4 * 4;
      int col = n0 + wn * 64 + j * 16 + r16;
      float bv = bias[col];
#pragma unroll
      for (int q = 0; q < 4; ++q)
        C[(size_t)(row + q) * 1024 + col] = acc[i][j][q] + bv;
    }
}

extern "C" void kernel_launch(void* const* d_in, const int* in_sizes, int n_in,
                              void* d_out, int out_size, void* d_ws, size_t ws_size,
                              hipStream_t stream) {
  const float* x      = (const float*)d_in[0];
  const float* W_attn = (const float*)d_in[1];
  const float* b_attn = (const float*)d_in[2];
  const float* W_proj = (const float*)d_in[3];
  const float* b_proj = (const float*)d_in[4];
  const float* E      = (const float*)d_in[5];
  const float* F      = (const float*)d_in[6];
  float* out = (float*)d_out;

  char* ws = (char*)d_ws;
  short* xb  = (short*)(ws + 0);          //  32 MB: x bf16            (16384x1024)
  short* WaT = (short*)(ws + 33554432);   //   6 MB: W_attn^T bf16     (3072x1024)
  short* WpT = (short*)(ws + 39845888);   //   2 MB: W_proj^T bf16     (1024x1024)
  short* Et  = (short*)(ws + 41943040);   //   8 MB: E^T bf16          (1024x4096)
  short* Ft  = (short*)(ws + 50331648);   //   8 MB: F^T bf16          (1024x4096)
  short* qb  = (short*)(ws + 58720256);   //  32 MB: q bf16            (16384x1024)
  short* xTb = (short*)(ws + 92274688);   //  32 MB: x^T bf16          (4x1024x4096)
  short* xEk = (short*)(ws + 125829120);  //   8 MB: E^T@x bf16        (4x1024x1024)
  short* xEv = (short*)(ws + 134217728);  //   8 MB: F^T@x bf16        (4x1024x1024)
  short* kp  = (short*)(ws + 142606336);  //   8 MB: k_proj bf16       (4x1024x1024)
  short* vpt = (short*)(ws + 150994944);  //   8 MB: v_proj^T bf16     (4x1024x1024)
  short* yb  = (short*)(ws + 159383552);  //  32 MB: attn out bf16     (16384x1024)
  float* sE  = (float*)(ws + 192937984);  //   4 KB: colsum(E)
  float* sF  = (float*)(ws + 192942080);  //   4 KB: colsum(F)
  float* part= (float*)(ws + 192946176);  // 512 KB: colsum partials (2x64x1024)

  k_cvt_tr<<<dim3(32, 128, 4), 256, 0, stream>>>(x, xb, xTb);
  k_transpose_cvt<<<dim3(96, 32), 256, 0, stream>>>(W_attn, WaT, 1024, 3072);
  k_transpose_cvt<<<dim3(32, 32), 256, 0, stream>>>(W_proj, WpT, 1024, 1024);
  k_transpose_cvt<<<dim3(32, 128), 256, 0, stream>>>(E, Et, 4096, 1024);
  k_transpose_cvt<<<dim3(32, 128), 256, 0, stream>>>(F, Ft, 4096, 1024);
  k_colsum1<<<dim3(4, 64, 2), 256, 0, stream>>>(E, F, part);
  k_colsum2<<<8, 256, 0, stream>>>(part, sE, sF);

  k_gemm_q<<<256, 512, 0, stream>>>(xb, WaT, b_attn, qb);
  k_proj<<<dim3(4, 8, 8), 512, 0, stream>>>(Et, Ft, xTb, xEk, xEv);
  k_kpvp<<<dim3(32, 8, 2), 256, 0, stream>>>(xEk, xEv, WaT, b_attn, sE, sF, kp, vpt);
  k_attn<<<dim3(32, 64), 256, 0, stream>>>(qb, kp, vpt, yb);
  k_gemm_out<<<256, 512, 0, stream>>>(yb, WpT, b_proj, out);
}